// Round 8
// baseline (297.260 us; speedup 1.0000x reference)
//
#include <hip/hip_runtime.h>
#include <hip/hip_bf16.h>
#include <stdint.h>

#define B_ 8
#define T_ 2048
#define E_ 1024
#define H_ 1024
#define M_ (B_*T_)   // 16384

typedef __attribute__((ext_vector_type(8))) short bf16x8;
typedef __attribute__((ext_vector_type(4))) float f32x4;

__device__ __forceinline__ unsigned short f2bf(float f) {
  union { float f; unsigned int u; } v; v.f = f;
  unsigned int u = v.u;
  unsigned int r = u + 0x7fffu + ((u >> 16) & 1u);   // RNE (inputs finite)
  return (unsigned short)(r >> 16);
}

__device__ __forceinline__ float bf2f(unsigned short s) {
  union { unsigned int u; float f; } v; v.u = ((unsigned int)s) << 16;
  return v.f;
}

// async global->LDS, 16B per lane; LDS dest = wave-uniform base + lane*16
__device__ __forceinline__ void gload_lds16(const void* g, void* l) {
  __builtin_amdgcn_global_load_lds((const __attribute__((address_space(1))) void*)g,
                                   (__attribute__((address_space(3))) void*)l, 16, 0, 0);
}

#define MEMFENCE asm volatile("" ::: "memory")
#define BARRIER() do { MEMFENCE; __builtin_amdgcn_s_barrier(); MEMFENCE; } while (0)

// ---------- convert x (fp32) -> xb (bf16), 8 elems / thread ----------
__global__ void conv_x_kernel(const float* __restrict__ x,
                              unsigned short* __restrict__ xb, int n8) {
  int i = blockIdx.x * blockDim.x + threadIdx.x;
  if (i >= n8) return;
  const float4* src = (const float4*)(x + (size_t)i * 8);
  float4 a = src[0], b = src[1];
  uint4 o;
  o.x = (unsigned)f2bf(a.x) | ((unsigned)f2bf(a.y) << 16);
  o.y = (unsigned)f2bf(a.z) | ((unsigned)f2bf(a.w) << 16);
  o.z = (unsigned)f2bf(b.x) | ((unsigned)f2bf(b.y) << 16);
  o.w = (unsigned)f2bf(b.z) | ((unsigned)f2bf(b.w) << 16);
  *(uint4*)(xb + (size_t)i * 8) = o;
}

// ---------- convert + transpose W (E x H fp32) -> wT (H x E bf16) ----------
__global__ void conv_wT_kernel(const float* __restrict__ W0, const float* __restrict__ W1,
                               const float* __restrict__ W2,
                               unsigned short* __restrict__ T0, unsigned short* __restrict__ T1,
                               unsigned short* __restrict__ T2) {
  __shared__ float tile[32][33];
  const float* W = (blockIdx.z == 0) ? W0 : (blockIdx.z == 1) ? W1 : W2;
  unsigned short* Tt = (blockIdx.z == 0) ? T0 : (blockIdx.z == 1) ? T1 : T2;
  int k0 = blockIdx.x * 32;
  int n0 = blockIdx.y * 32;
  int t = threadIdx.x;
#pragma unroll
  for (int i = 0; i < 4; ++i) {
    int e = t + i * 256; int r = e >> 5, c = e & 31;
    tile[r][c] = W[(size_t)(k0 + r) * H_ + n0 + c];
  }
  __syncthreads();
#pragma unroll
  for (int i = 0; i < 4; ++i) {
    int e = t + i * 256; int r = e >> 5, c = e & 31;   // r = n-local, c = k-local
    Tt[(size_t)(n0 + r) * E_ + k0 + c] = f2bf(tile[c][r]);
  }
}

// ================== 256x256 8-phase GEMM (QKV projection) ==================
// 8 waves (2M x 4N), BK=64, double-buffered 128KB LDS, counted vmcnt(6),
// raw s_barrier + explicit lgkmcnt(0)+sched_barrier(0), setprio around MFMA.
// Stage swizzle = pre-swizzled global source + XOR read. Staging schedule
// (ph1:B-lo(U+1), ph3:B-hi(U+2), ph4:A-lo+A-hi(U+2)) is hazard-derived: A parts
// are read in ph1 AND ph3 -> only safe at ph4; B parts read ph1-2 -> safe ph3.

// part: 0=A rows 0-127, 1=A rows 128-255, 2=B rows 0-127, 3=B rows 128-255
__device__ __forceinline__ void stage_part(const unsigned short* Ap, size_t sA,
                                           const unsigned short* Bp, size_t sB,
                                           short* Alds, short* Blds, int V, int part, int tid) {
  const int srow = tid >> 3;                      // 0..63
  const int sg = ((tid & 7) ^ (srow & 7)) * 8;    // pre-swizzled granule (shorts)
  const int w = tid >> 6;
  const unsigned short* g; short* l; size_t gs;
  if (part == 0)      { g = Ap;                    l = Alds;            gs = sA; }
  else if (part == 1) { g = Ap + (size_t)128 * sA; l = Alds + 128 * 64; gs = sA; }
  else if (part == 2) { g = Bp;                    l = Blds;            gs = sB; }
  else                { g = Bp + (size_t)128 * sB; l = Blds + 128 * 64; gs = sB; }
  const unsigned short* gr = g + (size_t)V * 64 + (size_t)srow * gs + sg;
#pragma unroll
  for (int r = 0; r < 2; ++r)
    gload_lds16(gr + (size_t)(r * 64) * gs, l + (r * 64 + w * 8) * 64);
}

__global__ __launch_bounds__(512, 2)
void gemm_qkv256_kernel(const unsigned short* __restrict__ xb,
                        const unsigned short* __restrict__ wqT, const unsigned short* __restrict__ wkT,
                        const unsigned short* __restrict__ wvT,
                        const float* __restrict__ bq, const float* __restrict__ bk,
                        const float* __restrict__ bv,
                        unsigned short* __restrict__ qb, unsigned short* __restrict__ kb,
                        unsigned short* __restrict__ vb) {
  __shared__ short LDSU[4 * 256 * 64];   // 128KB: [A0][A1][B0][B1], reused by epilogue bounce
  const int which = blockIdx.y >> 2;
  const int ncol0 = (blockIdx.y & 3) * 256;
  const unsigned short* Bt = (which == 0) ? wqT : (which == 1) ? wkT : wvT;
  const float* bias = (which == 0) ? bq : (which == 1) ? bk : bv;
  unsigned short* outp = (which == 0) ? qb : (which == 1) ? kb : vb;
  const int m0 = blockIdx.x * 256;
  const unsigned short* Ap = xb + (size_t)m0 * E_;
  const unsigned short* Bp = Bt + (size_t)ncol0 * E_;
  const int NT = E_ / 64;   // 16

  const int tid = threadIdx.x, lane = tid & 63, w = tid >> 6;
  const int lo = lane & 15, hi = lane >> 4;
  const int wm = (w >> 2) * 128, wn = (w & 3) * 64;

  // hoisted lane-constant LDS read offsets: addr = buf + laneX + X[kt] + (imm)
  const int X0 = (hi << 4) ^ ((lo & 7) << 4);
  const int X1 = ((4 + hi) << 4) ^ ((lo & 7) << 4);
  const int laneA = (wm + lo) << 7;
  const int laneB = (wn + lo) << 7;

  f32x4 acc[8][4];
#pragma unroll
  for (int i = 0; i < 8; ++i)
#pragma unroll
    for (int j = 0; j < 4; ++j)
#pragma unroll
      for (int r = 0; r < 4; ++r) acc[i][j][r] = 0.f;

#define ST(V, P) do { if ((V) < NT) stage_part(Ap, E_, Bp, E_, LDSU + (((V) & 1) * 16384), LDSU + 32768 + (((V) & 1) * 16384), (V), (P), tid); } while (0)
#define WAITMFMA() do { asm volatile("s_waitcnt lgkmcnt(0)" ::: "memory"); __builtin_amdgcn_sched_barrier(0); } while (0)

  // ---- prologue: tile0 all 4 halves, stagger, tile1 {B-hi, A-lo, A-hi} ----
  ST(0, 0); ST(0, 1); ST(0, 2); ST(0, 3);
  asm volatile("s_waitcnt vmcnt(4)" ::: "memory");
  ST(1, 3); ST(1, 0); ST(1, 1);
  asm volatile("s_waitcnt vmcnt(6)" ::: "memory");
  BARRIER();

  bf16x8 a[4][2], b0[2][2], b1[2][2];
  for (int U = 0; U < NT; ++U) {
    const char* Ac = (const char*)LDSU + (U & 1) * 32768;
    const char* Bc = (const char*)LDSU + 65536 + (U & 1) * 32768;
    const char* pA0 = Ac + laneA + X0; const char* pA1 = Ac + laneA + X1;
    const char* pB0 = Bc + laneB + X0; const char* pB1 = Bc + laneB + X1;
    // ---------- phase 1: read A-M0 + B-N0, stage (U+1).B-lo, MFMA (M0,N0) ----------
#pragma unroll
    for (int mt = 0; mt < 4; ++mt) {
      a[mt][0] = *(const bf16x8*)(pA0 + mt * 2048);
      a[mt][1] = *(const bf16x8*)(pA1 + mt * 2048);
    }
#pragma unroll
    for (int nt = 0; nt < 2; ++nt) {
      b0[nt][0] = *(const bf16x8*)(pB0 + nt * 2048);
      b0[nt][1] = *(const bf16x8*)(pB1 + nt * 2048);
    }
    ST(U + 1, 2);
    BARRIER();
    WAITMFMA();
    __builtin_amdgcn_s_setprio(1);
#pragma unroll
    for (int mt = 0; mt < 4; ++mt)
#pragma unroll
      for (int nt = 0; nt < 2; ++nt)
#pragma unroll
        for (int kt = 0; kt < 2; ++kt)
          acc[mt][nt] = __builtin_amdgcn_mfma_f32_16x16x32_bf16(a[mt][kt], b0[nt][kt], acc[mt][nt], 0, 0, 0);
    __builtin_amdgcn_s_setprio(0);
    BARRIER();
    // ---------- phase 2: read B-N1, MFMA (M0,N1) ----------
#pragma unroll
    for (int nt = 0; nt < 2; ++nt) {
      b1[nt][0] = *(const bf16x8*)(pB0 + 4096 + nt * 2048);
      b1[nt][1] = *(const bf16x8*)(pB1 + 4096 + nt * 2048);
    }
    BARRIER();
    WAITMFMA();
    __builtin_amdgcn_s_setprio(1);
#pragma unroll
    for (int mt = 0; mt < 4; ++mt)
#pragma unroll
      for (int nt = 0; nt < 2; ++nt)
#pragma unroll
        for (int kt = 0; kt < 2; ++kt)
          acc[mt][2 + nt] = __builtin_amdgcn_mfma_f32_16x16x32_bf16(a[mt][kt], b1[nt][kt], acc[mt][2 + nt], 0, 0, 0);
    __builtin_amdgcn_s_setprio(0);
    BARRIER();
    // ---------- phase 3: read A-M1, stage (U+2).B-hi, MFMA (M1,N0) ----------
#pragma unroll
    for (int mt = 0; mt < 4; ++mt) {
      a[mt][0] = *(const bf16x8*)(pA0 + 8192 + mt * 2048);
      a[mt][1] = *(const bf16x8*)(pA1 + 8192 + mt * 2048);
    }
    ST(U + 2, 3);
    BARRIER();
    WAITMFMA();
    __builtin_amdgcn_s_setprio(1);
#pragma unroll
    for (int mt = 0; mt < 4; ++mt)
#pragma unroll
      for (int nt = 0; nt < 2; ++nt)
#pragma unroll
        for (int kt = 0; kt < 2; ++kt)
          acc[4 + mt][nt] = __builtin_amdgcn_mfma_f32_16x16x32_bf16(a[mt][kt], b0[nt][kt], acc[4 + mt][nt], 0, 0, 0);
    __builtin_amdgcn_s_setprio(0);
    BARRIER();
    // ---------- phase 4: stage (U+2).A-lo + A-hi, MFMA (M1,N1), boundary vmcnt ----------
    ST(U + 2, 0);
    ST(U + 2, 1);
    BARRIER();
    __builtin_amdgcn_s_setprio(1);
#pragma unroll
    for (int mt = 0; mt < 4; ++mt)
#pragma unroll
      for (int nt = 0; nt < 2; ++nt)
#pragma unroll
        for (int kt = 0; kt < 2; ++kt)
          acc[4 + mt][2 + nt] = __builtin_amdgcn_mfma_f32_16x16x32_bf16(a[mt][kt], b1[nt][kt], acc[4 + mt][2 + nt], 0, 0, 0);
    __builtin_amdgcn_s_setprio(0);
    if (U + 2 < NT) asm volatile("s_waitcnt vmcnt(6)" ::: "memory");
    else            asm volatile("s_waitcnt vmcnt(0)" ::: "memory");
    BARRIER();
  }
#undef ST
#undef WAITMFMA

  // ---------- epilogue: bounce acc through LDS (now free) for coalesced stores ----------
  char* Ep = (char*)LDSU;   // 128KB = full 256x256 bf16 tile
  if (which == 2) {
    // layout [tc][tr] (column-major -> vT), granule-XOR swizzled within each 512B row
#pragma unroll
    for (int j = 0; j < 4; ++j) {
      int tc = wn + (j >> 1) * 32 + (j & 1) * 16 + lo;
      float bb = bias[ncol0 + tc];
      char* rowp = Ep + tc * 512;
      int xr = (tc & 31) << 4;
#pragma unroll
      for (int i = 0; i < 8; ++i) {
        int trb = wm + (i >> 2) * 64 + (i & 3) * 16 + hi * 4;
#pragma unroll
        for (int r = 0; r < 4; ++r)
          *(unsigned short*)(rowp + (((trb + r) * 2) ^ xr)) = f2bf(acc[i][j][r] + bb);
      }
    }
  } else {
    // layout [tr][tc] (row-major -> q/k)
#pragma unroll
    for (int j = 0; j < 4; ++j) {
      int tc = wn + (j >> 1) * 32 + (j & 1) * 16 + lo;
      float bb = bias[ncol0 + tc];
#pragma unroll
      for (int i = 0; i < 8; ++i) {
        int trb = wm + (i >> 2) * 64 + (i & 3) * 16 + hi * 4;
#pragma unroll
        for (int r = 0; r < 4; ++r) {
          int tr = trb + r;
          *(unsigned short*)(Ep + tr * 512 + ((tc * 2) ^ ((tr & 31) << 4))) = f2bf(acc[i][j][r] + bb);
        }
      }
    }
  }
  __syncthreads();
  {
    const int rr = tid >> 1, hf = tid & 1;
    const char* rowp = Ep + rr * 512;
    const int xr = (rr & 31) << 4;
    unsigned short* gp = (which == 2) ? outp + (size_t)(ncol0 + rr) * M_ + m0
                                      : outp + (size_t)(m0 + rr) * H_ + ncol0;
#pragma unroll
    for (int k = 0; k < 16; ++k) {
      int kk = hf * 16 + k;
      bf16x8 v = *(const bf16x8*)(rowp + ((kk << 4) ^ xr));
      *(bf16x8*)(gp + kk * 8) = v;
    }
  }
}

// ---------- shared 128x128 GEMM core (hoisted swizzle addresses) ----------
__device__ __forceinline__ void gemm_core(const unsigned short* __restrict__ Ap, size_t strideA,
                                          const unsigned short* __restrict__ Bp, size_t strideB,
                                          int kmax, short* Alds, short* Blds,
                                          int lane, int wid, f32x4 acc[4][4]) {
  const int lo = lane & 15, hi = lane >> 4;
  const int wm = (wid >> 1) * 64, wn = (wid & 1) * 64;
  const int srow = wid * 8 + (lane >> 3);
  const int scol = ((lane & 7) ^ (srow & 7)) * 8;
  short* Al = Alds + wid * 512;
  short* Bl = Blds + wid * 512;
  const int X0 = (hi << 4) ^ ((lo & 7) << 4);
  const int X1 = ((4 + hi) << 4) ^ ((lo & 7) << 4);
  const char* pA = (const char*)Alds + ((wm + lo) << 7);
  const char* pB = (const char*)Blds + ((wn + lo) << 7);

  for (int kb0 = 0; kb0 < kmax; kb0 += 64) {
#pragma unroll
    for (int i = 0; i < 4; ++i) {
      gload_lds16(Ap + (size_t)(i * 32 + srow) * strideA + kb0 + scol, Al + i * 2048);
      gload_lds16(Bp + (size_t)(i * 32 + srow) * strideB + kb0 + scol, Bl + i * 2048);
    }
    __syncthreads();
#pragma unroll
    for (int kt = 0; kt < 2; ++kt) {
      const char* ap = kt ? (pA + X1) : (pA + X0);
      const char* bp = kt ? (pB + X1) : (pB + X0);
      bf16x8 af[4], bfr[4];
#pragma unroll
      for (int mt = 0; mt < 4; ++mt) af[mt] = *(const bf16x8*)(ap + mt * 2048);
#pragma unroll
      for (int nt = 0; nt < 4; ++nt) bfr[nt] = *(const bf16x8*)(bp + nt * 2048);
#pragma unroll
      for (int mt = 0; mt < 4; ++mt)
#pragma unroll
        for (int nt = 0; nt < 4; ++nt)
          acc[mt][nt] = __builtin_amdgcn_mfma_f32_16x16x32_bf16(af[mt], bfr[nt], acc[mt][nt], 0, 0, 0);
    }
    __syncthreads();
  }
}

// ---------- S = (Q K^T) * scale, causal lower-tri 128x128 tiles, bf16 out ----------
__global__ __launch_bounds__(256)
void sgemm_kernel(const unsigned short* __restrict__ qb, const unsigned short* __restrict__ kb,
                  unsigned short* __restrict__ S) {
  __shared__ short LU[2 * 128 * 64];   // 32KB; reused for epilogue bounce
  int id = blockIdx.x;
  int b = id & 7, t = id >> 3;            // batch-fastest: same batch -> same XCD
  int mb = 0;
  while ((mb + 1) * (mb + 2) / 2 <= t) ++mb;
  int nb = t - mb * (mb + 1) / 2;         // nb <= mb (lower triangle)
  const size_t bT = (size_t)b * T_;
  int tid = threadIdx.x, lane = tid & 63, wid = tid >> 6;
  int wm = (wid >> 1) * 64, wn = (wid & 1) * 64;
  const int lo = lane & 15, hi = lane >> 4;

  f32x4 acc[4][4];
#pragma unroll
  for (int i = 0; i < 4; ++i)
#pragma unroll
    for (int j = 0; j < 4; ++j)
#pragma unroll
      for (int r = 0; r < 4; ++r) acc[i][j][r] = 0.f;

  gemm_core(qb + (bT + mb * 128) * (size_t)H_, H_,
            kb + (bT + nb * 128) * (size_t)H_, H_, H_,
            LU, LU + 8192, lane, wid, acc);

  // bounce S tile (128x128 bf16 = 32KB) through LDS for coalesced b128 stores
  char* Ep = (char*)LU;
#pragma unroll
  for (int nt = 0; nt < 4; ++nt) {
    int tc = wn + nt * 16 + lo;
#pragma unroll
    for (int mt = 0; mt < 4; ++mt) {
      int trb = wm + mt * 16 + hi * 4;
#pragma unroll
      for (int r = 0; r < 4; ++r) {
        int tr = trb + r;
        *(unsigned short*)(Ep + tr * 256 + ((tc * 2) ^ ((tr & 15) << 4))) = f2bf(acc[mt][nt][r] * 0.03125f);
      }
    }
  }
  __syncthreads();
  {
    const int rr = tid >> 1, hf = tid & 1;
    const char* rowp = Ep + rr * 256;
    const int xr = (rr & 15) << 4;
    unsigned short* gp = S + (bT + mb * 128 + rr) * (size_t)T_ + nb * 128;
#pragma unroll
    for (int k = 0; k < 8; ++k) {
      int kk = hf * 8 + k;
      bf16x8 v = *(const bf16x8*)(rowp + ((kk << 4) ^ xr));
      *(bf16x8*)(gp + kk * 8) = v;
    }
  }
}

// ---------- in-place causal row softmax: S(bf16 scores) -> P(bf16 probs) ----------
__global__ __launch_bounds__(256)
void smax_kernel(unsigned short* __restrict__ S) {
  int id = blockIdx.x;
  int b = id & 7, rb = id >> 3;                 // rb 0..511
  int w = threadIdx.x >> 6, lane = threadIdx.x & 63;
  int row = rb * 4 + w;
  unsigned short* rp = S + ((size_t)b * T_ + row) * T_;

  bf16x8 d[4];
#pragma unroll
  for (int j = 0; j < 4; ++j)
    d[j] = *(const bf16x8*)(rp + j * 512 + lane * 8);

  float v[32];
  float mx = -1e30f;
#pragma unroll
  for (int j = 0; j < 4; ++j)
#pragma unroll
    for (int e = 0; e < 8; ++e) {
      int col = j * 512 + lane * 8 + e;
      float f = bf2f((unsigned short)d[j][e]);
      f = (col <= row) ? f : -1e30f;
      v[j * 8 + e] = f;
      mx = fmaxf(mx, f);
    }
#pragma unroll
  for (int msk = 1; msk <= 32; msk <<= 1) mx = fmaxf(mx, __shfl_xor(mx, msk));

  float s = 0.f;
#pragma unroll
  for (int i = 0; i < 32; ++i) {
    v[i] = __expf(v[i] - mx);                   // masked: exp(-1e30 - mx) underflows to 0
    s += v[i];
  }
#pragma unroll
  for (int msk = 1; msk <= 32; msk <<= 1) s += __shfl_xor(s, msk);
  float inv = 1.0f / s;

#pragma unroll
  for (int j = 0; j < 4; ++j) {
    bf16x8 o;
#pragma unroll
    for (int e = 0; e < 8; ++e) o[e] = (short)f2bf(v[j * 8 + e] * inv);
    *(bf16x8*)(rp + j * 512 + lane * 8) = o;
  }
}

// ---------- O = P V, causal (K-range = (mb+1)*128), fp32 out ----------
__global__ __launch_bounds__(256)
void pv_kernel(const unsigned short* __restrict__ P, const unsigned short* __restrict__ vT,
               float* __restrict__ out) {
  __shared__ short Alds[128 * 64];
  __shared__ short Blds[128 * 64];
  int id = blockIdx.x;
  int b = id & 7, u = id >> 3;
  int mb = 15 - (u >> 3);                  // biggest K-range first (load balance)
  int nb = u & 7;                          // d-block 0..7
  const size_t bT = (size_t)b * T_;
  int tid = threadIdx.x, lane = tid & 63, wid = tid >> 6;
  int wm = (wid >> 1) * 64, wn = (wid & 1) * 64;

  f32x4 acc[4][4];
#pragma unroll
  for (int i = 0; i < 4; ++i)
#pragma unroll
    for (int j = 0; j < 4; ++j)
#pragma unroll
      for (int r = 0; r < 4; ++r) acc[i][j][r] = 0.f;

  gemm_core(P + (bT + mb * 128) * (size_t)T_, T_,
            vT + (size_t)(nb * 128) * M_ + bT, M_,
            (mb + 1) * 128, Alds, Blds, lane, wid, acc);

#pragma unroll
  for (int nt = 0; nt < 4; ++nt) {
    int gcol = nb * 128 + wn + nt * 16 + (lane & 15);
#pragma unroll
    for (int mt = 0; mt < 4; ++mt) {
      int grow = mb * 128 + wm + mt * 16 + (lane >> 4) * 4;
#pragma unroll
      for (int r = 0; r < 4; ++r)
        out[(bT + grow + r) * (size_t)H_ + gcol] = acc[mt][nt][r];
    }
  }
}

extern "C" void kernel_launch(void* const* d_in, const int* in_sizes, int n_in,
                              void* d_out, int out_size, void* d_ws, size_t ws_size,
                              hipStream_t stream) {
  const float* x  = (const float*)d_in[0];
  const float* Wq = (const float*)d_in[1];
  const float* bq = (const float*)d_in[2];
  const float* Wk = (const float*)d_in[3];
  const float* bk = (const float*)d_in[4];
  const float* Wv = (const float*)d_in[5];
  const float* bv = (const float*)d_in[6];
  float* out = (float*)d_out;

  unsigned short* ws = (unsigned short*)d_ws;
  unsigned short* xb  = ws;                              // M x E bf16      (32MB)
  unsigned short* wqT = xb  + (size_t)M_ * E_;           // H x E bf16
  unsigned short* wkT = wqT + (size_t)E_ * H_;
  unsigned short* wvT = wkT + (size_t)E_ * H_;
  unsigned short* qb  = wvT + (size_t)E_ * H_;           // M x H bf16      (32MB)
  unsigned short* kbp = qb  + (size_t)M_ * H_;           // M x H bf16
  unsigned short* vTp = kbp + (size_t)M_ * H_;           // H x M bf16 (V transposed)
  unsigned short* Sp  = vTp + (size_t)M_ * H_;           // B x T x T bf16  (67MB) S, then P in-place

  conv_x_kernel<<<(M_ * E_ / 8 + 255) / 256, 256, 0, stream>>>(x, xb, M_ * E_ / 8);
  conv_wT_kernel<<<dim3(32, 32, 3), 256, 0, stream>>>(Wq, Wk, Wv, wqT, wkT, wvT);
  gemm_qkv256_kernel<<<dim3(64, 12), 512, 0, stream>>>(xb, wqT, wkT, wvT, bq, bk, bv, qb, kbp, vTp);
  sgemm_kernel<<<dim3(136 * 8), 256, 0, stream>>>(qb, kbp, Sp);
  smax_kernel<<<dim3(512 * 8), 256, 0, stream>>>(Sp);
  pv_kernel<<<dim3(128 * 8), 256, 0, stream>>>(Sp, vTp, out);
}

// Round 9
// 280.360 us; speedup vs baseline: 1.0603x; 1.0603x over previous
//
#include <hip/hip_runtime.h>
#include <hip/hip_bf16.h>
#include <stdint.h>

#define B_ 8
#define T_ 2048
#define E_ 1024
#define H_ 1024
#define M_ (B_*T_)   // 16384

typedef __attribute__((ext_vector_type(8))) short bf16x8;
typedef __attribute__((ext_vector_type(4))) float f32x4;

__device__ __forceinline__ unsigned short f2bf(float f) {
  union { float f; unsigned int u; } v; v.f = f;
  unsigned int u = v.u;
  unsigned int r = u + 0x7fffu + ((u >> 16) & 1u);   // RNE (inputs finite)
  return (unsigned short)(r >> 16);
}

__device__ __forceinline__ float bf2f(unsigned short s) {
  union { unsigned int u; float f; } v; v.u = ((unsigned int)s) << 16;
  return v.f;
}

// async global->LDS, 16B per lane; LDS dest = wave-uniform base + lane*16
__device__ __forceinline__ void gload_lds16(const void* g, void* l) {
  __builtin_amdgcn_global_load_lds((const __attribute__((address_space(1))) void*)g,
                                   (__attribute__((address_space(3))) void*)l, 16, 0, 0);
}

// swizzled LDS fragment read: row R (stride 128B), 16B-granule G, XOR (R&7) into granule bits
__device__ __forceinline__ bf16x8 lds_read_swz(const short* base, int R, int G) {
  return *(const bf16x8*)((const char*)base + (((R << 7) + (G << 4)) ^ ((R & 7) << 4)));
}

#define MEMFENCE asm volatile("" ::: "memory")
#define BARRIER() do { MEMFENCE; __builtin_amdgcn_s_barrier(); MEMFENCE; } while (0)
#define WAITLGKM() do { asm volatile("s_waitcnt lgkmcnt(0)" ::: "memory"); __builtin_amdgcn_sched_barrier(0); } while (0)

// ---------- convert x (fp32) -> xb (bf16), 8 elems / thread ----------
__global__ void conv_x_kernel(const float* __restrict__ x,
                              unsigned short* __restrict__ xb, int n8) {
  int i = blockIdx.x * blockDim.x + threadIdx.x;
  if (i >= n8) return;
  const float4* src = (const float4*)(x + (size_t)i * 8);
  float4 a = src[0], b = src[1];
  uint4 o;
  o.x = (unsigned)f2bf(a.x) | ((unsigned)f2bf(a.y) << 16);
  o.y = (unsigned)f2bf(a.z) | ((unsigned)f2bf(a.w) << 16);
  o.z = (unsigned)f2bf(b.x) | ((unsigned)f2bf(b.y) << 16);
  o.w = (unsigned)f2bf(b.z) | ((unsigned)f2bf(b.w) << 16);
  *(uint4*)(xb + (size_t)i * 8) = o;
}

// ---------- convert + transpose W (E x H fp32) -> wT (H x E bf16) ----------
__global__ void conv_wT_kernel(const float* __restrict__ W0, const float* __restrict__ W1,
                               const float* __restrict__ W2,
                               unsigned short* __restrict__ T0, unsigned short* __restrict__ T1,
                               unsigned short* __restrict__ T2) {
  __shared__ float tile[32][33];
  const float* W = (blockIdx.z == 0) ? W0 : (blockIdx.z == 1) ? W1 : W2;
  unsigned short* Tt = (blockIdx.z == 0) ? T0 : (blockIdx.z == 1) ? T1 : T2;
  int k0 = blockIdx.x * 32;
  int n0 = blockIdx.y * 32;
  int t = threadIdx.x;
#pragma unroll
  for (int i = 0; i < 4; ++i) {
    int e = t + i * 256; int r = e >> 5, c = e & 31;
    tile[r][c] = W[(size_t)(k0 + r) * H_ + n0 + c];
  }
  __syncthreads();
#pragma unroll
  for (int i = 0; i < 4; ++i) {
    int e = t + i * 256; int r = e >> 5, c = e & 31;   // r = n-local, c = k-local
    Tt[(size_t)(n0 + r) * E_ + k0 + c] = f2bf(tile[c][r]);
  }
}

// ================== 256x256 pipelined 8-phase GEMM (QKV projection) ==================
// 8 waves (2M x 4N), BK=64, double-buffered 128KB LDS. Fragment ds_reads are issued
// ONE PHASE AHEAD, inside the previous MFMA cluster (LDS pipe hidden under MFMA pipe).
// Counted vmcnt placed at phase END (before the barrier) so cross-wave gload->ds_read
// hazards are barrier-ordered. Stage schedule: ph1: (U+1).B-lo; ph3: (U+2).B-hi;
// ph4: (U+2).A-lo+A-hi (A read in ph1+ph3 -> only safe at ph4).

// part: 0=A rows 0-127, 1=A rows 128-255, 2=B rows 0-127, 3=B rows 128-255
__device__ __forceinline__ void stage_part(const unsigned short* Ap, size_t sA,
                                           const unsigned short* Bp, size_t sB,
                                           short* Alds, short* Blds, int V, int part, int tid) {
  const int srow = tid >> 3;                      // 0..63
  const int sg = ((tid & 7) ^ (srow & 7)) * 8;    // pre-swizzled granule (shorts)
  const int w = tid >> 6;
  const unsigned short* g; short* l; size_t gs;
  if (part == 0)      { g = Ap;                    l = Alds;            gs = sA; }
  else if (part == 1) { g = Ap + (size_t)128 * sA; l = Alds + 128 * 64; gs = sA; }
  else if (part == 2) { g = Bp;                    l = Blds;            gs = sB; }
  else                { g = Bp + (size_t)128 * sB; l = Blds + 128 * 64; gs = sB; }
  const unsigned short* gr = g + (size_t)V * 64 + (size_t)srow * gs + sg;
#pragma unroll
  for (int r = 0; r < 2; ++r)
    gload_lds16(gr + (size_t)(r * 64) * gs, l + (r * 64 + w * 8) * 64);
}

__global__ __launch_bounds__(512, 2)
void gemm_qkv256_kernel(const unsigned short* __restrict__ xb,
                        const unsigned short* __restrict__ wqT, const unsigned short* __restrict__ wkT,
                        const unsigned short* __restrict__ wvT,
                        const float* __restrict__ bq, const float* __restrict__ bk,
                        const float* __restrict__ bv,
                        unsigned short* __restrict__ qb, unsigned short* __restrict__ kb,
                        unsigned short* __restrict__ vb) {
  __shared__ short LDSU[4 * 256 * 64];   // 128KB: [A0][A1][B0][B1]; reused by epilogue bounce
  const int which = blockIdx.y >> 2;
  const int ncol0 = (blockIdx.y & 3) * 256;
  const unsigned short* Bt = (which == 0) ? wqT : (which == 1) ? wkT : wvT;
  const float* bias = (which == 0) ? bq : (which == 1) ? bk : bv;
  unsigned short* outp = (which == 0) ? qb : (which == 1) ? kb : vb;
  const int m0 = blockIdx.x * 256;
  const unsigned short* Ap = xb + (size_t)m0 * E_;
  const unsigned short* Bp = Bt + (size_t)ncol0 * E_;
  const int NT = E_ / 64;   // 16

  const int tid = threadIdx.x, lane = tid & 63, w = tid >> 6;
  const int lo = lane & 15, hi = lane >> 4;
  const int wm = (w >> 2) * 128, wn = (w & 3) * 64;

  // hoisted lane-constant LDS read offsets
  const int X0 = (hi << 4) ^ ((lo & 7) << 4);
  const int X1 = ((4 + hi) << 4) ^ ((lo & 7) << 4);
  const int laneA = (wm + lo) << 7;
  const int laneB = (wn + lo) << 7;

  f32x4 acc[8][4];
#pragma unroll
  for (int i = 0; i < 8; ++i)
#pragma unroll
    for (int j = 0; j < 4; ++j)
#pragma unroll
      for (int r = 0; r < 4; ++r) acc[i][j][r] = 0.f;

#define ST(V, P) do { if ((V) < NT) stage_part(Ap, E_, Bp, E_, LDSU + (((V) & 1) * 16384), LDSU + 32768 + (((V) & 1) * 16384), (V), (P), tid); } while (0)

  // fragment registers (all statically indexed)
  bf16x8 aM0[4][2], aM1[4][2], b0[2][2], b1[2][2];

  // ---- prologue: tile0 all 4 parts; tile1 {B-hi, A-lo, A-hi}; drain t0; prefetch ph1 frags ----
  ST(0, 0); ST(0, 1); ST(0, 2); ST(0, 3);
  ST(1, 3); ST(1, 0); ST(1, 1);
  asm volatile("s_waitcnt vmcnt(6)" ::: "memory");
  BARRIER();
  {
    const char* Ac = (const char*)LDSU;
    const char* Bc = (const char*)LDSU + 65536;
#pragma unroll
    for (int mt = 0; mt < 4; ++mt) {
      aM0[mt][0] = *(const bf16x8*)(Ac + laneA + X0 + mt * 2048);
      aM0[mt][1] = *(const bf16x8*)(Ac + laneA + X1 + mt * 2048);
    }
#pragma unroll
    for (int nt = 0; nt < 2; ++nt) {
      b0[nt][0] = *(const bf16x8*)(Bc + laneB + X0 + nt * 2048);
      b0[nt][1] = *(const bf16x8*)(Bc + laneB + X1 + nt * 2048);
    }
  }

  for (int U = 0; U < NT; ++U) {
    const char* Ac = (const char*)LDSU + (U & 1) * 32768;
    const char* Bc = (const char*)LDSU + 65536 + (U & 1) * 32768;
    const char* An = (const char*)LDSU + ((U + 1) & 1) * 32768;
    const char* Bn = (const char*)LDSU + 65536 + ((U + 1) & 1) * 32768;
    const bool pf = (U + 1 < NT);

    // ---------- phase 1: MFMA(aM0,b0) -> acc[0..3][0..1]  ||  read b1 ----------
    WAITLGKM();                         // aM0,b0 ready (issued prev tile ph3/ph4)
    ST(U + 1, 2);                       // stage next B-lo
    __builtin_amdgcn_s_setprio(1);
#pragma unroll
    for (int mt = 0; mt < 2; ++mt)
#pragma unroll
      for (int nt = 0; nt < 2; ++nt)
#pragma unroll
        for (int kt = 0; kt < 2; ++kt)
          acc[mt][nt] = __builtin_amdgcn_mfma_f32_16x16x32_bf16(aM0[mt][kt], b0[nt][kt], acc[mt][nt], 0, 0, 0);
#pragma unroll
    for (int nt = 0; nt < 2; ++nt) {
      b1[nt][0] = *(const bf16x8*)(Bc + laneB + X0 + 4096 + nt * 2048);
      b1[nt][1] = *(const bf16x8*)(Bc + laneB + X1 + 4096 + nt * 2048);
    }
#pragma unroll
    for (int mt = 2; mt < 4; ++mt)
#pragma unroll
      for (int nt = 0; nt < 2; ++nt)
#pragma unroll
        for (int kt = 0; kt < 2; ++kt)
          acc[mt][nt] = __builtin_amdgcn_mfma_f32_16x16x32_bf16(aM0[mt][kt], b0[nt][kt], acc[mt][nt], 0, 0, 0);
    __builtin_amdgcn_s_setprio(0);
    BARRIER();

    // ---------- phase 2: MFMA(aM0,b1) -> acc[0..3][2..3]  ||  read aM1 ----------
    WAITLGKM();                         // b1 ready
    __builtin_amdgcn_s_setprio(1);
#pragma unroll
    for (int mt = 0; mt < 2; ++mt)
#pragma unroll
      for (int nt = 0; nt < 2; ++nt)
#pragma unroll
        for (int kt = 0; kt < 2; ++kt)
          acc[mt][2 + nt] = __builtin_amdgcn_mfma_f32_16x16x32_bf16(aM0[mt][kt], b1[nt][kt], acc[mt][2 + nt], 0, 0, 0);
#pragma unroll
    for (int mt = 0; mt < 4; ++mt) {
      aM1[mt][0] = *(const bf16x8*)(Ac + laneA + X0 + 8192 + mt * 2048);
      aM1[mt][1] = *(const bf16x8*)(Ac + laneA + X1 + 8192 + mt * 2048);
    }
#pragma unroll
    for (int mt = 2; mt < 4; ++mt)
#pragma unroll
      for (int nt = 0; nt < 2; ++nt)
#pragma unroll
        for (int kt = 0; kt < 2; ++kt)
          acc[mt][2 + nt] = __builtin_amdgcn_mfma_f32_16x16x32_bf16(aM0[mt][kt], b1[nt][kt], acc[mt][2 + nt], 0, 0, 0);
    __builtin_amdgcn_s_setprio(0);
    // next-buffer A + B-hi must be landed (all waves) before ph3's prefetch reads them
    if (pf) { if (U + 1 < NT) asm volatile("s_waitcnt vmcnt(2)" ::: "memory"); }
    else    { asm volatile("s_waitcnt vmcnt(0)" ::: "memory"); }
    BARRIER();

    // ---------- phase 3: MFMA(aM1,b0) -> acc[4..7][0..1]  ||  read next aM0 ----------
    WAITLGKM();                         // aM1 ready
    ST(U + 2, 3);                       // stage next-next B-hi
    __builtin_amdgcn_s_setprio(1);
#pragma unroll
    for (int mt = 0; mt < 2; ++mt)
#pragma unroll
      for (int nt = 0; nt < 2; ++nt)
#pragma unroll
        for (int kt = 0; kt < 2; ++kt)
          acc[4 + mt][nt] = __builtin_amdgcn_mfma_f32_16x16x32_bf16(aM1[mt][kt], b0[nt][kt], acc[4 + mt][nt], 0, 0, 0);
    if (pf) {
#pragma unroll
      for (int mt = 0; mt < 4; ++mt) {
        aM0[mt][0] = *(const bf16x8*)(An + laneA + X0 + mt * 2048);
        aM0[mt][1] = *(const bf16x8*)(An + laneA + X1 + mt * 2048);
      }
    }
#pragma unroll
    for (int mt = 2; mt < 4; ++mt)
#pragma unroll
      for (int nt = 0; nt < 2; ++nt)
#pragma unroll
        for (int kt = 0; kt < 2; ++kt)
          acc[4 + mt][nt] = __builtin_amdgcn_mfma_f32_16x16x32_bf16(aM1[mt][kt], b0[nt][kt], acc[4 + mt][nt], 0, 0, 0);
    __builtin_amdgcn_s_setprio(0);
    // next B-lo must be landed before ph4's prefetch reads it
    if (pf) {
      if (U + 2 < NT) asm volatile("s_waitcnt vmcnt(2)" ::: "memory");
      else            asm volatile("s_waitcnt vmcnt(0)" ::: "memory");
    }
    BARRIER();

    // ---------- phase 4: MFMA(aM1,b1) -> acc[4..7][2..3]  ||  read next b0; stage next-next A ----------
    ST(U + 2, 0);
    ST(U + 2, 1);
    __builtin_amdgcn_s_setprio(1);
#pragma unroll
    for (int mt = 0; mt < 2; ++mt)
#pragma unroll
      for (int nt = 0; nt < 2; ++nt)
#pragma unroll
        for (int kt = 0; kt < 2; ++kt)
          acc[4 + mt][2 + nt] = __builtin_amdgcn_mfma_f32_16x16x32_bf16(aM1[mt][kt], b1[nt][kt], acc[4 + mt][2 + nt], 0, 0, 0);
    if (pf) {
#pragma unroll
      for (int nt = 0; nt < 2; ++nt) {
        b0[nt][0] = *(const bf16x8*)(Bn + laneB + X0 + nt * 2048);
        b0[nt][1] = *(const bf16x8*)(Bn + laneB + X1 + nt * 2048);
      }
    }
#pragma unroll
    for (int mt = 2; mt < 4; ++mt)
#pragma unroll
      for (int nt = 0; nt < 2; ++nt)
#pragma unroll
        for (int kt = 0; kt < 2; ++kt)
          acc[4 + mt][2 + nt] = __builtin_amdgcn_mfma_f32_16x16x32_bf16(aM1[mt][kt], b1[nt][kt], acc[4 + mt][2 + nt], 0, 0, 0);
    __builtin_amdgcn_s_setprio(0);
    BARRIER();
  }
#undef ST

  // drain everything before overwriting LDS with the epilogue bounce
  asm volatile("s_waitcnt vmcnt(0) lgkmcnt(0)" ::: "memory");
  BARRIER();

  // ---------- epilogue: bounce acc through LDS for coalesced stores ----------
  char* Ep = (char*)LDSU;   // 128KB = full 256x256 bf16 tile
  if (which == 2) {
    // layout [tc][tr] (column-major -> vT), granule-XOR swizzled within each 512B row
#pragma unroll
    for (int j = 0; j < 4; ++j) {
      int tc = wn + (j >> 1) * 32 + (j & 1) * 16 + lo;
      float bb = bias[ncol0 + tc];
      char* rowp = Ep + tc * 512;
      int xr = (tc & 31) << 4;
#pragma unroll
      for (int i = 0; i < 8; ++i) {
        int trb = wm + (i >> 2) * 64 + (i & 3) * 16 + hi * 4;
#pragma unroll
        for (int r = 0; r < 4; ++r)
          *(unsigned short*)(rowp + (((trb + r) * 2) ^ xr)) = f2bf(acc[i][j][r] + bb);
      }
    }
  } else {
    // layout [tr][tc] (row-major -> q/k)
#pragma unroll
    for (int j = 0; j < 4; ++j) {
      int tc = wn + (j >> 1) * 32 + (j & 1) * 16 + lo;
      float bb = bias[ncol0 + tc];
#pragma unroll
      for (int i = 0; i < 8; ++i) {
        int trb = wm + (i >> 2) * 64 + (i & 3) * 16 + hi * 4;
#pragma unroll
        for (int r = 0; r < 4; ++r) {
          int tr = trb + r;
          *(unsigned short*)(Ep + tr * 512 + ((tc * 2) ^ ((tr & 31) << 4))) = f2bf(acc[i][j][r] + bb);
        }
      }
    }
  }
  __syncthreads();
  {
    const int rr = tid >> 1, hf = tid & 1;
    const char* rowp = Ep + rr * 512;
    const int xr = (rr & 31) << 4;
    unsigned short* gp = (which == 2) ? outp + (size_t)(ncol0 + rr) * M_ + m0
                                      : outp + (size_t)(m0 + rr) * H_ + ncol0;
#pragma unroll
    for (int k = 0; k < 16; ++k) {
      int kk = hf * 16 + k;
      bf16x8 v = *(const bf16x8*)(rowp + ((kk << 4) ^ xr));
      *(bf16x8*)(gp + kk * 8) = v;
    }
  }
}

// ---------- shared 128x128 GEMM core (hoisted swizzle addresses) ----------
__device__ __forceinline__ void gemm_core(const unsigned short* __restrict__ Ap, size_t strideA,
                                          const unsigned short* __restrict__ Bp, size_t strideB,
                                          int kmax, short* Alds, short* Blds,
                                          int lane, int wid, f32x4 acc[4][4]) {
  const int lo = lane & 15, hi = lane >> 4;
  const int wm = (wid >> 1) * 64, wn = (wid & 1) * 64;
  const int srow = wid * 8 + (lane >> 3);
  const int scol = ((lane & 7) ^ (srow & 7)) * 8;
  short* Al = Alds + wid * 512;
  short* Bl = Blds + wid * 512;
  const int X0 = (hi << 4) ^ ((lo & 7) << 4);
  const int X1 = ((4 + hi) << 4) ^ ((lo & 7) << 4);
  const char* pA = (const char*)Alds + ((wm + lo) << 7);
  const char* pB = (const char*)Blds + ((wn + lo) << 7);

  for (int kb0 = 0; kb0 < kmax; kb0 += 64) {
#pragma unroll
    for (int i = 0; i < 4; ++i) {
      gload_lds16(Ap + (size_t)(i * 32 + srow) * strideA + kb0 + scol, Al + i * 2048);
      gload_lds16(Bp + (size_t)(i * 32 + srow) * strideB + kb0 + scol, Bl + i * 2048);
    }
    __syncthreads();
#pragma unroll
    for (int kt = 0; kt < 2; ++kt) {
      const char* ap = kt ? (pA + X1) : (pA + X0);
      const char* bp = kt ? (pB + X1) : (pB + X0);
      bf16x8 af[4], bfr[4];
#pragma unroll
      for (int mt = 0; mt < 4; ++mt) af[mt] = *(const bf16x8*)(ap + mt * 2048);
#pragma unroll
      for (int nt = 0; nt < 4; ++nt) bfr[nt] = *(const bf16x8*)(bp + nt * 2048);
#pragma unroll
      for (int mt = 0; mt < 4; ++mt)
#pragma unroll
        for (int nt = 0; nt < 4; ++nt)
          acc[mt][nt] = __builtin_amdgcn_mfma_f32_16x16x32_bf16(af[mt], bfr[nt], acc[mt][nt], 0, 0, 0);
    }
    __syncthreads();
  }
}

// ---------- S = (Q K^T) * scale, causal lower-tri 128x128 tiles, bf16 out ----------
__global__ __launch_bounds__(256)
void sgemm_kernel(const unsigned short* __restrict__ qb, const unsigned short* __restrict__ kb,
                  unsigned short* __restrict__ S) {
  __shared__ short Alds[128 * 64];
  __shared__ short Blds[128 * 64];
  int id = blockIdx.x;
  int b = id & 7, t = id >> 3;            // batch-fastest: same batch -> same XCD
  int mb = 0;
  while ((mb + 1) * (mb + 2) / 2 <= t) ++mb;
  int nb = t - mb * (mb + 1) / 2;         // nb <= mb (lower triangle)
  const size_t bT = (size_t)b * T_;
  int tid = threadIdx.x, lane = tid & 63, wid = tid >> 6;
  int wm = (wid >> 1) * 64, wn = (wid & 1) * 64;

  f32x4 acc[4][4];
#pragma unroll
  for (int i = 0; i < 4; ++i)
#pragma unroll
    for (int j = 0; j < 4; ++j)
#pragma unroll
      for (int r = 0; r < 4; ++r) acc[i][j][r] = 0.f;

  gemm_core(qb + (bT + mb * 128) * (size_t)H_, H_,
            kb + (bT + nb * 128) * (size_t)H_, H_, H_,
            Alds, Blds, lane, wid, acc);

#pragma unroll
  for (int nt = 0; nt < 4; ++nt) {
    int gcol = nb * 128 + wn + nt * 16 + (lane & 15);
#pragma unroll
    for (int mt = 0; mt < 4; ++mt) {
      int grow = mb * 128 + wm + mt * 16 + (lane >> 4) * 4;
#pragma unroll
      for (int r = 0; r < 4; ++r)
        S[(bT + grow + r) * (size_t)T_ + gcol] = f2bf(acc[mt][nt][r] * 0.03125f);
    }
  }
}

// ---------- in-place causal row softmax: S(bf16 scores) -> P(bf16 probs) ----------
__global__ __launch_bounds__(256)
void smax_kernel(unsigned short* __restrict__ S) {
  int id = blockIdx.x;
  int b = id & 7, rb = id >> 3;                 // rb 0..511
  int w = threadIdx.x >> 6, lane = threadIdx.x & 63;
  int row = rb * 4 + w;
  unsigned short* rp = S + ((size_t)b * T_ + row) * T_;

  bf16x8 d[4];
#pragma unroll
  for (int j = 0; j < 4; ++j)
    d[j] = *(const bf16x8*)(rp + j * 512 + lane * 8);

  float v[32];
  float mx = -1e30f;
#pragma unroll
  for (int j = 0; j < 4; ++j)
#pragma unroll
    for (int e = 0; e < 8; ++e) {
      int col = j * 512 + lane * 8 + e;
      float f = bf2f((unsigned short)d[j][e]);
      f = (col <= row) ? f : -1e30f;
      v[j * 8 + e] = f;
      mx = fmaxf(mx, f);
    }
#pragma unroll
  for (int msk = 1; msk <= 32; msk <<= 1) mx = fmaxf(mx, __shfl_xor(mx, msk));

  float s = 0.f;
#pragma unroll
  for (int i = 0; i < 32; ++i) {
    v[i] = __expf(v[i] - mx);                   // masked: exp(-1e30 - mx) underflows to 0
    s += v[i];
  }
#pragma unroll
  for (int msk = 1; msk <= 32; msk <<= 1) s += __shfl_xor(s, msk);
  float inv = 1.0f / s;

#pragma unroll
  for (int j = 0; j < 4; ++j) {
    bf16x8 o;
#pragma unroll
    for (int e = 0; e < 8; ++e) o[e] = (short)f2bf(v[j * 8 + e] * inv);
    *(bf16x8*)(rp + j * 512 + lane * 8) = o;
  }
}

// ---------- O = P V, causal (K-range = (mb+1)*128), fp32 out ----------
__global__ __launch_bounds__(256)
void pv_kernel(const unsigned short* __restrict__ P, const unsigned short* __restrict__ vT,
               float* __restrict__ out) {
  __shared__ short Alds[128 * 64];
  __shared__ short Blds[128 * 64];
  int id = blockIdx.x;
  int b = id & 7, u = id >> 3;
  int mb = 15 - (u >> 3);                  // biggest K-range first (load balance)
  int nb = u & 7;                          // d-block 0..7
  const size_t bT = (size_t)b * T_;
  int tid = threadIdx.x, lane = tid & 63, wid = tid >> 6;
  int wm = (wid >> 1) * 64, wn = (wid & 1) * 64;

  f32x4 acc[4][4];
#pragma unroll
  for (int i = 0; i < 4; ++i)
#pragma unroll
    for (int j = 0; j < 4; ++j)
#pragma unroll
      for (int r = 0; r < 4; ++r) acc[i][j][r] = 0.f;

  gemm_core(P + (bT + mb * 128) * (size_t)T_, T_,
            vT + (size_t)(nb * 128) * M_ + bT, M_,
            (mb + 1) * 128, Alds, Blds, lane, wid, acc);

#pragma unroll
  for (int nt = 0; nt < 4; ++nt) {
    int gcol = nb * 128 + wn + nt * 16 + (lane & 15);
#pragma unroll
    for (int mt = 0; mt < 4; ++mt) {
      int grow = mb * 128 + wm + mt * 16 + (lane >> 4) * 4;
#pragma unroll
      for (int r = 0; r < 4; ++r)
        out[(bT + grow + r) * (size_t)H_ + gcol] = acc[mt][nt][r];
    }
  }
}

extern "C" void kernel_launch(void* const* d_in, const int* in_sizes, int n_in,
                              void* d_out, int out_size, void* d_ws, size_t ws_size,
                              hipStream_t stream) {
  const float* x  = (const float*)d_in[0];
  const float* Wq = (const float*)d_in[1];
  const float* bq = (const float*)d_in[2];
  const float* Wk = (const float*)d_in[3];
  const float* bk = (const float*)d_in[4];
  const float* Wv = (const float*)d_in[5];
  const float* bv = (const float*)d_in[6];
  float* out = (float*)d_out;

  unsigned short* ws = (unsigned short*)d_ws;
  unsigned short* xb  = ws;                              // M x E bf16      (32MB)
  unsigned short* wqT = xb  + (size_t)M_ * E_;           // H x E bf16
  unsigned short* wkT = wqT + (size_t)E_ * H_;
  unsigned short* wvT = wkT + (size_t)E_ * H_;
  unsigned short* qb  = wvT + (size_t)E_ * H_;           // M x H bf16      (32MB)
  unsigned short* kbp = qb  + (size_t)M_ * H_;           // M x H bf16
  unsigned short* vTp = kbp + (size_t)M_ * H_;           // H x M bf16 (V transposed)
  unsigned short* Sp  = vTp + (size_t)M_ * H_;           // B x T x T bf16  (67MB) S, then P in-place

  conv_x_kernel<<<(M_ * E_ / 8 + 255) / 256, 256, 0, stream>>>(x, xb, M_ * E_ / 8);
  conv_wT_kernel<<<dim3(32, 32, 3), 256, 0, stream>>>(Wq, Wk, Wv, wqT, wkT, wvT);
  gemm_qkv256_kernel<<<dim3(64, 12), 512, 0, stream>>>(xb, wqT, wkT, wvT, bq, bk, bv, qb, kbp, vTp);
  sgemm_kernel<<<dim3(136 * 8), 256, 0, stream>>>(qb, kbp, Sp);
  smax_kernel<<<dim3(512 * 8), 256, 0, stream>>>(Sp);
  pv_kernel<<<dim3(128 * 8), 256, 0, stream>>>(Sp, vTp, out);
}

// Round 10
// 261.062 us; speedup vs baseline: 1.1387x; 1.0739x over previous
//
#include <hip/hip_runtime.h>
#include <hip/hip_bf16.h>
#include <stdint.h>

#define B_ 8
#define T_ 2048
#define E_ 1024
#define H_ 1024
#define M_ (B_*T_)   // 16384

typedef __attribute__((ext_vector_type(8))) short bf16x8;
typedef __attribute__((ext_vector_type(4))) float f32x4;

__device__ __forceinline__ unsigned short f2bf(float f) {
  union { float f; unsigned int u; } v; v.f = f;
  unsigned int u = v.u;
  unsigned int r = u + 0x7fffu + ((u >> 16) & 1u);   // RNE (inputs finite)
  return (unsigned short)(r >> 16);
}

__device__ __forceinline__ float bf2f(unsigned short s) {
  union { unsigned int u; float f; } v; v.u = ((unsigned int)s) << 16;
  return v.f;
}

// async global->LDS, 16B per lane; LDS dest = wave-uniform base + lane*16
__device__ __forceinline__ void gload_lds16(const void* g, void* l) {
  __builtin_amdgcn_global_load_lds((const __attribute__((address_space(1))) void*)g,
                                   (__attribute__((address_space(3))) void*)l, 16, 0, 0);
}

#define MEMFENCE asm volatile("" ::: "memory")
#define BARRIER() do { MEMFENCE; __builtin_amdgcn_s_barrier(); MEMFENCE; } while (0)

// ---------- convert x (fp32) -> xb (bf16), 8 elems / thread ----------
__global__ void conv_x_kernel(const float* __restrict__ x,
                              unsigned short* __restrict__ xb, int n8) {
  int i = blockIdx.x * blockDim.x + threadIdx.x;
  if (i >= n8) return;
  const float4* src = (const float4*)(x + (size_t)i * 8);
  float4 a = src[0], b = src[1];
  uint4 o;
  o.x = (unsigned)f2bf(a.x) | ((unsigned)f2bf(a.y) << 16);
  o.y = (unsigned)f2bf(a.z) | ((unsigned)f2bf(a.w) << 16);
  o.z = (unsigned)f2bf(b.x) | ((unsigned)f2bf(b.y) << 16);
  o.w = (unsigned)f2bf(b.z) | ((unsigned)f2bf(b.w) << 16);
  *(uint4*)(xb + (size_t)i * 8) = o;
}

// ---------- convert + transpose W (E x H fp32) -> wT (H x E bf16) ----------
__global__ void conv_wT_kernel(const float* __restrict__ W0, const float* __restrict__ W1,
                               const float* __restrict__ W2,
                               unsigned short* __restrict__ T0, unsigned short* __restrict__ T1,
                               unsigned short* __restrict__ T2) {
  __shared__ float tile[32][33];
  const float* W = (blockIdx.z == 0) ? W0 : (blockIdx.z == 1) ? W1 : W2;
  unsigned short* Tt = (blockIdx.z == 0) ? T0 : (blockIdx.z == 1) ? T1 : T2;
  int k0 = blockIdx.x * 32;
  int n0 = blockIdx.y * 32;
  int t = threadIdx.x;
#pragma unroll
  for (int i = 0; i < 4; ++i) {
    int e = t + i * 256; int r = e >> 5, c = e & 31;
    tile[r][c] = W[(size_t)(k0 + r) * H_ + n0 + c];
  }
  __syncthreads();
#pragma unroll
  for (int i = 0; i < 4; ++i) {
    int e = t + i * 256; int r = e >> 5, c = e & 31;   // r = n-local, c = k-local
    Tt[(size_t)(n0 + r) * E_ + k0 + c] = f2bf(tile[c][r]);
  }
}

// ================== 256x256 pipelined GEMM (QKV projection) — R9 proven ==================
// part: 0=A rows 0-127, 1=A rows 128-255, 2=B rows 0-127, 3=B rows 128-255
__device__ __forceinline__ void stage_part(const unsigned short* Ap, size_t sA,
                                           const unsigned short* Bp, size_t sB,
                                           short* Alds, short* Blds, int V, int part, int tid) {
  const int srow = tid >> 3;                      // 0..63
  const int sg = ((tid & 7) ^ (srow & 7)) * 8;    // pre-swizzled granule (shorts)
  const int w = tid >> 6;
  const unsigned short* g; short* l; size_t gs;
  if (part == 0)      { g = Ap;                    l = Alds;            gs = sA; }
  else if (part == 1) { g = Ap + (size_t)128 * sA; l = Alds + 128 * 64; gs = sA; }
  else if (part == 2) { g = Bp;                    l = Blds;            gs = sB; }
  else                { g = Bp + (size_t)128 * sB; l = Blds + 128 * 64; gs = sB; }
  const unsigned short* gr = g + (size_t)V * 64 + (size_t)srow * gs + sg;
#pragma unroll
  for (int r = 0; r < 2; ++r)
    gload_lds16(gr + (size_t)(r * 64) * gs, l + (r * 64 + w * 8) * 64);
}

__global__ __launch_bounds__(512, 2)
void gemm_qkv256_kernel(const unsigned short* __restrict__ xb,
                        const unsigned short* __restrict__ wqT, const unsigned short* __restrict__ wkT,
                        const unsigned short* __restrict__ wvT,
                        const float* __restrict__ bq, const float* __restrict__ bk,
                        const float* __restrict__ bv,
                        unsigned short* __restrict__ qb, unsigned short* __restrict__ kb,
                        unsigned short* __restrict__ vb) {
  __shared__ short LDSU[4 * 256 * 64];   // 128KB: [A0][A1][B0][B1]; reused by epilogue bounce
  const int which = blockIdx.y >> 2;
  const int ncol0 = (blockIdx.y & 3) * 256;
  const unsigned short* Bt = (which == 0) ? wqT : (which == 1) ? wkT : wvT;
  const float* bias = (which == 0) ? bq : (which == 1) ? bk : bv;
  unsigned short* outp = (which == 0) ? qb : (which == 1) ? kb : vb;
  const int m0 = blockIdx.x * 256;
  const unsigned short* Ap = xb + (size_t)m0 * E_;
  const unsigned short* Bp = Bt + (size_t)ncol0 * E_;
  const int NT = E_ / 64;   // 16

  const int tid = threadIdx.x, lane = tid & 63, w = tid >> 6;
  const int lo = lane & 15, hi = lane >> 4;
  const int wm = (w >> 2) * 128, wn = (w & 3) * 64;

  const int X0 = (hi << 4) ^ ((lo & 7) << 4);
  const int X1 = ((4 + hi) << 4) ^ ((lo & 7) << 4);
  const int laneA = (wm + lo) << 7;
  const int laneB = (wn + lo) << 7;

  f32x4 acc[8][4];
#pragma unroll
  for (int i = 0; i < 8; ++i)
#pragma unroll
    for (int j = 0; j < 4; ++j)
#pragma unroll
      for (int r = 0; r < 4; ++r) acc[i][j][r] = 0.f;

#define ST(V, P) do { if ((V) < NT) stage_part(Ap, E_, Bp, E_, LDSU + (((V) & 1) * 16384), LDSU + 32768 + (((V) & 1) * 16384), (V), (P), tid); } while (0)
#define WAITLGKM() do { asm volatile("s_waitcnt lgkmcnt(0)" ::: "memory"); __builtin_amdgcn_sched_barrier(0); } while (0)

  ST(0, 0); ST(0, 1); ST(0, 2); ST(0, 3);
  ST(1, 3); ST(1, 0); ST(1, 1);
  asm volatile("s_waitcnt vmcnt(6)" ::: "memory");
  BARRIER();

  bf16x8 aM0[4][2], aM1[4][2], b0[2][2], b1[2][2];
  {
    const char* Ac = (const char*)LDSU;
    const char* Bc = (const char*)LDSU + 65536;
#pragma unroll
    for (int mt = 0; mt < 4; ++mt) {
      aM0[mt][0] = *(const bf16x8*)(Ac + laneA + X0 + mt * 2048);
      aM0[mt][1] = *(const bf16x8*)(Ac + laneA + X1 + mt * 2048);
    }
#pragma unroll
    for (int nt = 0; nt < 2; ++nt) {
      b0[nt][0] = *(const bf16x8*)(Bc + laneB + X0 + nt * 2048);
      b0[nt][1] = *(const bf16x8*)(Bc + laneB + X1 + nt * 2048);
    }
  }

  for (int U = 0; U < NT; ++U) {
    const char* Ac = (const char*)LDSU + (U & 1) * 32768;
    const char* Bc = (const char*)LDSU + 65536 + (U & 1) * 32768;
    const char* An = (const char*)LDSU + ((U + 1) & 1) * 32768;
    const char* Bn = (const char*)LDSU + 65536 + ((U + 1) & 1) * 32768;
    const bool pf = (U + 1 < NT);

    // phase 1: MFMA(aM0,b0) || read b1
    WAITLGKM();
    ST(U + 1, 2);
    __builtin_amdgcn_s_setprio(1);
#pragma unroll
    for (int mt = 0; mt < 2; ++mt)
#pragma unroll
      for (int nt = 0; nt < 2; ++nt)
#pragma unroll
        for (int kt = 0; kt < 2; ++kt)
          acc[mt][nt] = __builtin_amdgcn_mfma_f32_16x16x32_bf16(aM0[mt][kt], b0[nt][kt], acc[mt][nt], 0, 0, 0);
#pragma unroll
    for (int nt = 0; nt < 2; ++nt) {
      b1[nt][0] = *(const bf16x8*)(Bc + laneB + X0 + 4096 + nt * 2048);
      b1[nt][1] = *(const bf16x8*)(Bc + laneB + X1 + 4096 + nt * 2048);
    }
#pragma unroll
    for (int mt = 2; mt < 4; ++mt)
#pragma unroll
      for (int nt = 0; nt < 2; ++nt)
#pragma unroll
        for (int kt = 0; kt < 2; ++kt)
          acc[mt][nt] = __builtin_amdgcn_mfma_f32_16x16x32_bf16(aM0[mt][kt], b0[nt][kt], acc[mt][nt], 0, 0, 0);
    __builtin_amdgcn_s_setprio(0);
    BARRIER();

    // phase 2: MFMA(aM0,b1) || read aM1
    WAITLGKM();
    __builtin_amdgcn_s_setprio(1);
#pragma unroll
    for (int mt = 0; mt < 2; ++mt)
#pragma unroll
      for (int nt = 0; nt < 2; ++nt)
#pragma unroll
        for (int kt = 0; kt < 2; ++kt)
          acc[mt][2 + nt] = __builtin_amdgcn_mfma_f32_16x16x32_bf16(aM0[mt][kt], b1[nt][kt], acc[mt][2 + nt], 0, 0, 0);
#pragma unroll
    for (int mt = 0; mt < 4; ++mt) {
      aM1[mt][0] = *(const bf16x8*)(Ac + laneA + X0 + 8192 + mt * 2048);
      aM1[mt][1] = *(const bf16x8*)(Ac + laneA + X1 + 8192 + mt * 2048);
    }
#pragma unroll
    for (int mt = 2; mt < 4; ++mt)
#pragma unroll
      for (int nt = 0; nt < 2; ++nt)
#pragma unroll
        for (int kt = 0; kt < 2; ++kt)
          acc[mt][2 + nt] = __builtin_amdgcn_mfma_f32_16x16x32_bf16(aM0[mt][kt], b1[nt][kt], acc[mt][2 + nt], 0, 0, 0);
    __builtin_amdgcn_s_setprio(0);
    if (pf) { if (U + 1 < NT) asm volatile("s_waitcnt vmcnt(2)" ::: "memory"); }
    else    { asm volatile("s_waitcnt vmcnt(0)" ::: "memory"); }
    BARRIER();

    // phase 3: MFMA(aM1,b0) || read next aM0
    WAITLGKM();
    ST(U + 2, 3);
    __builtin_amdgcn_s_setprio(1);
#pragma unroll
    for (int mt = 0; mt < 2; ++mt)
#pragma unroll
      for (int nt = 0; nt < 2; ++nt)
#pragma unroll
        for (int kt = 0; kt < 2; ++kt)
          acc[4 + mt][nt] = __builtin_amdgcn_mfma_f32_16x16x32_bf16(aM1[mt][kt], b0[nt][kt], acc[4 + mt][nt], 0, 0, 0);
    if (pf) {
#pragma unroll
      for (int mt = 0; mt < 4; ++mt) {
        aM0[mt][0] = *(const bf16x8*)(An + laneA + X0 + mt * 2048);
        aM0[mt][1] = *(const bf16x8*)(An + laneA + X1 + mt * 2048);
      }
    }
#pragma unroll
    for (int mt = 2; mt < 4; ++mt)
#pragma unroll
      for (int nt = 0; nt < 2; ++nt)
#pragma unroll
        for (int kt = 0; kt < 2; ++kt)
          acc[4 + mt][nt] = __builtin_amdgcn_mfma_f32_16x16x32_bf16(aM1[mt][kt], b0[nt][kt], acc[4 + mt][nt], 0, 0, 0);
    __builtin_amdgcn_s_setprio(0);
    if (pf) {
      if (U + 2 < NT) asm volatile("s_waitcnt vmcnt(2)" ::: "memory");
      else            asm volatile("s_waitcnt vmcnt(0)" ::: "memory");
    }
    BARRIER();

    // phase 4: MFMA(aM1,b1) || read next b0; stage next-next A
    ST(U + 2, 0);
    ST(U + 2, 1);
    __builtin_amdgcn_s_setprio(1);
#pragma unroll
    for (int mt = 0; mt < 2; ++mt)
#pragma unroll
      for (int nt = 0; nt < 2; ++nt)
#pragma unroll
        for (int kt = 0; kt < 2; ++kt)
          acc[4 + mt][2 + nt] = __builtin_amdgcn_mfma_f32_16x16x32_bf16(aM1[mt][kt], b1[nt][kt], acc[4 + mt][2 + nt], 0, 0, 0);
    if (pf) {
#pragma unroll
      for (int nt = 0; nt < 2; ++nt) {
        b0[nt][0] = *(const bf16x8*)(Bn + laneB + X0 + nt * 2048);
        b0[nt][1] = *(const bf16x8*)(Bn + laneB + X1 + nt * 2048);
      }
    }
#pragma unroll
    for (int mt = 2; mt < 4; ++mt)
#pragma unroll
      for (int nt = 0; nt < 2; ++nt)
#pragma unroll
        for (int kt = 0; kt < 2; ++kt)
          acc[4 + mt][2 + nt] = __builtin_amdgcn_mfma_f32_16x16x32_bf16(aM1[mt][kt], b1[nt][kt], acc[4 + mt][2 + nt], 0, 0, 0);
    __builtin_amdgcn_s_setprio(0);
    BARRIER();
  }
#undef ST
#undef WAITLGKM

  asm volatile("s_waitcnt vmcnt(0) lgkmcnt(0)" ::: "memory");
  BARRIER();

  // epilogue: bounce acc through LDS for coalesced stores
  char* Ep = (char*)LDSU;
  if (which == 2) {
#pragma unroll
    for (int j = 0; j < 4; ++j) {
      int tc = wn + (j >> 1) * 32 + (j & 1) * 16 + lo;
      float bb = bias[ncol0 + tc];
      char* rowp = Ep + tc * 512;
      int xr = (tc & 31) << 4;
#pragma unroll
      for (int i = 0; i < 8; ++i) {
        int trb = wm + (i >> 2) * 64 + (i & 3) * 16 + hi * 4;
#pragma unroll
        for (int r = 0; r < 4; ++r)
          *(unsigned short*)(rowp + (((trb + r) * 2) ^ xr)) = f2bf(acc[i][j][r] + bb);
      }
    }
  } else {
#pragma unroll
    for (int j = 0; j < 4; ++j) {
      int tc = wn + (j >> 1) * 32 + (j & 1) * 16 + lo;
      float bb = bias[ncol0 + tc];
#pragma unroll
      for (int i = 0; i < 8; ++i) {
        int trb = wm + (i >> 2) * 64 + (i & 3) * 16 + hi * 4;
#pragma unroll
        for (int r = 0; r < 4; ++r) {
          int tr = trb + r;
          *(unsigned short*)(Ep + tr * 512 + ((tc * 2) ^ ((tr & 31) << 4))) = f2bf(acc[i][j][r] + bb);
        }
      }
    }
  }
  __syncthreads();
  {
    const int rr = tid >> 1, hf = tid & 1;
    const char* rowp = Ep + rr * 512;
    const int xr = (rr & 31) << 4;
    unsigned short* gp = (which == 2) ? outp + (size_t)(ncol0 + rr) * M_ + m0
                                      : outp + (size_t)(m0 + rr) * H_ + ncol0;
#pragma unroll
    for (int k = 0; k < 16; ++k) {
      int kk = hf * 16 + k;
      bf16x8 v = *(const bf16x8*)(rowp + ((kk << 4) ^ xr));
      *(bf16x8*)(gp + kk * 8) = v;
    }
  }
}

// ========== pipelined 128x128 core (4 waves, dbuf 64KB, counted vmcnt, 2 blocks/CU) ==========
// LDS buffer layout (bytes): A0 @0, B0 @16384, A1 @32768, B1 @49152.
__device__ __forceinline__ void stage128(const unsigned short* __restrict__ p, size_t stride,
                                         int kb0, short* buf, int lane, int wid) {
  const int srow = wid * 8 + (lane >> 3);
  const int scol = ((lane & 7) ^ (srow & 7)) * 8;
  short* l = buf + wid * 512;
#pragma unroll
  for (int i = 0; i < 4; ++i)
    gload_lds16(p + (size_t)(i * 32 + srow) * stride + kb0 + scol, l + i * 2048);
}

__device__ __forceinline__ void gemm_core_pipe(const unsigned short* __restrict__ Ap, size_t sA,
                                               const unsigned short* __restrict__ Bp, size_t sB,
                                               int NT, short* L, int lane, int wid, f32x4 acc[4][4]) {
  const int lo = lane & 15, hi = lane >> 4;
  const int wm = (wid >> 1) * 64, wn = (wid & 1) * 64;
  const int X0 = (hi << 4) ^ ((lo & 7) << 4);
  const int X1 = ((4 + hi) << 4) ^ ((lo & 7) << 4);
  const int laneA = (wm + lo) << 7;
  const int laneB = (wn + lo) << 7;

  bf16x8 a[4][2], b0[2][2], b1[2][2];

#define STA_(V) do { if ((V) < NT) stage128(Ap, sA, (V) * 64, L + (((V) & 1) ? 16384 : 0), lane, wid); } while (0)
#define STB_(V) do { if ((V) < NT) stage128(Bp, sB, (V) * 64, L + (((V) & 1) ? 24576 : 8192), lane, wid); } while (0)

  // prologue: A0 B0 A1 B1; wait A0,B0; preload a,b0 of tile 0
  STA_(0); STB_(0); STA_(1); STB_(1);
  asm volatile("s_waitcnt vmcnt(8)" ::: "memory");
  BARRIER();
  __builtin_amdgcn_sched_barrier(0);
  {
    const char* Ac = (const char*)L;
    const char* Bc = (const char*)L + 16384;
#pragma unroll
    for (int mt = 0; mt < 4; ++mt) {
      a[mt][0] = *(const bf16x8*)(Ac + laneA + X0 + mt * 2048);
      a[mt][1] = *(const bf16x8*)(Ac + laneA + X1 + mt * 2048);
    }
#pragma unroll
    for (int nt = 0; nt < 2; ++nt) {
      b0[nt][0] = *(const bf16x8*)(Bc + laneB + X0 + nt * 2048);
      b0[nt][1] = *(const bf16x8*)(Bc + laneB + X1 + nt * 2048);
    }
    asm volatile("s_waitcnt lgkmcnt(0)" ::: "memory");
    __builtin_amdgcn_sched_barrier(0);
  }

  for (int U = 0; U < NT; ++U) {
    const char* Bc = (const char*)L + 16384 + (U & 1) * 32768;
    const char* An = (const char*)L + (((U + 1) & 1) ? 32768 : 0);
    const char* Bn = (const char*)L + 16384 + (((U + 1) & 1) ? 32768 : 0);
    const bool pf = (U + 1 < NT);

    // ---- phase 1: MFMA a*b0 -> acc[*][0..1] || read b1 || stage A(U+2) ----
    STA_(U + 2);
    __builtin_amdgcn_s_setprio(1);
#pragma unroll
    for (int mt = 0; mt < 2; ++mt)
#pragma unroll
      for (int nt = 0; nt < 2; ++nt)
#pragma unroll
        for (int kt = 0; kt < 2; ++kt)
          acc[mt][nt] = __builtin_amdgcn_mfma_f32_16x16x32_bf16(a[mt][kt], b0[nt][kt], acc[mt][nt], 0, 0, 0);
#pragma unroll
    for (int nt = 0; nt < 2; ++nt) {
      b1[nt][0] = *(const bf16x8*)(Bc + laneB + X0 + 4096 + nt * 2048);
      b1[nt][1] = *(const bf16x8*)(Bc + laneB + X1 + 4096 + nt * 2048);
    }
#pragma unroll
    for (int mt = 2; mt < 4; ++mt)
#pragma unroll
      for (int nt = 0; nt < 2; ++nt)
#pragma unroll
        for (int kt = 0; kt < 2; ++kt)
          acc[mt][nt] = __builtin_amdgcn_mfma_f32_16x16x32_bf16(a[mt][kt], b0[nt][kt], acc[mt][nt], 0, 0, 0);
    __builtin_amdgcn_s_setprio(0);
    asm volatile("s_waitcnt lgkmcnt(0)" ::: "memory");   // drain my ds_reads before releasing overwriters
    if (U + 2 < NT) asm volatile("s_waitcnt vmcnt(4)" ::: "memory");   // A(U+1),B(U+1) landed
    else            asm volatile("s_waitcnt vmcnt(0)" ::: "memory");
    BARRIER();
    __builtin_amdgcn_sched_barrier(0);

    // ---- phase 2: MFMA a*b1 -> acc[*][2..3] || read next a,b0 || stage B(U+2) ----
    STB_(U + 2);
    __builtin_amdgcn_s_setprio(1);
#pragma unroll
    for (int mt = 0; mt < 2; ++mt)
#pragma unroll
      for (int nt = 0; nt < 2; ++nt)
#pragma unroll
        for (int kt = 0; kt < 2; ++kt)
          acc[mt][2 + nt] = __builtin_amdgcn_mfma_f32_16x16x32_bf16(a[mt][kt], b1[nt][kt], acc[mt][2 + nt], 0, 0, 0);
    if (pf) {
      // overwrite a[0..1] (already consumed) + b0 (not used this phase)
#pragma unroll
      for (int mt = 0; mt < 2; ++mt) {
        a[mt][0] = *(const bf16x8*)(An + laneA + X0 + mt * 2048);
        a[mt][1] = *(const bf16x8*)(An + laneA + X1 + mt * 2048);
      }
#pragma unroll
      for (int nt = 0; nt < 2; ++nt) {
        b0[nt][0] = *(const bf16x8*)(Bn + laneB + X0 + nt * 2048);
        b0[nt][1] = *(const bf16x8*)(Bn + laneB + X1 + nt * 2048);
      }
    }
#pragma unroll
    for (int mt = 2; mt < 4; ++mt)
#pragma unroll
      for (int nt = 0; nt < 2; ++nt)
#pragma unroll
        for (int kt = 0; kt < 2; ++kt)
          acc[mt][2 + nt] = __builtin_amdgcn_mfma_f32_16x16x32_bf16(a[mt][kt], b1[nt][kt], acc[mt][2 + nt], 0, 0, 0);
    if (pf) {
#pragma unroll
      for (int mt = 2; mt < 4; ++mt) {
        a[mt][0] = *(const bf16x8*)(An + laneA + X0 + mt * 2048);
        a[mt][1] = *(const bf16x8*)(An + laneA + X1 + mt * 2048);
      }
    }
    __builtin_amdgcn_s_setprio(0);
    asm volatile("s_waitcnt lgkmcnt(0)" ::: "memory");
    BARRIER();
    __builtin_amdgcn_sched_barrier(0);
  }
#undef STA_
#undef STB_
}

// ---------- S = (Q K^T) * scale, causal lower-tri 128x128 tiles, bf16 out ----------
__global__ __launch_bounds__(256, 2)
void sgemm_kernel(const unsigned short* __restrict__ qb, const unsigned short* __restrict__ kb,
                  unsigned short* __restrict__ S) {
  __shared__ short L[32768];   // 64KB double-buffered
  int id = blockIdx.x;
  int b = id & 7, t = id >> 3;            // batch-fastest: same batch -> same XCD
  int mb = 0;
  while ((mb + 1) * (mb + 2) / 2 <= t) ++mb;
  int nb = t - mb * (mb + 1) / 2;         // nb <= mb (lower triangle)
  const size_t bT = (size_t)b * T_;
  int tid = threadIdx.x, lane = tid & 63, wid = tid >> 6;
  int wm = (wid >> 1) * 64, wn = (wid & 1) * 64;

  f32x4 acc[4][4];
#pragma unroll
  for (int i = 0; i < 4; ++i)
#pragma unroll
    for (int j = 0; j < 4; ++j)
#pragma unroll
      for (int r = 0; r < 4; ++r) acc[i][j][r] = 0.f;

  gemm_core_pipe(qb + (bT + mb * 128) * (size_t)H_, H_,
                 kb + (bT + nb * 128) * (size_t)H_, H_, H_ / 64,
                 L, lane, wid, acc);

#pragma unroll
  for (int nt = 0; nt < 4; ++nt) {
    int gcol = nb * 128 + wn + nt * 16 + (lane & 15);
#pragma unroll
    for (int mt = 0; mt < 4; ++mt) {
      int grow = mb * 128 + wm + mt * 16 + (lane >> 4) * 4;
#pragma unroll
      for (int r = 0; r < 4; ++r)
        S[(bT + grow + r) * (size_t)T_ + gcol] = f2bf(acc[mt][nt][r] * 0.03125f);
    }
  }
}

// ---------- in-place causal row softmax: S(bf16 scores) -> P(bf16 probs) ----------
__global__ __launch_bounds__(256)
void smax_kernel(unsigned short* __restrict__ S) {
  int id = blockIdx.x;
  int b = id & 7, rb = id >> 3;                 // rb 0..511
  int w = threadIdx.x >> 6, lane = threadIdx.x & 63;
  int row = rb * 4 + w;
  unsigned short* rp = S + ((size_t)b * T_ + row) * T_;

  bf16x8 d[4];
#pragma unroll
  for (int j = 0; j < 4; ++j)
    d[j] = *(const bf16x8*)(rp + j * 512 + lane * 8);

  float v[32];
  float mx = -1e30f;
#pragma unroll
  for (int j = 0; j < 4; ++j)
#pragma unroll
    for (int e = 0; e < 8; ++e) {
      int col = j * 512 + lane * 8 + e;
      float f = bf2f((unsigned short)d[j][e]);
      f = (col <= row) ? f : -1e30f;
      v[j * 8 + e] = f;
      mx = fmaxf(mx, f);
    }
#pragma unroll
  for (int msk = 1; msk <= 32; msk <<= 1) mx = fmaxf(mx, __shfl_xor(mx, msk));

  float s = 0.f;
#pragma unroll
  for (int i = 0; i < 32; ++i) {
    v[i] = __expf(v[i] - mx);                   // masked: exp(-1e30 - mx) underflows to 0
    s += v[i];
  }
#pragma unroll
  for (int msk = 1; msk <= 32; msk <<= 1) s += __shfl_xor(s, msk);
  float inv = 1.0f / s;

#pragma unroll
  for (int j = 0; j < 4; ++j) {
    bf16x8 o;
#pragma unroll
    for (int e = 0; e < 8; ++e) o[e] = (short)f2bf(v[j * 8 + e] * inv);
    *(bf16x8*)(rp + j * 512 + lane * 8) = o;
  }
}

// ---------- O = P V, causal (K-range = (mb+1)*128), fp32 out ----------
__global__ __launch_bounds__(256, 2)
void pv_kernel(const unsigned short* __restrict__ P, const unsigned short* __restrict__ vT,
               float* __restrict__ out) {
  __shared__ short L[32768];   // 64KB double-buffered
  int id = blockIdx.x;
  int b = id & 7, u = id >> 3;
  int mb = 15 - (u >> 3);                  // biggest K-range first (load balance)
  int nb = u & 7;                          // d-block 0..7
  const size_t bT = (size_t)b * T_;
  int tid = threadIdx.x, lane = tid & 63, wid = tid >> 6;
  int wm = (wid >> 1) * 64, wn = (wid & 1) * 64;

  f32x4 acc[4][4];
#pragma unroll
  for (int i = 0; i < 4; ++i)
#pragma unroll
    for (int j = 0; j < 4; ++j)
#pragma unroll
      for (int r = 0; r < 4; ++r) acc[i][j][r] = 0.f;

  gemm_core_pipe(P + (bT + mb * 128) * (size_t)T_, T_,
                 vT + (size_t)(nb * 128) * M_ + bT, M_,
                 (mb + 1) * 2, L, lane, wid, acc);

#pragma unroll
  for (int nt = 0; nt < 4; ++nt) {
    int gcol = nb * 128 + wn + nt * 16 + (lane & 15);
#pragma unroll
    for (int mt = 0; mt < 4; ++mt) {
      int grow = mb * 128 + wm + mt * 16 + (lane >> 4) * 4;
#pragma unroll
      for (int r = 0; r < 4; ++r)
        out[(bT + grow + r) * (size_t)H_ + gcol] = acc[mt][nt][r];
    }
  }
}

extern "C" void kernel_launch(void* const* d_in, const int* in_sizes, int n_in,
                              void* d_out, int out_size, void* d_ws, size_t ws_size,
                              hipStream_t stream) {
  const float* x  = (const float*)d_in[0];
  const float* Wq = (const float*)d_in[1];
  const float* bq = (const float*)d_in[2];
  const float* Wk = (const float*)d_in[3];
  const float* bk = (const float*)d_in[4];
  const float* Wv = (const float*)d_in[5];
  const float* bv = (const float*)d_in[6];
  float* out = (float*)d_out;

  unsigned short* ws = (unsigned short*)d_ws;
  unsigned short* xb  = ws;                              // M x E bf16      (32MB)
  unsigned short* wqT = xb  + (size_t)M_ * E_;           // H x E bf16
  unsigned short* wkT = wqT + (size_t)E_ * H_;
  unsigned short* wvT = wkT + (size_t)E_ * H_;
  unsigned short* qb  = wvT + (size_t)E_ * H_;           // M x H bf16      (32MB)
  unsigned short* kbp = qb  + (size_t)M_ * H_;           // M x H bf16
  unsigned short* vTp = kbp + (size_t)M_ * H_;           // H x M bf16 (V transposed)
  unsigned short* Sp  = vTp + (size_t)M_ * H_;           // B x T x T bf16  (67MB) S, then P in-place

  conv_x_kernel<<<(M_ * E_ / 8 + 255) / 256, 256, 0, stream>>>(x, xb, M_ * E_ / 8);
  conv_wT_kernel<<<dim3(32, 32, 3), 256, 0, stream>>>(Wq, Wk, Wv, wqT, wkT, wvT);
  gemm_qkv256_kernel<<<dim3(64, 12), 512, 0, stream>>>(xb, wqT, wkT, wvT, bq, bk, bv, qb, kbp, vTp);
  sgemm_kernel<<<dim3(136 * 8), 256, 0, stream>>>(qb, kbp, Sp);
  smax_kernel<<<dim3(512 * 8), 256, 0, stream>>>(Sp);
  pv_kernel<<<dim3(128 * 8), 256, 0, stream>>>(Sp, vTp, out);
}

// Round 12
// 252.091 us; speedup vs baseline: 1.1792x; 1.0356x over previous
//
#include <hip/hip_runtime.h>
#include <hip/hip_bf16.h>
#include <stdint.h>

#define B_ 8
#define T_ 2048
#define E_ 1024
#define H_ 1024
#define M_ (B_*T_)   // 16384

typedef __attribute__((ext_vector_type(8))) short bf16x8;
typedef __attribute__((ext_vector_type(4))) float f32x4;

__device__ __forceinline__ unsigned short f2bf(float f) {
  union { float f; unsigned int u; } v; v.f = f;
  unsigned int u = v.u;
  unsigned int r = u + 0x7fffu + ((u >> 16) & 1u);   // RNE (inputs finite)
  return (unsigned short)(r >> 16);
}

__device__ __forceinline__ float bf2f(unsigned short s) {
  union { unsigned int u; float f; } v; v.u = ((unsigned int)s) << 16;
  return v.f;
}

// async global->LDS, 16B per lane; LDS dest = wave-uniform base + lane*16
__device__ __forceinline__ void gload_lds16(const void* g, void* l) {
  __builtin_amdgcn_global_load_lds((const __attribute__((address_space(1))) void*)g,
                                   (__attribute__((address_space(3))) void*)l, 16, 0, 0);
}

#define MEMFENCE asm volatile("" ::: "memory")
#define BARRIER() do { MEMFENCE; __builtin_amdgcn_s_barrier(); MEMFENCE; } while (0)

// ---------- convert x (fp32) -> xb (bf16), 8 elems / thread ----------
__global__ void conv_x_kernel(const float* __restrict__ x,
                              unsigned short* __restrict__ xb, int n8) {
  int i = blockIdx.x * blockDim.x + threadIdx.x;
  if (i >= n8) return;
  const float4* src = (const float4*)(x + (size_t)i * 8);
  float4 a = src[0], b = src[1];
  uint4 o;
  o.x = (unsigned)f2bf(a.x) | ((unsigned)f2bf(a.y) << 16);
  o.y = (unsigned)f2bf(a.z) | ((unsigned)f2bf(a.w) << 16);
  o.z = (unsigned)f2bf(b.x) | ((unsigned)f2bf(b.y) << 16);
  o.w = (unsigned)f2bf(b.z) | ((unsigned)f2bf(b.w) << 16);
  *(uint4*)(xb + (size_t)i * 8) = o;
}

// ---------- convert + transpose W (E x H fp32) -> wT (H x E bf16) ----------
__global__ void conv_wT_kernel(const float* __restrict__ W0, const float* __restrict__ W1,
                               const float* __restrict__ W2,
                               unsigned short* __restrict__ T0, unsigned short* __restrict__ T1,
                               unsigned short* __restrict__ T2) {
  __shared__ float tile[32][33];
  const float* W = (blockIdx.z == 0) ? W0 : (blockIdx.z == 1) ? W1 : W2;
  unsigned short* Tt = (blockIdx.z == 0) ? T0 : (blockIdx.z == 1) ? T1 : T2;
  int k0 = blockIdx.x * 32;
  int n0 = blockIdx.y * 32;
  int t = threadIdx.x;
#pragma unroll
  for (int i = 0; i < 4; ++i) {
    int e = t + i * 256; int r = e >> 5, c = e & 31;
    tile[r][c] = W[(size_t)(k0 + r) * H_ + n0 + c];
  }
  __syncthreads();
#pragma unroll
  for (int i = 0; i < 4; ++i) {
    int e = t + i * 256; int r = e >> 5, c = e & 31;   // r = n-local, c = k-local
    Tt[(size_t)(n0 + r) * E_ + k0 + c] = f2bf(tile[c][r]);
  }
}

// ================== 256x256 pipelined GEMM (QKV projection) — R9 schedule (passed 2x) ==================
// part: 0=A rows 0-127, 1=A rows 128-255, 2=B rows 0-127, 3=B rows 128-255
__device__ __forceinline__ void stage_part(const unsigned short* Ap, size_t sA,
                                           const unsigned short* Bp, size_t sB,
                                           short* Alds, short* Blds, int V, int part, int tid) {
  const int srow = tid >> 3;                      // 0..63
  const int sg = ((tid & 7) ^ (srow & 7)) * 8;    // pre-swizzled granule (shorts)
  const int w = tid >> 6;
  const unsigned short* g; short* l; size_t gs;
  if (part == 0)      { g = Ap;                    l = Alds;            gs = sA; }
  else if (part == 1) { g = Ap + (size_t)128 * sA; l = Alds + 128 * 64; gs = sA; }
  else if (part == 2) { g = Bp;                    l = Blds;            gs = sB; }
  else                { g = Bp + (size_t)128 * sB; l = Blds + 128 * 64; gs = sB; }
  const unsigned short* gr = g + (size_t)V * 64 + (size_t)srow * gs + sg;
#pragma unroll
  for (int r = 0; r < 2; ++r)
    gload_lds16(gr + (size_t)(r * 64) * gs, l + (r * 64 + w * 8) * 64);
}

__global__ __launch_bounds__(512, 2)
void gemm_qkv256_kernel(const unsigned short* __restrict__ xb,
                        const unsigned short* __restrict__ wqT, const unsigned short* __restrict__ wkT,
                        const unsigned short* __restrict__ wvT,
                        const float* __restrict__ bq, const float* __restrict__ bk,
                        const float* __restrict__ bv,
                        unsigned short* __restrict__ qb, unsigned short* __restrict__ kb,
                        unsigned short* __restrict__ vb) {
  __shared__ short LDSU[4 * 256 * 64];   // 128KB: [A0][A1][B0][B1]; reused by epilogue bounce
  const int which = blockIdx.y >> 2;
  const int ncol0 = (blockIdx.y & 3) * 256;
  const unsigned short* Bt = (which == 0) ? wqT : (which == 1) ? wkT : wvT;
  const float* bias = (which == 0) ? bq : (which == 1) ? bk : bv;
  unsigned short* outp = (which == 0) ? qb : (which == 1) ? kb : vb;
  const int m0 = blockIdx.x * 256;
  const unsigned short* Ap = xb + (size_t)m0 * E_;
  const unsigned short* Bp = Bt + (size_t)ncol0 * E_;
  const int NT = E_ / 64;   // 16

  const int tid = threadIdx.x, lane = tid & 63, w = tid >> 6;
  const int lo = lane & 15, hi = lane >> 4;
  const int wm = (w >> 2) * 128, wn = (w & 3) * 64;

  const int X0 = (hi << 4) ^ ((lo & 7) << 4);
  const int X1 = ((4 + hi) << 4) ^ ((lo & 7) << 4);
  const int laneA = (wm + lo) << 7;
  const int laneB = (wn + lo) << 7;

  f32x4 acc[8][4];
#pragma unroll
  for (int i = 0; i < 8; ++i)
#pragma unroll
    for (int j = 0; j < 4; ++j)
#pragma unroll
      for (int r = 0; r < 4; ++r) acc[i][j][r] = 0.f;

#define ST(V, P) do { if ((V) < NT) stage_part(Ap, E_, Bp, E_, LDSU + (((V) & 1) * 16384), LDSU + 32768 + (((V) & 1) * 16384), (V), (P), tid); } while (0)
#define WAITLGKM() do { asm volatile("s_waitcnt lgkmcnt(0)" ::: "memory"); __builtin_amdgcn_sched_barrier(0); } while (0)

  ST(0, 0); ST(0, 1); ST(0, 2); ST(0, 3);
  ST(1, 3); ST(1, 0); ST(1, 1);
  asm volatile("s_waitcnt vmcnt(6)" ::: "memory");
  BARRIER();

  bf16x8 aM0[4][2], aM1[4][2], b0[2][2], b1[2][2];
  {
    const char* Ac = (const char*)LDSU;
    const char* Bc = (const char*)LDSU + 65536;
#pragma unroll
    for (int mt = 0; mt < 4; ++mt) {
      aM0[mt][0] = *(const bf16x8*)(Ac + laneA + X0 + mt * 2048);
      aM0[mt][1] = *(const bf16x8*)(Ac + laneA + X1 + mt * 2048);
    }
#pragma unroll
    for (int nt = 0; nt < 2; ++nt) {
      b0[nt][0] = *(const bf16x8*)(Bc + laneB + X0 + nt * 2048);
      b0[nt][1] = *(const bf16x8*)(Bc + laneB + X1 + nt * 2048);
    }
  }

  for (int U = 0; U < NT; ++U) {
    const char* Ac = (const char*)LDSU + (U & 1) * 32768;
    const char* Bc = (const char*)LDSU + 65536 + (U & 1) * 32768;
    const char* An = (const char*)LDSU + ((U + 1) & 1) * 32768;
    const char* Bn = (const char*)LDSU + 65536 + ((U + 1) & 1) * 32768;
    const bool pf = (U + 1 < NT);

    // phase 1: MFMA(aM0,b0) || read b1
    WAITLGKM();
    ST(U + 1, 2);
    __builtin_amdgcn_s_setprio(1);
#pragma unroll
    for (int mt = 0; mt < 2; ++mt)
#pragma unroll
      for (int nt = 0; nt < 2; ++nt)
#pragma unroll
        for (int kt = 0; kt < 2; ++kt)
          acc[mt][nt] = __builtin_amdgcn_mfma_f32_16x16x32_bf16(aM0[mt][kt], b0[nt][kt], acc[mt][nt], 0, 0, 0);
#pragma unroll
    for (int nt = 0; nt < 2; ++nt) {
      b1[nt][0] = *(const bf16x8*)(Bc + laneB + X0 + 4096 + nt * 2048);
      b1[nt][1] = *(const bf16x8*)(Bc + laneB + X1 + 4096 + nt * 2048);
    }
#pragma unroll
    for (int mt = 2; mt < 4; ++mt)
#pragma unroll
      for (int nt = 0; nt < 2; ++nt)
#pragma unroll
        for (int kt = 0; kt < 2; ++kt)
          acc[mt][nt] = __builtin_amdgcn_mfma_f32_16x16x32_bf16(aM0[mt][kt], b0[nt][kt], acc[mt][nt], 0, 0, 0);
    __builtin_amdgcn_s_setprio(0);
    BARRIER();

    // phase 2: MFMA(aM0,b1) || read aM1
    WAITLGKM();
    __builtin_amdgcn_s_setprio(1);
#pragma unroll
    for (int mt = 0; mt < 2; ++mt)
#pragma unroll
      for (int nt = 0; nt < 2; ++nt)
#pragma unroll
        for (int kt = 0; kt < 2; ++kt)
          acc[mt][2 + nt] = __builtin_amdgcn_mfma_f32_16x16x32_bf16(aM0[mt][kt], b1[nt][kt], acc[mt][2 + nt], 0, 0, 0);
#pragma unroll
    for (int mt = 0; mt < 4; ++mt) {
      aM1[mt][0] = *(const bf16x8*)(Ac + laneA + X0 + 8192 + mt * 2048);
      aM1[mt][1] = *(const bf16x8*)(Ac + laneA + X1 + 8192 + mt * 2048);
    }
#pragma unroll
    for (int mt = 2; mt < 4; ++mt)
#pragma unroll
      for (int nt = 0; nt < 2; ++nt)
#pragma unroll
        for (int kt = 0; kt < 2; ++kt)
          acc[mt][2 + nt] = __builtin_amdgcn_mfma_f32_16x16x32_bf16(aM0[mt][kt], b1[nt][kt], acc[mt][2 + nt], 0, 0, 0);
    __builtin_amdgcn_s_setprio(0);
    if (pf) { if (U + 1 < NT) asm volatile("s_waitcnt vmcnt(2)" ::: "memory"); }
    else    { asm volatile("s_waitcnt vmcnt(0)" ::: "memory"); }
    BARRIER();

    // phase 3: MFMA(aM1,b0) || read next aM0
    WAITLGKM();
    ST(U + 2, 3);
    __builtin_amdgcn_s_setprio(1);
#pragma unroll
    for (int mt = 0; mt < 2; ++mt)
#pragma unroll
      for (int nt = 0; nt < 2; ++nt)
#pragma unroll
        for (int kt = 0; kt < 2; ++kt)
          acc[4 + mt][nt] = __builtin_amdgcn_mfma_f32_16x16x32_bf16(aM1[mt][kt], b0[nt][kt], acc[4 + mt][nt], 0, 0, 0);
    if (pf) {
#pragma unroll
      for (int mt = 0; mt < 4; ++mt) {
        aM0[mt][0] = *(const bf16x8*)(An + laneA + X0 + mt * 2048);
        aM0[mt][1] = *(const bf16x8*)(An + laneA + X1 + mt * 2048);
      }
    }
#pragma unroll
    for (int mt = 2; mt < 4; ++mt)
#pragma unroll
      for (int nt = 0; nt < 2; ++nt)
#pragma unroll
        for (int kt = 0; kt < 2; ++kt)
          acc[4 + mt][nt] = __builtin_amdgcn_mfma_f32_16x16x32_bf16(aM1[mt][kt], b0[nt][kt], acc[4 + mt][nt], 0, 0, 0);
    __builtin_amdgcn_s_setprio(0);
    if (pf) {
      if (U + 2 < NT) asm volatile("s_waitcnt vmcnt(2)" ::: "memory");
      else            asm volatile("s_waitcnt vmcnt(0)" ::: "memory");
    }
    BARRIER();

    // phase 4: MFMA(aM1,b1) || read next b0; stage next-next A
    ST(U + 2, 0);
    ST(U + 2, 1);
    __builtin_amdgcn_s_setprio(1);
#pragma unroll
    for (int mt = 0; mt < 2; ++mt)
#pragma unroll
      for (int nt = 0; nt < 2; ++nt)
#pragma unroll
        for (int kt = 0; kt < 2; ++kt)
          acc[4 + mt][2 + nt] = __builtin_amdgcn_mfma_f32_16x16x32_bf16(aM1[mt][kt], b1[nt][kt], acc[4 + mt][2 + nt], 0, 0, 0);
    if (pf) {
#pragma unroll
      for (int nt = 0; nt < 2; ++nt) {
        b0[nt][0] = *(const bf16x8*)(Bn + laneB + X0 + nt * 2048);
        b0[nt][1] = *(const bf16x8*)(Bn + laneB + X1 + nt * 2048);
      }
    }
#pragma unroll
    for (int mt = 2; mt < 4; ++mt)
#pragma unroll
      for (int nt = 0; nt < 2; ++nt)
#pragma unroll
        for (int kt = 0; kt < 2; ++kt)
          acc[4 + mt][2 + nt] = __builtin_amdgcn_mfma_f32_16x16x32_bf16(aM1[mt][kt], b1[nt][kt], acc[4 + mt][2 + nt], 0, 0, 0);
    __builtin_amdgcn_s_setprio(0);
    BARRIER();
  }
#undef ST
#undef WAITLGKM

  asm volatile("s_waitcnt vmcnt(0) lgkmcnt(0)" ::: "memory");
  BARRIER();

  // epilogue: bounce acc through LDS for coalesced stores
  char* Ep = (char*)LDSU;
  if (which == 2) {
#pragma unroll
    for (int j = 0; j < 4; ++j) {
      int tc = wn + (j >> 1) * 32 + (j & 1) * 16 + lo;
      float bb = bias[ncol0 + tc];
      char* rowp = Ep + tc * 512;
      int xr = (tc & 31) << 4;
#pragma unroll
      for (int i = 0; i < 8; ++i) {
        int trb = wm + (i >> 2) * 64 + (i & 3) * 16 + hi * 4;
#pragma unroll
        for (int r = 0; r < 4; ++r)
          *(unsigned short*)(rowp + (((trb + r) * 2) ^ xr)) = f2bf(acc[i][j][r] + bb);
      }
    }
  } else {
#pragma unroll
    for (int j = 0; j < 4; ++j) {
      int tc = wn + (j >> 1) * 32 + (j & 1) * 16 + lo;
      float bb = bias[ncol0 + tc];
#pragma unroll
      for (int i = 0; i < 8; ++i) {
        int trb = wm + (i >> 2) * 64 + (i & 3) * 16 + hi * 4;
#pragma unroll
        for (int r = 0; r < 4; ++r) {
          int tr = trb + r;
          *(unsigned short*)(Ep + tr * 512 + ((tc * 2) ^ ((tr & 31) << 4))) = f2bf(acc[i][j][r] + bb);
        }
      }
    }
  }
  __syncthreads();
  {
    const int rr = tid >> 1, hf = tid & 1;
    const char* rowp = Ep + rr * 512;
    const int xr = (rr & 31) << 4;
    unsigned short* gp = (which == 2) ? outp + (size_t)(ncol0 + rr) * M_ + m0
                                      : outp + (size_t)(m0 + rr) * H_ + ncol0;
#pragma unroll
    for (int k = 0; k < 16; ++k) {
      int kk = hf * 16 + k;
      bf16x8 v = *(const bf16x8*)(rowp + ((kk << 4) ^ xr));
      *(bf16x8*)(gp + kk * 8) = v;
    }
  }
}

// ========== pipelined 128x128 core (4 waves, dbuf 64KB, counted vmcnt, 2 blocks/CU) ==========
__device__ __forceinline__ void stage128(const unsigned short* __restrict__ p, size_t stride,
                                         int kb0, short* buf, int lane, int wid) {
  const int srow = wid * 8 + (lane >> 3);
  const int scol = ((lane & 7) ^ (srow & 7)) * 8;
  short* l = buf + wid * 512;
#pragma unroll
  for (int i = 0; i < 4; ++i)
    gload_lds16(p + (size_t)(i * 32 + srow) * stride + kb0 + scol, l + i * 2048);
}

__device__ __forceinline__ void gemm_core_pipe(const unsigned short* __restrict__ Ap, size_t sA,
                                               const unsigned short* __restrict__ Bp, size_t sB,
                                               int NT, short* L, int lane, int wid, f32x4 acc[4][4]) {
  const int lo = lane & 15, hi = lane >> 4;
  const int wm = (wid >> 1) * 64, wn = (wid & 1) * 64;
  const int X0 = (hi << 4) ^ ((lo & 7) << 4);
  const int X1 = ((4 + hi) << 4) ^ ((lo & 7) << 4);
  const int laneA = (wm + lo) << 7;
  const int laneB = (wn + lo) << 7;

  bf16x8 a[4][2], b0[2][2], b1[2][2];

#define STA_(V) do { if ((V) < NT) stage128(Ap, sA, (V) * 64, L + (((V) & 1) ? 16384 : 0), lane, wid); } while (0)
#define STB_(V) do { if ((V) < NT) stage128(Bp, sB, (V) * 64, L + (((V) & 1) ? 24576 : 8192), lane, wid); } while (0)

  STA_(0); STB_(0); STA_(1); STB_(1);
  asm volatile("s_waitcnt vmcnt(8)" ::: "memory");
  BARRIER();
  __builtin_amdgcn_sched_barrier(0);
  {
    const char* Ac = (const char*)L;
    const char* Bc = (const char*)L + 16384;
#pragma unroll
    for (int mt = 0; mt < 4; ++mt) {
      a[mt][0] = *(const bf16x8*)(Ac + laneA + X0 + mt * 2048);
      a[mt][1] = *(const bf16x8*)(Ac + laneA + X1 + mt * 2048);
    }
#pragma unroll
    for (int nt = 0; nt < 2; ++nt) {
      b0[nt][0] = *(const bf16x8*)(Bc + laneB + X0 + nt * 2048);
      b0[nt][1] = *(const bf16x8*)(Bc + laneB + X1 + nt * 2048);
    }
    asm volatile("s_waitcnt lgkmcnt(0)" ::: "memory");
    __builtin_amdgcn_sched_barrier(0);
  }

  for (int U = 0; U < NT; ++U) {
    const char* Bc = (const char*)L + 16384 + (U & 1) * 32768;
    const char* An = (const char*)L + (((U + 1) & 1) ? 32768 : 0);
    const char* Bn = (const char*)L + 16384 + (((U + 1) & 1) ? 32768 : 0);
    const bool pf = (U + 1 < NT);

    // phase 1: MFMA a*b0 || read b1 || stage A(U+2)
    STA_(U + 2);
    __builtin_amdgcn_s_setprio(1);
#pragma unroll
    for (int mt = 0; mt < 2; ++mt)
#pragma unroll
      for (int nt = 0; nt < 2; ++nt)
#pragma unroll
        for (int kt = 0; kt < 2; ++kt)
          acc[mt][nt] = __builtin_amdgcn_mfma_f32_16x16x32_bf16(a[mt][kt], b0[nt][kt], acc[mt][nt], 0, 0, 0);
#pragma unroll
    for (int nt = 0; nt < 2; ++nt) {
      b1[nt][0] = *(const bf16x8*)(Bc + laneB + X0 + 4096 + nt * 2048);
      b1[nt][1] = *(const bf16x8*)(Bc + laneB + X1 + 4096 + nt * 2048);
    }
#pragma unroll
    for (int mt = 2; mt < 4; ++mt)
#pragma unroll
      for (int nt = 0; nt < 2; ++nt)
#pragma unroll
        for (int kt = 0; kt < 2; ++kt)
          acc[mt][nt] = __builtin_amdgcn_mfma_f32_16x16x32_bf16(a[mt][kt], b0[nt][kt], acc[mt][nt], 0, 0, 0);
    __builtin_amdgcn_s_setprio(0);
    asm volatile("s_waitcnt lgkmcnt(0)" ::: "memory");
    if (U + 2 < NT) asm volatile("s_waitcnt vmcnt(4)" ::: "memory");
    else            asm volatile("s_waitcnt vmcnt(0)" ::: "memory");
    BARRIER();
    __builtin_amdgcn_sched_barrier(0);

    // phase 2: MFMA a*b1 || read next a,b0 || stage B(U+2)
    STB_(U + 2);
    __builtin_amdgcn_s_setprio(1);
#pragma unroll
    for (int mt = 0; mt < 2; ++mt)
#pragma unroll
      for (int nt = 0; nt < 2; ++nt)
#pragma unroll
        for (int kt = 0; kt < 2; ++kt)
          acc[mt][2 + nt] = __builtin_amdgcn_mfma_f32_16x16x32_bf16(a[mt][kt], b1[nt][kt], acc[mt][2 + nt], 0, 0, 0);
    if (pf) {
#pragma unroll
      for (int mt = 0; mt < 2; ++mt) {
        a[mt][0] = *(const bf16x8*)(An + laneA + X0 + mt * 2048);
        a[mt][1] = *(const bf16x8*)(An + laneA + X1 + mt * 2048);
      }
#pragma unroll
      for (int nt = 0; nt < 2; ++nt) {
        b0[nt][0] = *(const bf16x8*)(Bn + laneB + X0 + nt * 2048);
        b0[nt][1] = *(const bf16x8*)(Bn + laneB + X1 + nt * 2048);
      }
    }
#pragma unroll
    for (int mt = 2; mt < 4; ++mt)
#pragma unroll
      for (int nt = 0; nt < 2; ++nt)
#pragma unroll
        for (int kt = 0; kt < 2; ++kt)
          acc[mt][2 + nt] = __builtin_amdgcn_mfma_f32_16x16x32_bf16(a[mt][kt], b1[nt][kt], acc[mt][2 + nt], 0, 0, 0);
    if (pf) {
#pragma unroll
      for (int mt = 2; mt < 4; ++mt) {
        a[mt][0] = *(const bf16x8*)(An + laneA + X0 + mt * 2048);
        a[mt][1] = *(const bf16x8*)(An + laneA + X1 + mt * 2048);
      }
    }
    __builtin_amdgcn_s_setprio(0);
    asm volatile("s_waitcnt lgkmcnt(0)" ::: "memory");
    BARRIER();
    __builtin_amdgcn_sched_barrier(0);
  }
#undef STA_
#undef STB_
}

// ---------- S = (Q K^T) * scale, causal lower-tri 128x128 tiles, bf16 out ----------
__global__ __launch_bounds__(256, 2)
void sgemm_kernel(const unsigned short* __restrict__ qb, const unsigned short* __restrict__ kb,
                  unsigned short* __restrict__ S) {
  __shared__ short L[32768];   // 64KB double-buffered
  int id = blockIdx.x;
  int b = id & 7, t = id >> 3;            // batch-fastest: same batch -> same XCD
  int mb = 0;
  while ((mb + 1) * (mb + 2) / 2 <= t) ++mb;
  int nb = t - mb * (mb + 1) / 2;         // nb <= mb (lower triangle)
  const size_t bT = (size_t)b * T_;
  int tid = threadIdx.x, lane = tid & 63, wid = tid >> 6;
  int wm = (wid >> 1) * 64, wn = (wid & 1) * 64;

  f32x4 acc[4][4];
#pragma unroll
  for (int i = 0; i < 4; ++i)
#pragma unroll
    for (int j = 0; j < 4; ++j)
#pragma unroll
      for (int r = 0; r < 4; ++r) acc[i][j][r] = 0.f;

  gemm_core_pipe(qb + (bT + mb * 128) * (size_t)H_, H_,
                 kb + (bT + nb * 128) * (size_t)H_, H_, H_ / 64,
                 L, lane, wid, acc);

#pragma unroll
  for (int nt = 0; nt < 4; ++nt) {
    int gcol = nb * 128 + wn + nt * 16 + (lane & 15);
#pragma unroll
    for (int mt = 0; mt < 4; ++mt) {
      int grow = mb * 128 + wm + mt * 16 + (lane >> 4) * 4;
#pragma unroll
      for (int r = 0; r < 4; ++r)
        S[(bT + grow + r) * (size_t)T_ + gcol] = f2bf(acc[mt][nt][r] * 0.03125f);
    }
  }
}

// ---------- in-place causal row softmax: only needed 512-col blocks ----------
// coverage: nj = (row>>9)+1 blocks covers pv's K-range ((row>>7)+1)*128. Biggest rows first.
__global__ __launch_bounds__(256)
void smax_kernel(unsigned short* __restrict__ S) {
  int id = blockIdx.x;
  int b = id & 7, rb = id >> 3;                 // rb 0..511
  int w = threadIdx.x >> 6, lane = threadIdx.x & 63;
  int row = (511 - rb) * 4 + w;                 // biggest rows dispatched first
  unsigned short* rp = S + ((size_t)b * T_ + row) * T_;
  const int nj = (row >> 9) + 1;                // 1..4 column blocks needed

  bf16x8 d0, d1, d2, d3;
  d0 = *(const bf16x8*)(rp + lane * 8);
  if (nj > 1) d1 = *(const bf16x8*)(rp + 512 + lane * 8);
  if (nj > 2) d2 = *(const bf16x8*)(rp + 1024 + lane * 8);
  if (nj > 3) d3 = *(const bf16x8*)(rp + 1536 + lane * 8);

  float v0[8], v1[8], v2[8], v3[8];
  float mx = -1e30f;
#define PROC(VV, DD, BASE) do { \
    _Pragma("unroll") \
    for (int e = 0; e < 8; ++e) { \
      int col = (BASE) + lane * 8 + e; \
      float f = bf2f((unsigned short)DD[e]); \
      f = (col <= row) ? f : -1e30f; \
      VV[e] = f; mx = fmaxf(mx, f); \
    } } while (0)
  PROC(v0, d0, 0);
  if (nj > 1) PROC(v1, d1, 512);
  if (nj > 2) PROC(v2, d2, 1024);
  if (nj > 3) PROC(v3, d3, 1536);
#undef PROC
#pragma unroll
  for (int msk = 1; msk <= 32; msk <<= 1) mx = fmaxf(mx, __shfl_xor(mx, msk));

  float s = 0.f;
#define EXPS(VV) do { \
    _Pragma("unroll") \
    for (int e = 0; e < 8; ++e) { VV[e] = __expf(VV[e] - mx); s += VV[e]; } } while (0)
  EXPS(v0);
  if (nj > 1) EXPS(v1);
  if (nj > 2) EXPS(v2);
  if (nj > 3) EXPS(v3);
#undef EXPS
#pragma unroll
  for (int msk = 1; msk <= 32; msk <<= 1) s += __shfl_xor(s, msk);
  float inv = 1.0f / s;

#define WRB(VV, BASE) do { \
    bf16x8 o; \
    _Pragma("unroll") \
    for (int e = 0; e < 8; ++e) o[e] = (short)f2bf(VV[e] * inv); \
    *(bf16x8*)(rp + (BASE) + lane * 8) = o; } while (0)
  WRB(v0, 0);
  if (nj > 1) WRB(v1, 512);
  if (nj > 2) WRB(v2, 1024);
  if (nj > 3) WRB(v3, 1536);
#undef WRB
}

// ---------- O = P V, causal (K-range = (mb+1)*128), fp32 out ----------
__global__ __launch_bounds__(256, 2)
void pv_kernel(const unsigned short* __restrict__ P, const unsigned short* __restrict__ vT,
               float* __restrict__ out) {
  __shared__ short L[32768];   // 64KB double-buffered
  int id = blockIdx.x;
  int b = id & 7, u = id >> 3;
  int mb = 15 - (u >> 3);                  // biggest K-range first (load balance)
  int nb = u & 7;                          // d-block 0..7
  const size_t bT = (size_t)b * T_;
  int tid = threadIdx.x, lane = tid & 63, wid = tid >> 6;
  int wm = (wid >> 1) * 64, wn = (wid & 1) * 64;

  f32x4 acc[4][4];
#pragma unroll
  for (int i = 0; i < 4; ++i)
#pragma unroll
    for (int j = 0; j < 4; ++j)
#pragma unroll
      for (int r = 0; r < 4; ++r) acc[i][j][r] = 0.f;

  gemm_core_pipe(P + (bT + mb * 128) * (size_t)T_, T_,
                 vT + (size_t)(nb * 128) * M_ + bT, M_,
                 (mb + 1) * 2, L, lane, wid, acc);

#pragma unroll
  for (int nt = 0; nt < 4; ++nt) {
    int gcol = nb * 128 + wn + nt * 16 + (lane & 15);
#pragma unroll
    for (int mt = 0; mt < 4; ++mt) {
      int grow = mb * 128 + wm + mt * 16 + (lane >> 4) * 4;
#pragma unroll
      for (int r = 0; r < 4; ++r)
        out[(bT + grow + r) * (size_t)H_ + gcol] = acc[mt][nt][r];
    }
  }
}

extern "C" void kernel_launch(void* const* d_in, const int* in_sizes, int n_in,
                              void* d_out, int out_size, void* d_ws, size_t ws_size,
                              hipStream_t stream) {
  const float* x  = (const float*)d_in[0];
  const float* Wq = (const float*)d_in[1];
  const float* bq = (const float*)d_in[2];
  const float* Wk = (const float*)d_in[3];
  const float* bk = (const float*)d_in[4];
  const float* Wv = (const float*)d_in[5];
  const float* bv = (const float*)d_in[6];
  float* out = (float*)d_out;

  unsigned short* ws = (unsigned short*)d_ws;
  unsigned short* xb  = ws;                              // M x E bf16      (32MB)
  unsigned short* wqT = xb  + (size_t)M_ * E_;           // H x E bf16
  unsigned short* wkT = wqT + (size_t)E_ * H_;
  unsigned short* wvT = wkT + (size_t)E_ * H_;
  unsigned short* qb  = wvT + (size_t)E_ * H_;           // M x H bf16      (32MB)
  unsigned short* kbp = qb  + (size_t)M_ * H_;           // M x H bf16
  unsigned short* vTp = kbp + (size_t)M_ * H_;           // H x M bf16 (V transposed)
  unsigned short* Sp  = vTp + (size_t)M_ * H_;           // B x T x T bf16  (67MB) S, then P in-place

  conv_x_kernel<<<(M_ * E_ / 8 + 255) / 256, 256, 0, stream>>>(x, xb, M_ * E_ / 8);
  conv_wT_kernel<<<dim3(32, 32, 3), 256, 0, stream>>>(Wq, Wk, Wv, wqT, wkT, wvT);
  gemm_qkv256_kernel<<<dim3(64, 12), 512, 0, stream>>>(xb, wqT, wkT, wvT, bq, bk, bv, qb, kbp, vTp);
  sgemm_kernel<<<dim3(136 * 8), 256, 0, stream>>>(qb, kbp, Sp);
  smax_kernel<<<dim3(512 * 8), 256, 0, stream>>>(Sp);
  pv_kernel<<<dim3(128 * 8), 256, 0, stream>>>(Sp, vTp, out);
}

// Round 13
// 246.690 us; speedup vs baseline: 1.2050x; 1.0219x over previous
//
#include <hip/hip_runtime.h>
#include <hip/hip_bf16.h>
#include <stdint.h>

#define B_ 8
#define T_ 2048
#define E_ 1024
#define H_ 1024
#define M_ (B_*T_)   // 16384

typedef __attribute__((ext_vector_type(8))) short bf16x8;
typedef __attribute__((ext_vector_type(4))) float f32x4;

__device__ __forceinline__ unsigned short f2bf(float f) {
  union { float f; unsigned int u; } v; v.f = f;
  unsigned int u = v.u;
  unsigned int r = u + 0x7fffu + ((u >> 16) & 1u);   // RNE (inputs finite)
  return (unsigned short)(r >> 16);
}

__device__ __forceinline__ float bf2f(unsigned short s) {
  union { unsigned int u; float f; } v; v.u = ((unsigned int)s) << 16;
  return v.f;
}

// async global->LDS, 16B per lane; LDS dest = wave-uniform base + lane*16
__device__ __forceinline__ void gload_lds16(const void* g, void* l) {
  __builtin_amdgcn_global_load_lds((const __attribute__((address_space(1))) void*)g,
                                   (__attribute__((address_space(3))) void*)l, 16, 0, 0);
}

#define MEMFENCE asm volatile("" ::: "memory")
#define BARRIER() do { MEMFENCE; __builtin_amdgcn_s_barrier(); MEMFENCE; } while (0)

// ---------- convert x (fp32) -> xb (bf16), 8 elems / thread ----------
__global__ void conv_x_kernel(const float* __restrict__ x,
                              unsigned short* __restrict__ xb, int n8) {
  int i = blockIdx.x * blockDim.x + threadIdx.x;
  if (i >= n8) return;
  const float4* src = (const float4*)(x + (size_t)i * 8);
  float4 a = src[0], b = src[1];
  uint4 o;
  o.x = (unsigned)f2bf(a.x) | ((unsigned)f2bf(a.y) << 16);
  o.y = (unsigned)f2bf(a.z) | ((unsigned)f2bf(a.w) << 16);
  o.z = (unsigned)f2bf(b.x) | ((unsigned)f2bf(b.y) << 16);
  o.w = (unsigned)f2bf(b.z) | ((unsigned)f2bf(b.w) << 16);
  *(uint4*)(xb + (size_t)i * 8) = o;
}

// ---------- convert + transpose W (E x H fp32) -> wT (H x E bf16) ----------
__global__ void conv_wT_kernel(const float* __restrict__ W0, const float* __restrict__ W1,
                               const float* __restrict__ W2,
                               unsigned short* __restrict__ T0, unsigned short* __restrict__ T1,
                               unsigned short* __restrict__ T2) {
  __shared__ float tile[32][33];
  const float* W = (blockIdx.z == 0) ? W0 : (blockIdx.z == 1) ? W1 : W2;
  unsigned short* Tt = (blockIdx.z == 0) ? T0 : (blockIdx.z == 1) ? T1 : T2;
  int k0 = blockIdx.x * 32;
  int n0 = blockIdx.y * 32;
  int t = threadIdx.x;
#pragma unroll
  for (int i = 0; i < 4; ++i) {
    int e = t + i * 256; int r = e >> 5, c = e & 31;
    tile[r][c] = W[(size_t)(k0 + r) * H_ + n0 + c];
  }
  __syncthreads();
#pragma unroll
  for (int i = 0; i < 4; ++i) {
    int e = t + i * 256; int r = e >> 5, c = e & 31;   // r = n-local, c = k-local
    Tt[(size_t)(n0 + r) * E_ + k0 + c] = f2bf(tile[c][r]);
  }
}

// ========== pipelined 128x128 core (4 waves, dbuf 64KB, counted vmcnt, 2 blocks/CU) ==========
// LDS buffer layout (bytes): A0 @0, B0 @16384, A1 @32768, B1 @49152.
__device__ __forceinline__ void stage128(const unsigned short* __restrict__ p, size_t stride,
                                         int kb0, short* buf, int lane, int wid) {
  const int srow = wid * 8 + (lane >> 3);
  const int scol = ((lane & 7) ^ (srow & 7)) * 8;
  short* l = buf + wid * 512;
#pragma unroll
  for (int i = 0; i < 4; ++i)
    gload_lds16(p + (size_t)(i * 32 + srow) * stride + kb0 + scol, l + i * 2048);
}

__device__ __forceinline__ void gemm_core_pipe(const unsigned short* __restrict__ Ap, size_t sA,
                                               const unsigned short* __restrict__ Bp, size_t sB,
                                               int NT, short* L, int lane, int wid, f32x4 acc[4][4]) {
  const int lo = lane & 15, hi = lane >> 4;
  const int wm = (wid >> 1) * 64, wn = (wid & 1) * 64;
  const int X0 = (hi << 4) ^ ((lo & 7) << 4);
  const int X1 = ((4 + hi) << 4) ^ ((lo & 7) << 4);
  const int laneA = (wm + lo) << 7;
  const int laneB = (wn + lo) << 7;

  bf16x8 a[4][2], b0[2][2], b1[2][2];

#define STA_(V) do { if ((V) < NT) stage128(Ap, sA, (V) * 64, L + (((V) & 1) ? 16384 : 0), lane, wid); } while (0)
#define STB_(V) do { if ((V) < NT) stage128(Bp, sB, (V) * 64, L + (((V) & 1) ? 24576 : 8192), lane, wid); } while (0)

  STA_(0); STB_(0); STA_(1); STB_(1);
  asm volatile("s_waitcnt vmcnt(8)" ::: "memory");
  BARRIER();
  __builtin_amdgcn_sched_barrier(0);
  {
    const char* Ac = (const char*)L;
    const char* Bc = (const char*)L + 16384;
#pragma unroll
    for (int mt = 0; mt < 4; ++mt) {
      a[mt][0] = *(const bf16x8*)(Ac + laneA + X0 + mt * 2048);
      a[mt][1] = *(const bf16x8*)(Ac + laneA + X1 + mt * 2048);
    }
#pragma unroll
    for (int nt = 0; nt < 2; ++nt) {
      b0[nt][0] = *(const bf16x8*)(Bc + laneB + X0 + nt * 2048);
      b0[nt][1] = *(const bf16x8*)(Bc + laneB + X1 + nt * 2048);
    }
    asm volatile("s_waitcnt lgkmcnt(0)" ::: "memory");
    __builtin_amdgcn_sched_barrier(0);
  }

  for (int U = 0; U < NT; ++U) {
    const char* Bc = (const char*)L + 16384 + (U & 1) * 32768;
    const char* An = (const char*)L + (((U + 1) & 1) ? 32768 : 0);
    const char* Bn = (const char*)L + 16384 + (((U + 1) & 1) ? 32768 : 0);
    const bool pf = (U + 1 < NT);

    // phase 1: MFMA a*b0 || read b1 || stage A(U+2)
    STA_(U + 2);
    __builtin_amdgcn_s_setprio(1);
#pragma unroll
    for (int mt = 0; mt < 2; ++mt)
#pragma unroll
      for (int nt = 0; nt < 2; ++nt)
#pragma unroll
        for (int kt = 0; kt < 2; ++kt)
          acc[mt][nt] = __builtin_amdgcn_mfma_f32_16x16x32_bf16(a[mt][kt], b0[nt][kt], acc[mt][nt], 0, 0, 0);
#pragma unroll
    for (int nt = 0; nt < 2; ++nt) {
      b1[nt][0] = *(const bf16x8*)(Bc + laneB + X0 + 4096 + nt * 2048);
      b1[nt][1] = *(const bf16x8*)(Bc + laneB + X1 + 4096 + nt * 2048);
    }
#pragma unroll
    for (int mt = 2; mt < 4; ++mt)
#pragma unroll
      for (int nt = 0; nt < 2; ++nt)
#pragma unroll
        for (int kt = 0; kt < 2; ++kt)
          acc[mt][nt] = __builtin_amdgcn_mfma_f32_16x16x32_bf16(a[mt][kt], b0[nt][kt], acc[mt][nt], 0, 0, 0);
    __builtin_amdgcn_s_setprio(0);
    asm volatile("s_waitcnt lgkmcnt(0)" ::: "memory");
    if (U + 2 < NT) asm volatile("s_waitcnt vmcnt(4)" ::: "memory");
    else            asm volatile("s_waitcnt vmcnt(0)" ::: "memory");
    BARRIER();
    __builtin_amdgcn_sched_barrier(0);

    // phase 2: MFMA a*b1 || read next a,b0 || stage B(U+2)
    STB_(U + 2);
    __builtin_amdgcn_s_setprio(1);
#pragma unroll
    for (int mt = 0; mt < 2; ++mt)
#pragma unroll
      for (int nt = 0; nt < 2; ++nt)
#pragma unroll
        for (int kt = 0; kt < 2; ++kt)
          acc[mt][2 + nt] = __builtin_amdgcn_mfma_f32_16x16x32_bf16(a[mt][kt], b1[nt][kt], acc[mt][2 + nt], 0, 0, 0);
    if (pf) {
#pragma unroll
      for (int mt = 0; mt < 2; ++mt) {
        a[mt][0] = *(const bf16x8*)(An + laneA + X0 + mt * 2048);
        a[mt][1] = *(const bf16x8*)(An + laneA + X1 + mt * 2048);
      }
#pragma unroll
      for (int nt = 0; nt < 2; ++nt) {
        b0[nt][0] = *(const bf16x8*)(Bn + laneB + X0 + nt * 2048);
        b0[nt][1] = *(const bf16x8*)(Bn + laneB + X1 + nt * 2048);
      }
    }
#pragma unroll
    for (int mt = 2; mt < 4; ++mt)
#pragma unroll
      for (int nt = 0; nt < 2; ++nt)
#pragma unroll
        for (int kt = 0; kt < 2; ++kt)
          acc[mt][2 + nt] = __builtin_amdgcn_mfma_f32_16x16x32_bf16(a[mt][kt], b1[nt][kt], acc[mt][2 + nt], 0, 0, 0);
    if (pf) {
#pragma unroll
      for (int mt = 2; mt < 4; ++mt) {
        a[mt][0] = *(const bf16x8*)(An + laneA + X0 + mt * 2048);
        a[mt][1] = *(const bf16x8*)(An + laneA + X1 + mt * 2048);
      }
    }
    __builtin_amdgcn_s_setprio(0);
    asm volatile("s_waitcnt lgkmcnt(0)" ::: "memory");
    BARRIER();
    __builtin_amdgcn_sched_barrier(0);
  }
#undef STA_
#undef STB_
}

// ---------- fused QKV GEMM on the pipelined 128x128 core ----------
// grid: (128 M-tiles, 24 = which*8 + n-tile). 3072 blocks = exactly 6 waves @2/CU.
__global__ __launch_bounds__(256, 2)
void gemm_qkv_kernel(const unsigned short* __restrict__ xb,
                     const unsigned short* __restrict__ wqT, const unsigned short* __restrict__ wkT,
                     const unsigned short* __restrict__ wvT,
                     const float* __restrict__ bq, const float* __restrict__ bk,
                     const float* __restrict__ bv,
                     unsigned short* __restrict__ qb, unsigned short* __restrict__ kb,
                     unsigned short* __restrict__ vb) {
  __shared__ short L[32768];   // 64KB double-buffered
  const int which = blockIdx.y >> 3;
  const int ncol0 = (blockIdx.y & 7) * 128;
  const unsigned short* Bt = (which == 0) ? wqT : (which == 1) ? wkT : wvT;
  const float* bias = (which == 0) ? bq : (which == 1) ? bk : bv;
  unsigned short* outp = (which == 0) ? qb : (which == 1) ? kb : vb;
  const int m0 = blockIdx.x * 128;
  int tid = threadIdx.x, lane = tid & 63, wid = tid >> 6;
  int wm = (wid >> 1) * 64, wn = (wid & 1) * 64;

  f32x4 acc[4][4];
#pragma unroll
  for (int i = 0; i < 4; ++i)
#pragma unroll
    for (int j = 0; j < 4; ++j)
#pragma unroll
      for (int r = 0; r < 4; ++r) acc[i][j][r] = 0.f;

  gemm_core_pipe(xb + (size_t)m0 * E_, E_,
                 Bt + (size_t)ncol0 * E_, E_, E_ / 64,
                 L, lane, wid, acc);

  if (which == 2) {
    // transposed write: vT[d = gcol][m = grow..grow+3], 8B packed
#pragma unroll
    for (int nt = 0; nt < 4; ++nt) {
      int gcol = ncol0 + wn + nt * 16 + (lane & 15);
      float bb = bias[gcol];
#pragma unroll
      for (int mt = 0; mt < 4; ++mt) {
        int grow = m0 + wm + mt * 16 + (lane >> 4) * 4;
        ushort4 o;
        o.x = f2bf(acc[mt][nt][0] + bb);
        o.y = f2bf(acc[mt][nt][1] + bb);
        o.z = f2bf(acc[mt][nt][2] + bb);
        o.w = f2bf(acc[mt][nt][3] + bb);
        *(ushort4*)(outp + (size_t)gcol * M_ + grow) = o;
      }
    }
  } else {
#pragma unroll
    for (int nt = 0; nt < 4; ++nt) {
      int gcol = ncol0 + wn + nt * 16 + (lane & 15);
      float bb = bias[gcol];
#pragma unroll
      for (int mt = 0; mt < 4; ++mt) {
        int grow = m0 + wm + mt * 16 + (lane >> 4) * 4;
#pragma unroll
        for (int r = 0; r < 4; ++r)
          outp[(size_t)(grow + r) * H_ + gcol] = f2bf(acc[mt][nt][r] + bb);
      }
    }
  }
}

// ---------- S = (Q K^T) * scale, causal lower-tri 128x128 tiles, bf16 out ----------
__global__ __launch_bounds__(256, 2)
void sgemm_kernel(const unsigned short* __restrict__ qb, const unsigned short* __restrict__ kb,
                  unsigned short* __restrict__ S) {
  __shared__ short L[32768];   // 64KB double-buffered
  int id = blockIdx.x;
  int b = id & 7, t = id >> 3;            // batch-fastest: same batch -> same XCD
  int mb = 0;
  while ((mb + 1) * (mb + 2) / 2 <= t) ++mb;
  int nb = t - mb * (mb + 1) / 2;         // nb <= mb (lower triangle)
  const size_t bT = (size_t)b * T_;
  int tid = threadIdx.x, lane = tid & 63, wid = tid >> 6;
  int wm = (wid >> 1) * 64, wn = (wid & 1) * 64;

  f32x4 acc[4][4];
#pragma unroll
  for (int i = 0; i < 4; ++i)
#pragma unroll
    for (int j = 0; j < 4; ++j)
#pragma unroll
      for (int r = 0; r < 4; ++r) acc[i][j][r] = 0.f;

  gemm_core_pipe(qb + (bT + mb * 128) * (size_t)H_, H_,
                 kb + (bT + nb * 128) * (size_t)H_, H_, H_ / 64,
                 L, lane, wid, acc);

#pragma unroll
  for (int nt = 0; nt < 4; ++nt) {
    int gcol = nb * 128 + wn + nt * 16 + (lane & 15);
#pragma unroll
    for (int mt = 0; mt < 4; ++mt) {
      int grow = mb * 128 + wm + mt * 16 + (lane >> 4) * 4;
#pragma unroll
      for (int r = 0; r < 4; ++r)
        S[(bT + grow + r) * (size_t)T_ + gcol] = f2bf(acc[mt][nt][r] * 0.03125f);
    }
  }
}

// ---------- in-place causal row softmax: only needed 512-col blocks ----------
// coverage: nj = (row>>9)+1 blocks covers pv's K-range ((row>>7)+1)*128. Biggest rows first.
__global__ __launch_bounds__(256)
void smax_kernel(unsigned short* __restrict__ S) {
  int id = blockIdx.x;
  int b = id & 7, rb = id >> 3;                 // rb 0..511
  int w = threadIdx.x >> 6, lane = threadIdx.x & 63;
  int row = (511 - rb) * 4 + w;                 // biggest rows dispatched first
  unsigned short* rp = S + ((size_t)b * T_ + row) * T_;
  const int nj = (row >> 9) + 1;                // 1..4 column blocks needed

  bf16x8 d0, d1, d2, d3;
  d0 = *(const bf16x8*)(rp + lane * 8);
  if (nj > 1) d1 = *(const bf16x8*)(rp + 512 + lane * 8);
  if (nj > 2) d2 = *(const bf16x8*)(rp + 1024 + lane * 8);
  if (nj > 3) d3 = *(const bf16x8*)(rp + 1536 + lane * 8);

  float v0[8], v1[8], v2[8], v3[8];
  float mx = -1e30f;
#define PROC(VV, DD, BASE) do { \
    _Pragma("unroll") \
    for (int e = 0; e < 8; ++e) { \
      int col = (BASE) + lane * 8 + e; \
      float f = bf2f((unsigned short)DD[e]); \
      f = (col <= row) ? f : -1e30f; \
      VV[e] = f; mx = fmaxf(mx, f); \
    } } while (0)
  PROC(v0, d0, 0);
  if (nj > 1) PROC(v1, d1, 512);
  if (nj > 2) PROC(v2, d2, 1024);
  if (nj > 3) PROC(v3, d3, 1536);
#undef PROC
#pragma unroll
  for (int msk = 1; msk <= 32; msk <<= 1) mx = fmaxf(mx, __shfl_xor(mx, msk));

  float s = 0.f;
#define EXPS(VV) do { \
    _Pragma("unroll") \
    for (int e = 0; e < 8; ++e) { VV[e] = __expf(VV[e] - mx); s += VV[e]; } } while (0)
  EXPS(v0);
  if (nj > 1) EXPS(v1);
  if (nj > 2) EXPS(v2);
  if (nj > 3) EXPS(v3);
#undef EXPS
#pragma unroll
  for (int msk = 1; msk <= 32; msk <<= 1) s += __shfl_xor(s, msk);
  float inv = 1.0f / s;

#define WRB(VV, BASE) do { \
    bf16x8 o; \
    _Pragma("unroll") \
    for (int e = 0; e < 8; ++e) o[e] = (short)f2bf(VV[e] * inv); \
    *(bf16x8*)(rp + (BASE) + lane * 8) = o; } while (0)
  WRB(v0, 0);
  if (nj > 1) WRB(v1, 512);
  if (nj > 2) WRB(v2, 1024);
  if (nj > 3) WRB(v3, 1536);
#undef WRB
}

// ---------- O = P V, causal (K-range = (mb+1)*128), fp32 out ----------
__global__ __launch_bounds__(256, 2)
void pv_kernel(const unsigned short* __restrict__ P, const unsigned short* __restrict__ vT,
               float* __restrict__ out) {
  __shared__ short L[32768];   // 64KB double-buffered
  int id = blockIdx.x;
  int b = id & 7, u = id >> 3;
  int mb = 15 - (u >> 3);                  // biggest K-range first (load balance)
  int nb = u & 7;                          // d-block 0..7
  const size_t bT = (size_t)b * T_;
  int tid = threadIdx.x, lane = tid & 63, wid = tid >> 6;
  int wm = (wid >> 1) * 64, wn = (wid & 1) * 64;

  f32x4 acc[4][4];
#pragma unroll
  for (int i = 0; i < 4; ++i)
#pragma unroll
    for (int j = 0; j < 4; ++j)
#pragma unroll
      for (int r = 0; r < 4; ++r) acc[i][j][r] = 0.f;

  gemm_core_pipe(P + (bT + mb * 128) * (size_t)T_, T_,
                 vT + (size_t)(nb * 128) * M_ + bT, M_,
                 (mb + 1) * 2, L, lane, wid, acc);

#pragma unroll
  for (int nt = 0; nt < 4; ++nt) {
    int gcol = nb * 128 + wn + nt * 16 + (lane & 15);
#pragma unroll
    for (int mt = 0; mt < 4; ++mt) {
      int grow = mb * 128 + wm + mt * 16 + (lane >> 4) * 4;
#pragma unroll
      for (int r = 0; r < 4; ++r)
        out[(bT + grow + r) * (size_t)H_ + gcol] = acc[mt][nt][r];
    }
  }
}

extern "C" void kernel_launch(void* const* d_in, const int* in_sizes, int n_in,
                              void* d_out, int out_size, void* d_ws, size_t ws_size,
                              hipStream_t stream) {
  const float* x  = (const float*)d_in[0];
  const float* Wq = (const float*)d_in[1];
  const float* bq = (const float*)d_in[2];
  const float* Wk = (const float*)d_in[3];
  const float* bk = (const float*)d_in[4];
  const float* Wv = (const float*)d_in[5];
  const float* bv = (const float*)d_in[6];
  float* out = (float*)d_out;

  unsigned short* ws = (unsigned short*)d_ws;
  unsigned short* xb  = ws;                              // M x E bf16      (32MB)
  unsigned short* wqT = xb  + (size_t)M_ * E_;           // H x E bf16
  unsigned short* wkT = wqT + (size_t)E_ * H_;
  unsigned short* wvT = wkT + (size_t)E_ * H_;
  unsigned short* qb  = wvT + (size_t)E_ * H_;           // M x H bf16      (32MB)
  unsigned short* kbp = qb  + (size_t)M_ * H_;           // M x H bf16
  unsigned short* vTp = kbp + (size_t)M_ * H_;           // H x M bf16 (V transposed)
  unsigned short* Sp  = vTp + (size_t)M_ * H_;           // B x T x T bf16  (67MB) S, then P in-place

  conv_x_kernel<<<(M_ * E_ / 8 + 255) / 256, 256, 0, stream>>>(x, xb, M_ * E_ / 8);
  conv_wT_kernel<<<dim3(32, 32, 3), 256, 0, stream>>>(Wq, Wk, Wv, wqT, wkT, wvT);
  gemm_qkv_kernel<<<dim3(128, 24), 256, 0, stream>>>(xb, wqT, wkT, wvT, bq, bk, bv, qb, kbp, vTp);
  sgemm_kernel<<<dim3(136 * 8), 256, 0, stream>>>(qb, kbp, Sp);
  smax_kernel<<<dim3(512 * 8), 256, 0, stream>>>(Sp);
  pv_kernel<<<dim3(128 * 8), 256, 0, stream>>>(Sp, vTp, out);
}

// Round 14
// 245.190 us; speedup vs baseline: 1.2124x; 1.0061x over previous
//
#include <hip/hip_runtime.h>
#include <hip/hip_bf16.h>
#include <stdint.h>

#define B_ 8
#define T_ 2048
#define E_ 1024
#define H_ 1024
#define M_ (B_*T_)   // 16384

typedef __attribute__((ext_vector_type(8))) short bf16x8;
typedef __attribute__((ext_vector_type(4))) float f32x4;

__device__ __forceinline__ unsigned short f2bf(float f) {
  union { float f; unsigned int u; } v; v.f = f;
  unsigned int u = v.u;
  unsigned int r = u + 0x7fffu + ((u >> 16) & 1u);   // RNE (inputs finite)
  return (unsigned short)(r >> 16);
}

__device__ __forceinline__ float bf2f(unsigned short s) {
  union { unsigned int u; float f; } v; v.u = ((unsigned int)s) << 16;
  return v.f;
}

// async global->LDS, 16B per lane; LDS dest = wave-uniform base + lane*16
__device__ __forceinline__ void gload_lds16(const void* g, void* l) {
  __builtin_amdgcn_global_load_lds((const __attribute__((address_space(1))) void*)g,
                                   (__attribute__((address_space(3))) void*)l, 16, 0, 0);
}

#define MEMFENCE asm volatile("" ::: "memory")
#define BARRIER() do { MEMFENCE; __builtin_amdgcn_s_barrier(); MEMFENCE; } while (0)

// ---------- convert x (fp32) -> xb (bf16), 8 elems / thread ----------
__global__ void conv_x_kernel(const float* __restrict__ x,
                              unsigned short* __restrict__ xb, int n8) {
  int i = blockIdx.x * blockDim.x + threadIdx.x;
  if (i >= n8) return;
  const float4* src = (const float4*)(x + (size_t)i * 8);
  float4 a = src[0], b = src[1];
  uint4 o;
  o.x = (unsigned)f2bf(a.x) | ((unsigned)f2bf(a.y) << 16);
  o.y = (unsigned)f2bf(a.z) | ((unsigned)f2bf(a.w) << 16);
  o.z = (unsigned)f2bf(b.x) | ((unsigned)f2bf(b.y) << 16);
  o.w = (unsigned)f2bf(b.z) | ((unsigned)f2bf(b.w) << 16);
  *(uint4*)(xb + (size_t)i * 8) = o;
}

// ---------- convert + transpose W (E x H fp32) -> wT (H x E bf16) ----------
__global__ void conv_wT_kernel(const float* __restrict__ W0, const float* __restrict__ W1,
                               const float* __restrict__ W2,
                               unsigned short* __restrict__ T0, unsigned short* __restrict__ T1,
                               unsigned short* __restrict__ T2) {
  __shared__ float tile[32][33];
  const float* W = (blockIdx.z == 0) ? W0 : (blockIdx.z == 1) ? W1 : W2;
  unsigned short* Tt = (blockIdx.z == 0) ? T0 : (blockIdx.z == 1) ? T1 : T2;
  int k0 = blockIdx.x * 32;
  int n0 = blockIdx.y * 32;
  int t = threadIdx.x;
#pragma unroll
  for (int i = 0; i < 4; ++i) {
    int e = t + i * 256; int r = e >> 5, c = e & 31;
    tile[r][c] = W[(size_t)(k0 + r) * H_ + n0 + c];
  }
  __syncthreads();
#pragma unroll
  for (int i = 0; i < 4; ++i) {
    int e = t + i * 256; int r = e >> 5, c = e & 31;   // r = n-local, c = k-local
    Tt[(size_t)(n0 + r) * E_ + k0 + c] = f2bf(tile[c][r]);
  }
}

// ========== pipelined 128x128 core (4 waves, dbuf 64KB, counted vmcnt, 2 blocks/CU) ==========
// LDS buffer layout (bytes): A0 @0, B0 @16384, A1 @32768, B1 @49152.
__device__ __forceinline__ void stage128(const unsigned short* __restrict__ p, size_t stride,
                                         int kb0, short* buf, int lane, int wid) {
  const int srow = wid * 8 + (lane >> 3);
  const int scol = ((lane & 7) ^ (srow & 7)) * 8;
  short* l = buf + wid * 512;
#pragma unroll
  for (int i = 0; i < 4; ++i)
    gload_lds16(p + (size_t)(i * 32 + srow) * stride + kb0 + scol, l + i * 2048);
}

__device__ __forceinline__ void gemm_core_pipe(const unsigned short* __restrict__ Ap, size_t sA,
                                               const unsigned short* __restrict__ Bp, size_t sB,
                                               int NT, short* L, int lane, int wid, f32x4 acc[4][4]) {
  const int lo = lane & 15, hi = lane >> 4;
  const int wm = (wid >> 1) * 64, wn = (wid & 1) * 64;
  const int X0 = (hi << 4) ^ ((lo & 7) << 4);
  const int X1 = ((4 + hi) << 4) ^ ((lo & 7) << 4);
  const int laneA = (wm + lo) << 7;
  const int laneB = (wn + lo) << 7;

  bf16x8 a[4][2], b0[2][2], b1[2][2];

#define STA_(V) do { if ((V) < NT) stage128(Ap, sA, (V) * 64, L + (((V) & 1) ? 16384 : 0), lane, wid); } while (0)
#define STB_(V) do { if ((V) < NT) stage128(Bp, sB, (V) * 64, L + (((V) & 1) ? 24576 : 8192), lane, wid); } while (0)

  STA_(0); STB_(0); STA_(1); STB_(1);
  asm volatile("s_waitcnt vmcnt(8)" ::: "memory");
  BARRIER();
  __builtin_amdgcn_sched_barrier(0);
  {
    const char* Ac = (const char*)L;
    const char* Bc = (const char*)L + 16384;
#pragma unroll
    for (int mt = 0; mt < 4; ++mt) {
      a[mt][0] = *(const bf16x8*)(Ac + laneA + X0 + mt * 2048);
      a[mt][1] = *(const bf16x8*)(Ac + laneA + X1 + mt * 2048);
    }
#pragma unroll
    for (int nt = 0; nt < 2; ++nt) {
      b0[nt][0] = *(const bf16x8*)(Bc + laneB + X0 + nt * 2048);
      b0[nt][1] = *(const bf16x8*)(Bc + laneB + X1 + nt * 2048);
    }
    asm volatile("s_waitcnt lgkmcnt(0)" ::: "memory");
    __builtin_amdgcn_sched_barrier(0);
  }

  for (int U = 0; U < NT; ++U) {
    const char* Bc = (const char*)L + 16384 + (U & 1) * 32768;
    const char* An = (const char*)L + (((U + 1) & 1) ? 32768 : 0);
    const char* Bn = (const char*)L + 16384 + (((U + 1) & 1) ? 32768 : 0);
    const bool pf = (U + 1 < NT);

    // phase 1: MFMA a*b0 || read b1 || stage A(U+2)
    STA_(U + 2);
    __builtin_amdgcn_s_setprio(1);
#pragma unroll
    for (int mt = 0; mt < 2; ++mt)
#pragma unroll
      for (int nt = 0; nt < 2; ++nt)
#pragma unroll
        for (int kt = 0; kt < 2; ++kt)
          acc[mt][nt] = __builtin_amdgcn_mfma_f32_16x16x32_bf16(a[mt][kt], b0[nt][kt], acc[mt][nt], 0, 0, 0);
#pragma unroll
    for (int nt = 0; nt < 2; ++nt) {
      b1[nt][0] = *(const bf16x8*)(Bc + laneB + X0 + 4096 + nt * 2048);
      b1[nt][1] = *(const bf16x8*)(Bc + laneB + X1 + 4096 + nt * 2048);
    }
#pragma unroll
    for (int mt = 2; mt < 4; ++mt)
#pragma unroll
      for (int nt = 0; nt < 2; ++nt)
#pragma unroll
        for (int kt = 0; kt < 2; ++kt)
          acc[mt][nt] = __builtin_amdgcn_mfma_f32_16x16x32_bf16(a[mt][kt], b0[nt][kt], acc[mt][nt], 0, 0, 0);
    __builtin_amdgcn_s_setprio(0);
    asm volatile("s_waitcnt lgkmcnt(0)" ::: "memory");
    if (U + 2 < NT) asm volatile("s_waitcnt vmcnt(4)" ::: "memory");
    else            asm volatile("s_waitcnt vmcnt(0)" ::: "memory");
    BARRIER();
    __builtin_amdgcn_sched_barrier(0);

    // phase 2: MFMA a*b1 || read next a,b0 || stage B(U+2)
    STB_(U + 2);
    __builtin_amdgcn_s_setprio(1);
#pragma unroll
    for (int mt = 0; mt < 2; ++mt)
#pragma unroll
      for (int nt = 0; nt < 2; ++nt)
#pragma unroll
        for (int kt = 0; kt < 2; ++kt)
          acc[mt][2 + nt] = __builtin_amdgcn_mfma_f32_16x16x32_bf16(a[mt][kt], b1[nt][kt], acc[mt][2 + nt], 0, 0, 0);
    if (pf) {
#pragma unroll
      for (int mt = 0; mt < 2; ++mt) {
        a[mt][0] = *(const bf16x8*)(An + laneA + X0 + mt * 2048);
        a[mt][1] = *(const bf16x8*)(An + laneA + X1 + mt * 2048);
      }
#pragma unroll
      for (int nt = 0; nt < 2; ++nt) {
        b0[nt][0] = *(const bf16x8*)(Bn + laneB + X0 + nt * 2048);
        b0[nt][1] = *(const bf16x8*)(Bn + laneB + X1 + nt * 2048);
      }
    }
#pragma unroll
    for (int mt = 2; mt < 4; ++mt)
#pragma unroll
      for (int nt = 0; nt < 2; ++nt)
#pragma unroll
        for (int kt = 0; kt < 2; ++kt)
          acc[mt][2 + nt] = __builtin_amdgcn_mfma_f32_16x16x32_bf16(a[mt][kt], b1[nt][kt], acc[mt][2 + nt], 0, 0, 0);
    if (pf) {
#pragma unroll
      for (int mt = 2; mt < 4; ++mt) {
        a[mt][0] = *(const bf16x8*)(An + laneA + X0 + mt * 2048);
        a[mt][1] = *(const bf16x8*)(An + laneA + X1 + mt * 2048);
      }
    }
    __builtin_amdgcn_s_setprio(0);
    asm volatile("s_waitcnt lgkmcnt(0)" ::: "memory");
    BARRIER();
    __builtin_amdgcn_sched_barrier(0);
  }
#undef STA_
#undef STB_
}

// ---------- fused QKV GEMM on the pipelined 128x128 core ----------
// grid: (24 = which*8 + n-tile, 128 M-tiles). x fastest -> the 24 blocks sharing
// one A M-panel are co-resident (A read ~once; W panels stay L2-hot).
__global__ __launch_bounds__(256, 2)
void gemm_qkv_kernel(const unsigned short* __restrict__ xb,
                     const unsigned short* __restrict__ wqT, const unsigned short* __restrict__ wkT,
                     const unsigned short* __restrict__ wvT,
                     const float* __restrict__ bq, const float* __restrict__ bk,
                     const float* __restrict__ bv,
                     unsigned short* __restrict__ qb, unsigned short* __restrict__ kb,
                     unsigned short* __restrict__ vb) {
  __shared__ short L[32768];   // 64KB double-buffered
  const int which = blockIdx.x >> 3;
  const int ncol0 = (blockIdx.x & 7) * 128;
  const unsigned short* Bt = (which == 0) ? wqT : (which == 1) ? wkT : wvT;
  const float* bias = (which == 0) ? bq : (which == 1) ? bk : bv;
  unsigned short* outp = (which == 0) ? qb : (which == 1) ? kb : vb;
  const int m0 = blockIdx.y * 128;
  int tid = threadIdx.x, lane = tid & 63, wid = tid >> 6;
  int wm = (wid >> 1) * 64, wn = (wid & 1) * 64;

  f32x4 acc[4][4];
#pragma unroll
  for (int i = 0; i < 4; ++i)
#pragma unroll
    for (int j = 0; j < 4; ++j)
#pragma unroll
      for (int r = 0; r < 4; ++r) acc[i][j][r] = 0.f;

  gemm_core_pipe(xb + (size_t)m0 * E_, E_,
                 Bt + (size_t)ncol0 * E_, E_, E_ / 64,
                 L, lane, wid, acc);

  if (which == 2) {
    // transposed write: vT[d = gcol][m = grow..grow+3], 8B packed
#pragma unroll
    for (int nt = 0; nt < 4; ++nt) {
      int gcol = ncol0 + wn + nt * 16 + (lane & 15);
      float bb = bias[gcol];
#pragma unroll
      for (int mt = 0; mt < 4; ++mt) {
        int grow = m0 + wm + mt * 16 + (lane >> 4) * 4;
        ushort4 o;
        o.x = f2bf(acc[mt][nt][0] + bb);
        o.y = f2bf(acc[mt][nt][1] + bb);
        o.z = f2bf(acc[mt][nt][2] + bb);
        o.w = f2bf(acc[mt][nt][3] + bb);
        *(ushort4*)(outp + (size_t)gcol * M_ + grow) = o;
      }
    }
  } else {
#pragma unroll
    for (int nt = 0; nt < 4; ++nt) {
      int gcol = ncol0 + wn + nt * 16 + (lane & 15);
      float bb = bias[gcol];
#pragma unroll
      for (int mt = 0; mt < 4; ++mt) {
        int grow = m0 + wm + mt * 16 + (lane >> 4) * 4;
#pragma unroll
        for (int r = 0; r < 4; ++r)
          outp[(size_t)(grow + r) * H_ + gcol] = f2bf(acc[mt][nt][r] + bb);
      }
    }
  }
}

// ---------- S = (Q K^T) * scale, causal lower-tri 128x128 tiles, bf16 out ----------
__global__ __launch_bounds__(256, 2)
void sgemm_kernel(const unsigned short* __restrict__ qb, const unsigned short* __restrict__ kb,
                  unsigned short* __restrict__ S) {
  __shared__ short L[32768];   // 64KB double-buffered
  int id = blockIdx.x;
  int b = id & 7, t = id >> 3;            // batch-fastest: same batch -> same XCD
  int mb = 0;
  while ((mb + 1) * (mb + 2) / 2 <= t) ++mb;
  int nb = t - mb * (mb + 1) / 2;         // nb <= mb (lower triangle)
  const size_t bT = (size_t)b * T_;
  int tid = threadIdx.x, lane = tid & 63, wid = tid >> 6;
  int wm = (wid >> 1) * 64, wn = (wid & 1) * 64;

  f32x4 acc[4][4];
#pragma unroll
  for (int i = 0; i < 4; ++i)
#pragma unroll
    for (int j = 0; j < 4; ++j)
#pragma unroll
      for (int r = 0; r < 4; ++r) acc[i][j][r] = 0.f;

  gemm_core_pipe(qb + (bT + mb * 128) * (size_t)H_, H_,
                 kb + (bT + nb * 128) * (size_t)H_, H_, H_ / 64,
                 L, lane, wid, acc);

#pragma unroll
  for (int nt = 0; nt < 4; ++nt) {
    int gcol = nb * 128 + wn + nt * 16 + (lane & 15);
#pragma unroll
    for (int mt = 0; mt < 4; ++mt) {
      int grow = mb * 128 + wm + mt * 16 + (lane >> 4) * 4;
#pragma unroll
      for (int r = 0; r < 4; ++r)
        S[(bT + grow + r) * (size_t)T_ + gcol] = f2bf(acc[mt][nt][r] * 0.03125f);
    }
  }
}

// ---------- in-place causal row softmax: only needed 512-col blocks ----------
// coverage: nj = (row>>9)+1 blocks covers pv's K-range ((row>>7)+1)*128. Biggest rows first.
__global__ __launch_bounds__(256)
void smax_kernel(unsigned short* __restrict__ S) {
  int id = blockIdx.x;
  int b = id & 7, rb = id >> 3;                 // rb 0..511
  int w = threadIdx.x >> 6, lane = threadIdx.x & 63;
  int row = (511 - rb) * 4 + w;                 // biggest rows dispatched first
  unsigned short* rp = S + ((size_t)b * T_ + row) * T_;
  const int nj = (row >> 9) + 1;                // 1..4 column blocks needed

  bf16x8 d0, d1, d2, d3;
  d0 = *(const bf16x8*)(rp + lane * 8);
  if (nj > 1) d1 = *(const bf16x8*)(rp + 512 + lane * 8);
  if (nj > 2) d2 = *(const bf16x8*)(rp + 1024 + lane * 8);
  if (nj > 3) d3 = *(const bf16x8*)(rp + 1536 + lane * 8);

  float v0[8], v1[8], v2[8], v3[8];
  float mx = -1e30f;
#define PROC(VV, DD, BASE) do { \
    _Pragma("unroll") \
    for (int e = 0; e < 8; ++e) { \
      int col = (BASE) + lane * 8 + e; \
      float f = bf2f((unsigned short)DD[e]); \
      f = (col <= row) ? f : -1e30f; \
      VV[e] = f; mx = fmaxf(mx, f); \
    } } while (0)
  PROC(v0, d0, 0);
  if (nj > 1) PROC(v1, d1, 512);
  if (nj > 2) PROC(v2, d2, 1024);
  if (nj > 3) PROC(v3, d3, 1536);
#undef PROC
#pragma unroll
  for (int msk = 1; msk <= 32; msk <<= 1) mx = fmaxf(mx, __shfl_xor(mx, msk));

  float s = 0.f;
#define EXPS(VV) do { \
    _Pragma("unroll") \
    for (int e = 0; e < 8; ++e) { VV[e] = __expf(VV[e] - mx); s += VV[e]; } } while (0)
  EXPS(v0);
  if (nj > 1) EXPS(v1);
  if (nj > 2) EXPS(v2);
  if (nj > 3) EXPS(v3);
#undef EXPS
#pragma unroll
  for (int msk = 1; msk <= 32; msk <<= 1) s += __shfl_xor(s, msk);
  float inv = 1.0f / s;

#define WRB(VV, BASE) do { \
    bf16x8 o; \
    _Pragma("unroll") \
    for (int e = 0; e < 8; ++e) o[e] = (short)f2bf(VV[e] * inv); \
    *(bf16x8*)(rp + (BASE) + lane * 8) = o; } while (0)
  WRB(v0, 0);
  if (nj > 1) WRB(v1, 512);
  if (nj > 2) WRB(v2, 1024);
  if (nj > 3) WRB(v3, 1536);
#undef WRB
}

// ---------- O = P V, causal (K-range = (mb+1)*128), fp32 out ----------
__global__ __launch_bounds__(256, 2)
void pv_kernel(const unsigned short* __restrict__ P, const unsigned short* __restrict__ vT,
               float* __restrict__ out) {
  __shared__ short L[32768];   // 64KB double-buffered
  int id = blockIdx.x;
  int b = id & 7, u = id >> 3;
  int mb = 15 - (u >> 3);                  // biggest K-range first (load balance)
  int nb = u & 7;                          // d-block 0..7
  const size_t bT = (size_t)b * T_;
  int tid = threadIdx.x, lane = tid & 63, wid = tid >> 6;
  int wm = (wid >> 1) * 64, wn = (wid & 1) * 64;

  f32x4 acc[4][4];
#pragma unroll
  for (int i = 0; i < 4; ++i)
#pragma unroll
    for (int j = 0; j < 4; ++j)
#pragma unroll
      for (int r = 0; r < 4; ++r) acc[i][j][r] = 0.f;

  gemm_core_pipe(P + (bT + mb * 128) * (size_t)T_, T_,
                 vT + (size_t)(nb * 128) * M_ + bT, M_,
                 (mb + 1) * 2, L, lane, wid, acc);

#pragma unroll
  for (int nt = 0; nt < 4; ++nt) {
    int gcol = nb * 128 + wn + nt * 16 + (lane & 15);
#pragma unroll
    for (int mt = 0; mt < 4; ++mt) {
      int grow = mb * 128 + wm + mt * 16 + (lane >> 4) * 4;
#pragma unroll
      for (int r = 0; r < 4; ++r)
        out[(bT + grow + r) * (size_t)H_ + gcol] = acc[mt][nt][r];
    }
  }
}

extern "C" void kernel_launch(void* const* d_in, const int* in_sizes, int n_in,
                              void* d_out, int out_size, void* d_ws, size_t ws_size,
                              hipStream_t stream) {
  const float* x  = (const float*)d_in[0];
  const float* Wq = (const float*)d_in[1];
  const float* bq = (const float*)d_in[2];
  const float* Wk = (const float*)d_in[3];
  const float* bk = (const float*)d_in[4];
  const float* Wv = (const float*)d_in[5];
  const float* bv = (const float*)d_in[6];
  float* out = (float*)d_out;

  unsigned short* ws = (unsigned short*)d_ws;
  unsigned short* xb  = ws;                              // M x E bf16      (32MB)
  unsigned short* wqT = xb  + (size_t)M_ * E_;           // H x E bf16
  unsigned short* wkT = wqT + (size_t)E_ * H_;
  unsigned short* wvT = wkT + (size_t)E_ * H_;
  unsigned short* qb  = wvT + (size_t)E_ * H_;           // M x H bf16      (32MB)
  unsigned short* kbp = qb  + (size_t)M_ * H_;           // M x H bf16
  unsigned short* vTp = kbp + (size_t)M_ * H_;           // H x M bf16 (V transposed)
  unsigned short* Sp  = vTp + (size_t)M_ * H_;           // B x T x T bf16  (67MB) S, then P in-place

  conv_x_kernel<<<(M_ * E_ / 8 + 255) / 256, 256, 0, stream>>>(x, xb, M_ * E_ / 8);
  conv_wT_kernel<<<dim3(32, 32, 3), 256, 0, stream>>>(Wq, Wk, Wv, wqT, wkT, wvT);
  gemm_qkv_kernel<<<dim3(24, 128), 256, 0, stream>>>(xb, wqT, wkT, wvT, bq, bk, bv, qb, kbp, vTp);
  sgemm_kernel<<<dim3(136 * 8), 256, 0, stream>>>(qb, kbp, Sp);
  smax_kernel<<<dim3(512 * 8), 256, 0, stream>>>(Sp);
  pv_kernel<<<dim3(128 * 8), 256, 0, stream>>>(Sp, vTp, out);
}

// Round 15
// 244.707 us; speedup vs baseline: 1.2148x; 1.0020x over previous
//
#include <hip/hip_runtime.h>
#include <hip/hip_bf16.h>
#include <stdint.h>

#define B_ 8
#define T_ 2048
#define E_ 1024
#define H_ 1024
#define M_ (B_*T_)   // 16384

typedef __attribute__((ext_vector_type(8))) short bf16x8;
typedef __attribute__((ext_vector_type(4))) float f32x4;

__device__ __forceinline__ unsigned short f2bf(float f) {
  union { float f; unsigned int u; } v; v.f = f;
  unsigned int u = v.u;
  unsigned int r = u + 0x7fffu + ((u >> 16) & 1u);   // RNE (inputs finite)
  return (unsigned short)(r >> 16);
}

__device__ __forceinline__ float bf2f(unsigned short s) {
  union { unsigned int u; float f; } v; v.u = ((unsigned int)s) << 16;
  return v.f;
}

// async global->LDS, 16B per lane; LDS dest = wave-uniform base + lane*16
__device__ __forceinline__ void gload_lds16(const void* g, void* l) {
  __builtin_amdgcn_global_load_lds((const __attribute__((address_space(1))) void*)g,
                                   (__attribute__((address_space(3))) void*)l, 16, 0, 0);
}

#define MEMFENCE asm volatile("" ::: "memory")
#define BARRIER() do { MEMFENCE; __builtin_amdgcn_s_barrier(); MEMFENCE; } while (0)

// ---------- convert x (fp32) -> xb (bf16), 8 elems / thread ----------
__global__ void conv_x_kernel(const float* __restrict__ x,
                              unsigned short* __restrict__ xb, int n8) {
  int i = blockIdx.x * blockDim.x + threadIdx.x;
  if (i >= n8) return;
  const float4* src = (const float4*)(x + (size_t)i * 8);
  float4 a = src[0], b = src[1];
  uint4 o;
  o.x = (unsigned)f2bf(a.x) | ((unsigned)f2bf(a.y) << 16);
  o.y = (unsigned)f2bf(a.z) | ((unsigned)f2bf(a.w) << 16);
  o.z = (unsigned)f2bf(b.x) | ((unsigned)f2bf(b.y) << 16);
  o.w = (unsigned)f2bf(b.z) | ((unsigned)f2bf(b.w) << 16);
  *(uint4*)(xb + (size_t)i * 8) = o;
}

// ---------- convert + transpose W (E x H fp32) -> wT (H x E bf16) ----------
__global__ void conv_wT_kernel(const float* __restrict__ W0, const float* __restrict__ W1,
                               const float* __restrict__ W2,
                               unsigned short* __restrict__ T0, unsigned short* __restrict__ T1,
                               unsigned short* __restrict__ T2) {
  __shared__ float tile[32][33];
  const float* W = (blockIdx.z == 0) ? W0 : (blockIdx.z == 1) ? W1 : W2;
  unsigned short* Tt = (blockIdx.z == 0) ? T0 : (blockIdx.z == 1) ? T1 : T2;
  int k0 = blockIdx.x * 32;
  int n0 = blockIdx.y * 32;
  int t = threadIdx.x;
#pragma unroll
  for (int i = 0; i < 4; ++i) {
    int e = t + i * 256; int r = e >> 5, c = e & 31;
    tile[r][c] = W[(size_t)(k0 + r) * H_ + n0 + c];
  }
  __syncthreads();
#pragma unroll
  for (int i = 0; i < 4; ++i) {
    int e = t + i * 256; int r = e >> 5, c = e & 31;   // r = n-local, c = k-local
    Tt[(size_t)(n0 + r) * E_ + k0 + c] = f2bf(tile[c][r]);
  }
}

// ================== QKV GEMM: 256x256 tile, 8 waves (2Mx4N, 128x64/wave) ==================
// Same 2-phase sync structure as the proven gemm_core_pipe (identical stage-inst
// counts: 4 gloads/call, vmcnt(4) at ph1-end, lgkm(0) before each barrier).
// LDS (shorts): A0 @0, A1 @16384, B0 @32768, B1 @49152 (128KB total).
__device__ __forceinline__ void stage256(const unsigned short* __restrict__ p, size_t stride,
                                         int kb0, short* buf, int tid) {
  const int srow = tid >> 3;                        // 0..63
  const int scol = ((tid & 7) ^ (srow & 7)) * 8;    // pre-swizzled granule
  short* l = buf + (tid >> 6) * 512;                // wave-uniform base (+lane*16B implicit)
#pragma unroll
  for (int r = 0; r < 4; ++r)
    gload_lds16(p + (size_t)(r * 64 + srow) * stride + kb0 + scol, l + r * 4096);
}

__global__ __launch_bounds__(512, 2)
void gemm_qkv_kernel(const unsigned short* __restrict__ xb,
                     const unsigned short* __restrict__ wqT, const unsigned short* __restrict__ wkT,
                     const unsigned short* __restrict__ wvT,
                     const float* __restrict__ bq, const float* __restrict__ bk,
                     const float* __restrict__ bv,
                     unsigned short* __restrict__ qb, unsigned short* __restrict__ kb,
                     unsigned short* __restrict__ vb) {
  __shared__ short L[65536];   // 128KB
  const int which = blockIdx.x >> 2;
  const int ncol0 = (blockIdx.x & 3) * 256;
  const unsigned short* Bt = (which == 0) ? wqT : (which == 1) ? wkT : wvT;
  const float* bias = (which == 0) ? bq : (which == 1) ? bk : bv;
  unsigned short* outp = (which == 0) ? qb : (which == 1) ? kb : vb;
  const int m0 = blockIdx.y * 256;
  const unsigned short* Ap = xb + (size_t)m0 * E_;
  const unsigned short* Bp = Bt + (size_t)ncol0 * E_;
  const int NT = E_ / 64;   // 16

  const int tid = threadIdx.x, lane = tid & 63, w = tid >> 6;
  const int lo = lane & 15, hi = lane >> 4;
  const int wm = (w >> 2) * 128;    // 0 or 128
  const int wn = (w & 3) * 64;      // 0,64,128,192
  const int X0 = (hi << 4) ^ ((lo & 7) << 4);
  const int X1 = ((4 + hi) << 4) ^ ((lo & 7) << 4);
  const int laneA = (wm + lo) << 7;
  const int laneB = (wn + lo) << 7;

  f32x4 acc[8][4];
#pragma unroll
  for (int i = 0; i < 8; ++i)
#pragma unroll
    for (int j = 0; j < 4; ++j)
#pragma unroll
      for (int r = 0; r < 4; ++r) acc[i][j][r] = 0.f;

  bf16x8 a[8][2], b0[2][2], b1[2][2];

#define STA_(V) do { if ((V) < NT) stage256(Ap, E_, (V) * 64, L + (((V) & 1) ? 16384 : 0), tid); } while (0)
#define STB_(V) do { if ((V) < NT) stage256(Bp, E_, (V) * 64, L + 32768 + (((V) & 1) ? 16384 : 0), tid); } while (0)

  STA_(0); STB_(0); STA_(1); STB_(1);
  asm volatile("s_waitcnt vmcnt(8)" ::: "memory");
  BARRIER();
  __builtin_amdgcn_sched_barrier(0);
  {
    const char* Ac = (const char*)L;
    const char* Bc = (const char*)L + 65536;
#pragma unroll
    for (int mt = 0; mt < 8; ++mt) {
      a[mt][0] = *(const bf16x8*)(Ac + laneA + X0 + mt * 2048);
      a[mt][1] = *(const bf16x8*)(Ac + laneA + X1 + mt * 2048);
    }
#pragma unroll
    for (int nt = 0; nt < 2; ++nt) {
      b0[nt][0] = *(const bf16x8*)(Bc + laneB + X0 + nt * 2048);
      b0[nt][1] = *(const bf16x8*)(Bc + laneB + X1 + nt * 2048);
    }
    asm volatile("s_waitcnt lgkmcnt(0)" ::: "memory");
    __builtin_amdgcn_sched_barrier(0);
  }

  for (int U = 0; U < NT; ++U) {
    const char* Bc = (const char*)L + 65536 + (U & 1) * 32768;
    const char* An = (const char*)L + (((U + 1) & 1) ? 32768 : 0);
    const char* Bn = (const char*)L + 65536 + (((U + 1) & 1) ? 32768 : 0);
    const bool pf = (U + 1 < NT);

    // phase 1: MFMA a*b0 -> acc[*][0..1] || read b1 || stage A(U+2)
    STA_(U + 2);
    __builtin_amdgcn_s_setprio(1);
#pragma unroll
    for (int mt = 0; mt < 4; ++mt)
#pragma unroll
      for (int nt = 0; nt < 2; ++nt)
#pragma unroll
        for (int kt = 0; kt < 2; ++kt)
          acc[mt][nt] = __builtin_amdgcn_mfma_f32_16x16x32_bf16(a[mt][kt], b0[nt][kt], acc[mt][nt], 0, 0, 0);
#pragma unroll
    for (int nt = 0; nt < 2; ++nt) {
      b1[nt][0] = *(const bf16x8*)(Bc + laneB + X0 + 4096 + nt * 2048);
      b1[nt][1] = *(const bf16x8*)(Bc + laneB + X1 + 4096 + nt * 2048);
    }
#pragma unroll
    for (int mt = 4; mt < 8; ++mt)
#pragma unroll
      for (int nt = 0; nt < 2; ++nt)
#pragma unroll
        for (int kt = 0; kt < 2; ++kt)
          acc[mt][nt] = __builtin_amdgcn_mfma_f32_16x16x32_bf16(a[mt][kt], b0[nt][kt], acc[mt][nt], 0, 0, 0);
    __builtin_amdgcn_s_setprio(0);
    asm volatile("s_waitcnt lgkmcnt(0)" ::: "memory");
    if (U + 2 < NT) asm volatile("s_waitcnt vmcnt(4)" ::: "memory");
    else            asm volatile("s_waitcnt vmcnt(0)" ::: "memory");
    BARRIER();
    __builtin_amdgcn_sched_barrier(0);

    // phase 2: MFMA a*b1 -> acc[*][2..3] || read next a,b0 || stage B(U+2)
    STB_(U + 2);
    __builtin_amdgcn_s_setprio(1);
#pragma unroll
    for (int mt = 0; mt < 4; ++mt)
#pragma unroll
      for (int nt = 0; nt < 2; ++nt)
#pragma unroll
        for (int kt = 0; kt < 2; ++kt)
          acc[mt][2 + nt] = __builtin_amdgcn_mfma_f32_16x16x32_bf16(a[mt][kt], b1[nt][kt], acc[mt][2 + nt], 0, 0, 0);
    if (pf) {
#pragma unroll
      for (int mt = 0; mt < 4; ++mt) {
        a[mt][0] = *(const bf16x8*)(An + laneA + X0 + mt * 2048);
        a[mt][1] = *(const bf16x8*)(An + laneA + X1 + mt * 2048);
      }
#pragma unroll
      for (int nt = 0; nt < 2; ++nt) {
        b0[nt][0] = *(const bf16x8*)(Bn + laneB + X0 + nt * 2048);
        b0[nt][1] = *(const bf16x8*)(Bn + laneB + X1 + nt * 2048);
      }
    }
#pragma unroll
    for (int mt = 4; mt < 8; ++mt)
#pragma unroll
      for (int nt = 0; nt < 2; ++nt)
#pragma unroll
        for (int kt = 0; kt < 2; ++kt)
          acc[mt][2 + nt] = __builtin_amdgcn_mfma_f32_16x16x32_bf16(a[mt][kt], b1[nt][kt], acc[mt][2 + nt], 0, 0, 0);
    if (pf) {
#pragma unroll
      for (int mt = 4; mt < 8; ++mt) {
        a[mt][0] = *(const bf16x8*)(An + laneA + X0 + mt * 2048);
        a[mt][1] = *(const bf16x8*)(An + laneA + X1 + mt * 2048);
      }
    }
    __builtin_amdgcn_s_setprio(0);
    asm volatile("s_waitcnt lgkmcnt(0)" ::: "memory");
    BARRIER();
    __builtin_amdgcn_sched_barrier(0);
  }
#undef STA_
#undef STB_

  // ---------- epilogue ----------
  if (which == 2) {
    // transposed write: vT[d = gcol][m = grow..grow+3], 8B packed
#pragma unroll
    for (int j = 0; j < 4; ++j) {
      int gcol = ncol0 + wn + j * 16 + lo;
      float bb = bias[gcol];
#pragma unroll
      for (int mt = 0; mt < 8; ++mt) {
        int grow = m0 + wm + mt * 16 + hi * 4;
        ushort4 o;
        o.x = f2bf(acc[mt][j][0] + bb);
        o.y = f2bf(acc[mt][j][1] + bb);
        o.z = f2bf(acc[mt][j][2] + bb);
        o.w = f2bf(acc[mt][j][3] + bb);
        *(ushort4*)(outp + (size_t)gcol * M_ + grow) = o;
      }
    }
  } else {
#pragma unroll
    for (int j = 0; j < 4; ++j) {
      int gcol = ncol0 + wn + j * 16 + lo;
      float bb = bias[gcol];
#pragma unroll
      for (int mt = 0; mt < 8; ++mt) {
        int grow = m0 + wm + mt * 16 + hi * 4;
#pragma unroll
        for (int r = 0; r < 4; ++r)
          outp[(size_t)(grow + r) * H_ + gcol] = f2bf(acc[mt][j][r] + bb);
      }
    }
  }
}

// ========== pipelined 128x128 core (4 waves, dbuf 64KB, counted vmcnt, 2 blocks/CU) ==========
__device__ __forceinline__ void stage128(const unsigned short* __restrict__ p, size_t stride,
                                         int kb0, short* buf, int lane, int wid) {
  const int srow = wid * 8 + (lane >> 3);
  const int scol = ((lane & 7) ^ (srow & 7)) * 8;
  short* l = buf + wid * 512;
#pragma unroll
  for (int i = 0; i < 4; ++i)
    gload_lds16(p + (size_t)(i * 32 + srow) * stride + kb0 + scol, l + i * 2048);
}

__device__ __forceinline__ void gemm_core_pipe(const unsigned short* __restrict__ Ap, size_t sA,
                                               const unsigned short* __restrict__ Bp, size_t sB,
                                               int NT, short* L, int lane, int wid, f32x4 acc[4][4]) {
  const int lo = lane & 15, hi = lane >> 4;
  const int wm = (wid >> 1) * 64, wn = (wid & 1) * 64;
  const int X0 = (hi << 4) ^ ((lo & 7) << 4);
  const int X1 = ((4 + hi) << 4) ^ ((lo & 7) << 4);
  const int laneA = (wm + lo) << 7;
  const int laneB = (wn + lo) << 7;

  bf16x8 a[4][2], b0[2][2], b1[2][2];

#define STA_(V) do { if ((V) < NT) stage128(Ap, sA, (V) * 64, L + (((V) & 1) ? 16384 : 0), lane, wid); } while (0)
#define STB_(V) do { if ((V) < NT) stage128(Bp, sB, (V) * 64, L + (((V) & 1) ? 24576 : 8192), lane, wid); } while (0)

  STA_(0); STB_(0); STA_(1); STB_(1);
  asm volatile("s_waitcnt vmcnt(8)" ::: "memory");
  BARRIER();
  __builtin_amdgcn_sched_barrier(0);
  {
    const char* Ac = (const char*)L;
    const char* Bc = (const char*)L + 16384;
#pragma unroll
    for (int mt = 0; mt < 4; ++mt) {
      a[mt][0] = *(const bf16x8*)(Ac + laneA + X0 + mt * 2048);
      a[mt][1] = *(const bf16x8*)(Ac + laneA + X1 + mt * 2048);
    }
#pragma unroll
    for (int nt = 0; nt < 2; ++nt) {
      b0[nt][0] = *(const bf16x8*)(Bc + laneB + X0 + nt * 2048);
      b0[nt][1] = *(const bf16x8*)(Bc + laneB + X1 + nt * 2048);
    }
    asm volatile("s_waitcnt lgkmcnt(0)" ::: "memory");
    __builtin_amdgcn_sched_barrier(0);
  }

  for (int U = 0; U < NT; ++U) {
    const char* Bc = (const char*)L + 16384 + (U & 1) * 32768;
    const char* An = (const char*)L + (((U + 1) & 1) ? 32768 : 0);
    const char* Bn = (const char*)L + 16384 + (((U + 1) & 1) ? 32768 : 0);
    const bool pf = (U + 1 < NT);

    // phase 1: MFMA a*b0 || read b1 || stage A(U+2)
    STA_(U + 2);
    __builtin_amdgcn_s_setprio(1);
#pragma unroll
    for (int mt = 0; mt < 2; ++mt)
#pragma unroll
      for (int nt = 0; nt < 2; ++nt)
#pragma unroll
        for (int kt = 0; kt < 2; ++kt)
          acc[mt][nt] = __builtin_amdgcn_mfma_f32_16x16x32_bf16(a[mt][kt], b0[nt][kt], acc[mt][nt], 0, 0, 0);
#pragma unroll
    for (int nt = 0; nt < 2; ++nt) {
      b1[nt][0] = *(const bf16x8*)(Bc + laneB + X0 + 4096 + nt * 2048);
      b1[nt][1] = *(const bf16x8*)(Bc + laneB + X1 + 4096 + nt * 2048);
    }
#pragma unroll
    for (int mt = 2; mt < 4; ++mt)
#pragma unroll
      for (int nt = 0; nt < 2; ++nt)
#pragma unroll
        for (int kt = 0; kt < 2; ++kt)
          acc[mt][nt] = __builtin_amdgcn_mfma_f32_16x16x32_bf16(a[mt][kt], b0[nt][kt], acc[mt][nt], 0, 0, 0);
    __builtin_amdgcn_s_setprio(0);
    asm volatile("s_waitcnt lgkmcnt(0)" ::: "memory");
    if (U + 2 < NT) asm volatile("s_waitcnt vmcnt(4)" ::: "memory");
    else            asm volatile("s_waitcnt vmcnt(0)" ::: "memory");
    BARRIER();
    __builtin_amdgcn_sched_barrier(0);

    // phase 2: MFMA a*b1 || read next a,b0 || stage B(U+2)
    STB_(U + 2);
    __builtin_amdgcn_s_setprio(1);
#pragma unroll
    for (int mt = 0; mt < 2; ++mt)
#pragma unroll
      for (int nt = 0; nt < 2; ++nt)
#pragma unroll
        for (int kt = 0; kt < 2; ++kt)
          acc[mt][2 + nt] = __builtin_amdgcn_mfma_f32_16x16x32_bf16(a[mt][kt], b1[nt][kt], acc[mt][2 + nt], 0, 0, 0);
    if (pf) {
#pragma unroll
      for (int mt = 0; mt < 2; ++mt) {
        a[mt][0] = *(const bf16x8*)(An + laneA + X0 + mt * 2048);
        a[mt][1] = *(const bf16x8*)(An + laneA + X1 + mt * 2048);
      }
#pragma unroll
      for (int nt = 0; nt < 2; ++nt) {
        b0[nt][0] = *(const bf16x8*)(Bn + laneB + X0 + nt * 2048);
        b0[nt][1] = *(const bf16x8*)(Bn + laneB + X1 + nt * 2048);
      }
    }
#pragma unroll
    for (int mt = 2; mt < 4; ++mt)
#pragma unroll
      for (int nt = 0; nt < 2; ++nt)
#pragma unroll
        for (int kt = 0; kt < 2; ++kt)
          acc[mt][2 + nt] = __builtin_amdgcn_mfma_f32_16x16x32_bf16(a[mt][kt], b1[nt][kt], acc[mt][2 + nt], 0, 0, 0);
    if (pf) {
#pragma unroll
      for (int mt = 2; mt < 4; ++mt) {
        a[mt][0] = *(const bf16x8*)(An + laneA + X0 + mt * 2048);
        a[mt][1] = *(const bf16x8*)(An + laneA + X1 + mt * 2048);
      }
    }
    __builtin_amdgcn_s_setprio(0);
    asm volatile("s_waitcnt lgkmcnt(0)" ::: "memory");
    BARRIER();
    __builtin_amdgcn_sched_barrier(0);
  }
#undef STA_
#undef STB_
}

// ---------- S = (Q K^T) * scale, causal lower-tri 128x128 tiles, bf16 out ----------
__global__ __launch_bounds__(256, 2)
void sgemm_kernel(const unsigned short* __restrict__ qb, const unsigned short* __restrict__ kb,
                  unsigned short* __restrict__ S) {
  __shared__ short L[32768];   // 64KB double-buffered
  int id = blockIdx.x;
  int b = id & 7, t = id >> 3;            // batch-fastest: same batch -> same XCD
  int mb = 0;
  while ((mb + 1) * (mb + 2) / 2 <= t) ++mb;
  int nb = t - mb * (mb + 1) / 2;         // nb <= mb (lower triangle)
  const size_t bT = (size_t)b * T_;
  int tid = threadIdx.x, lane = tid & 63, wid = tid >> 6;
  int wm = (wid >> 1) * 64, wn = (wid & 1) * 64;

  f32x4 acc[4][4];
#pragma unroll
  for (int i = 0; i < 4; ++i)
#pragma unroll
    for (int j = 0; j < 4; ++j)
#pragma unroll
      for (int r = 0; r < 4; ++r) acc[i][j][r] = 0.f;

  gemm_core_pipe(qb + (bT + mb * 128) * (size_t)H_, H_,
                 kb + (bT + nb * 128) * (size_t)H_, H_, H_ / 64,
                 L, lane, wid, acc);

#pragma unroll
  for (int nt = 0; nt < 4; ++nt) {
    int gcol = nb * 128 + wn + nt * 16 + (lane & 15);
#pragma unroll
    for (int mt = 0; mt < 4; ++mt) {
      int grow = mb * 128 + wm + mt * 16 + (lane >> 4) * 4;
#pragma unroll
      for (int r = 0; r < 4; ++r)
        S[(bT + grow + r) * (size_t)T_ + gcol] = f2bf(acc[mt][nt][r] * 0.03125f);
    }
  }
}

// ---------- in-place causal row softmax: only needed 512-col blocks ----------
__global__ __launch_bounds__(256)
void smax_kernel(unsigned short* __restrict__ S) {
  int id = blockIdx.x;
  int b = id & 7, rb = id >> 3;                 // rb 0..511
  int w = threadIdx.x >> 6, lane = threadIdx.x & 63;
  int row = (511 - rb) * 4 + w;                 // biggest rows dispatched first
  unsigned short* rp = S + ((size_t)b * T_ + row) * T_;
  const int nj = (row >> 9) + 1;                // 1..4 column blocks needed

  bf16x8 d0, d1, d2, d3;
  d0 = *(const bf16x8*)(rp + lane * 8);
  if (nj > 1) d1 = *(const bf16x8*)(rp + 512 + lane * 8);
  if (nj > 2) d2 = *(const bf16x8*)(rp + 1024 + lane * 8);
  if (nj > 3) d3 = *(const bf16x8*)(rp + 1536 + lane * 8);

  float v0[8], v1[8], v2[8], v3[8];
  float mx = -1e30f;
#define PROC(VV, DD, BASE) do { \
    _Pragma("unroll") \
    for (int e = 0; e < 8; ++e) { \
      int col = (BASE) + lane * 8 + e; \
      float f = bf2f((unsigned short)DD[e]); \
      f = (col <= row) ? f : -1e30f; \
      VV[e] = f; mx = fmaxf(mx, f); \
    } } while (0)
  PROC(v0, d0, 0);
  if (nj > 1) PROC(v1, d1, 512);
  if (nj > 2) PROC(v2, d2, 1024);
  if (nj > 3) PROC(v3, d3, 1536);
#undef PROC
#pragma unroll
  for (int msk = 1; msk <= 32; msk <<= 1) mx = fmaxf(mx, __shfl_xor(mx, msk));

  float s = 0.f;
#define EXPS(VV) do { \
    _Pragma("unroll") \
    for (int e = 0; e < 8; ++e) { VV[e] = __expf(VV[e] - mx); s += VV[e]; } } while (0)
  EXPS(v0);
  if (nj > 1) EXPS(v1);
  if (nj > 2) EXPS(v2);
  if (nj > 3) EXPS(v3);
#undef EXPS
#pragma unroll
  for (int msk = 1; msk <= 32; msk <<= 1) s += __shfl_xor(s, msk);
  float inv = 1.0f / s;

#define WRB(VV, BASE) do { \
    bf16x8 o; \
    _Pragma("unroll") \
    for (int e = 0; e < 8; ++e) o[e] = (short)f2bf(VV[e] * inv); \
    *(bf16x8*)(rp + (BASE) + lane * 8) = o; } while (0)
  WRB(v0, 0);
  if (nj > 1) WRB(v1, 512);
  if (nj > 2) WRB(v2, 1024);
  if (nj > 3) WRB(v3, 1536);
#undef WRB
}

// ---------- O = P V, causal (K-range = (mb+1)*128), fp32 out ----------
__global__ __launch_bounds__(256, 2)
void pv_kernel(const unsigned short* __restrict__ P, const unsigned short* __restrict__ vT,
               float* __restrict__ out) {
  __shared__ short L[32768];   // 64KB double-buffered
  int id = blockIdx.x;
  int b = id & 7, u = id >> 3;
  int mb = 15 - (u >> 3);                  // biggest K-range first (load balance)
  int nb = u & 7;                          // d-block 0..7
  const size_t bT = (size_t)b * T_;
  int tid = threadIdx.x, lane = tid & 63, wid = tid >> 6;
  int wm = (wid >> 1) * 64, wn = (wid & 1) * 64;

  f32x4 acc[4][4];
#pragma unroll
  for (int i = 0; i < 4; ++i)
#pragma unroll
    for (int j = 0; j < 4; ++j)
#pragma unroll
      for (int r = 0; r < 4; ++r) acc[i][j][r] = 0.f;

  gemm_core_pipe(P + (bT + mb * 128) * (size_t)T_, T_,
                 vT + (size_t)(nb * 128) * M_ + bT, M_,
                 (mb + 1) * 2, L, lane, wid, acc);

#pragma unroll
  for (int nt = 0; nt < 4; ++nt) {
    int gcol = nb * 128 + wn + nt * 16 + (lane & 15);
#pragma unroll
    for (int mt = 0; mt < 4; ++mt) {
      int grow = mb * 128 + wm + mt * 16 + (lane >> 4) * 4;
#pragma unroll
      for (int r = 0; r < 4; ++r)
        out[(bT + grow + r) * (size_t)H_ + gcol] = acc[mt][nt][r];
    }
  }
}

extern "C" void kernel_launch(void* const* d_in, const int* in_sizes, int n_in,
                              void* d_out, int out_size, void* d_ws, size_t ws_size,
                              hipStream_t stream) {
  const float* x  = (const float*)d_in[0];
  const float* Wq = (const float*)d_in[1];
  const float* bq = (const float*)d_in[2];
  const float* Wk = (const float*)d_in[3];
  const float* bk = (const float*)d_in[4];
  const float* Wv = (const float*)d_in[5];
  const float* bv = (const float*)d_in[6];
  float* out = (float*)d_out;

  unsigned short* ws = (unsigned short*)d_ws;
  unsigned short* xb  = ws;                              // M x E bf16      (32MB)
  unsigned short* wqT = xb  + (size_t)M_ * E_;           // H x E bf16
  unsigned short* wkT = wqT + (size_t)E_ * H_;
  unsigned short* wvT = wkT + (size_t)E_ * H_;
  unsigned short* qb  = wvT + (size_t)E_ * H_;           // M x H bf16      (32MB)
  unsigned short* kbp = qb  + (size_t)M_ * H_;           // M x H bf16
  unsigned short* vTp = kbp + (size_t)M_ * H_;           // H x M bf16 (V transposed)
  unsigned short* Sp  = vTp + (size_t)M_ * H_;           // B x T x T bf16  (67MB) S, then P in-place

  conv_x_kernel<<<(M_ * E_ / 8 + 255) / 256, 256, 0, stream>>>(x, xb, M_ * E_ / 8);
  conv_wT_kernel<<<dim3(32, 32, 3), 256, 0, stream>>>(Wq, Wk, Wv, wqT, wkT, wvT);
  gemm_qkv_kernel<<<dim3(12, 64), 512, 0, stream>>>(xb, wqT, wkT, wvT, bq, bk, bv, qb, kbp, vTp);
  sgemm_kernel<<<dim3(136 * 8), 256, 0, stream>>>(qb, kbp, Sp);
  smax_kernel<<<dim3(512 * 8), 256, 0, stream>>>(Sp);
  pv_kernel<<<dim3(128 * 8), 256, 0, stream>>>(Sp, vTp, out);
}

// Round 16
// 243.270 us; speedup vs baseline: 1.2219x; 1.0059x over previous
//
#include <hip/hip_runtime.h>
#include <hip/hip_bf16.h>
#include <stdint.h>

#define B_ 8
#define T_ 2048
#define E_ 1024
#define H_ 1024
#define M_ (B_*T_)   // 16384

typedef __attribute__((ext_vector_type(8))) short bf16x8;
typedef __attribute__((ext_vector_type(4))) float f32x4;

__device__ __forceinline__ unsigned short f2bf(float f) {
  union { float f; unsigned int u; } v; v.f = f;
  unsigned int u = v.u;
  unsigned int r = u + 0x7fffu + ((u >> 16) & 1u);   // RNE (inputs finite)
  return (unsigned short)(r >> 16);
}

__device__ __forceinline__ float bf2f(unsigned short s) {
  union { unsigned int u; float f; } v; v.u = ((unsigned int)s) << 16;
  return v.f;
}

// async global->LDS, 16B per lane; LDS dest = wave-uniform base + lane*16
__device__ __forceinline__ void gload_lds16(const void* g, void* l) {
  __builtin_amdgcn_global_load_lds((const __attribute__((address_space(1))) void*)g,
                                   (__attribute__((address_space(3))) void*)l, 16, 0, 0);
}

#define MEMFENCE asm volatile("" ::: "memory")
#define BARRIER() do { MEMFENCE; __builtin_amdgcn_s_barrier(); MEMFENCE; } while (0)

// ---------- convert x (fp32) -> xb (bf16), 8 elems / thread ----------
__global__ void conv_x_kernel(const float* __restrict__ x,
                              unsigned short* __restrict__ xb, int n8) {
  int i = blockIdx.x * blockDim.x + threadIdx.x;
  if (i >= n8) return;
  const float4* src = (const float4*)(x + (size_t)i * 8);
  float4 a = src[0], b = src[1];
  uint4 o;
  o.x = (unsigned)f2bf(a.x) | ((unsigned)f2bf(a.y) << 16);
  o.y = (unsigned)f2bf(a.z) | ((unsigned)f2bf(a.w) << 16);
  o.z = (unsigned)f2bf(b.x) | ((unsigned)f2bf(b.y) << 16);
  o.w = (unsigned)f2bf(b.z) | ((unsigned)f2bf(b.w) << 16);
  *(uint4*)(xb + (size_t)i * 8) = o;
}

// ---------- convert + transpose W (E x H fp32) -> wT (H x E bf16) ----------
__global__ void conv_wT_kernel(const float* __restrict__ W0, const float* __restrict__ W1,
                               const float* __restrict__ W2,
                               unsigned short* __restrict__ T0, unsigned short* __restrict__ T1,
                               unsigned short* __restrict__ T2) {
  __shared__ float tile[32][33];
  const float* W = (blockIdx.z == 0) ? W0 : (blockIdx.z == 1) ? W1 : W2;
  unsigned short* Tt = (blockIdx.z == 0) ? T0 : (blockIdx.z == 1) ? T1 : T2;
  int k0 = blockIdx.x * 32;
  int n0 = blockIdx.y * 32;
  int t = threadIdx.x;
#pragma unroll
  for (int i = 0; i < 4; ++i) {
    int e = t + i * 256; int r = e >> 5, c = e & 31;
    tile[r][c] = W[(size_t)(k0 + r) * H_ + n0 + c];
  }
  __syncthreads();
#pragma unroll
  for (int i = 0; i < 4; ++i) {
    int e = t + i * 256; int r = e >> 5, c = e & 31;   // r = n-local, c = k-local
    Tt[(size_t)(n0 + r) * E_ + k0 + c] = f2bf(tile[c][r]);
  }
}

// ========== pipelined 128x128 core (4 waves, dbuf 64KB, counted vmcnt, 2 blocks/CU) ==========
// LDS buffer layout (bytes): A0 @0, B0 @16384, A1 @32768, B1 @49152.
__device__ __forceinline__ void stage128(const unsigned short* __restrict__ p, size_t stride,
                                         int kb0, short* buf, int lane, int wid) {
  const int srow = wid * 8 + (lane >> 3);
  const int scol = ((lane & 7) ^ (srow & 7)) * 8;
  short* l = buf + wid * 512;
#pragma unroll
  for (int i = 0; i < 4; ++i)
    gload_lds16(p + (size_t)(i * 32 + srow) * stride + kb0 + scol, l + i * 2048);
}

__device__ __forceinline__ void gemm_core_pipe(const unsigned short* __restrict__ Ap, size_t sA,
                                               const unsigned short* __restrict__ Bp, size_t sB,
                                               int NT, short* L, int lane, int wid, f32x4 acc[4][4]) {
  const int lo = lane & 15, hi = lane >> 4;
  const int wm = (wid >> 1) * 64, wn = (wid & 1) * 64;
  const int X0 = (hi << 4) ^ ((lo & 7) << 4);
  const int X1 = ((4 + hi) << 4) ^ ((lo & 7) << 4);
  const int laneA = (wm + lo) << 7;
  const int laneB = (wn + lo) << 7;

  bf16x8 a[4][2], b0[2][2], b1[2][2];

#define STA_(V) do { if ((V) < NT) stage128(Ap, sA, (V) * 64, L + (((V) & 1) ? 16384 : 0), lane, wid); } while (0)
#define STB_(V) do { if ((V) < NT) stage128(Bp, sB, (V) * 64, L + (((V) & 1) ? 24576 : 8192), lane, wid); } while (0)

  STA_(0); STB_(0); STA_(1); STB_(1);
  asm volatile("s_waitcnt vmcnt(8)" ::: "memory");
  BARRIER();
  __builtin_amdgcn_sched_barrier(0);
  {
    const char* Ac = (const char*)L;
    const char* Bc = (const char*)L + 16384;
#pragma unroll
    for (int mt = 0; mt < 4; ++mt) {
      a[mt][0] = *(const bf16x8*)(Ac + laneA + X0 + mt * 2048);
      a[mt][1] = *(const bf16x8*)(Ac + laneA + X1 + mt * 2048);
    }
#pragma unroll
    for (int nt = 0; nt < 2; ++nt) {
      b0[nt][0] = *(const bf16x8*)(Bc + laneB + X0 + nt * 2048);
      b0[nt][1] = *(const bf16x8*)(Bc + laneB + X1 + nt * 2048);
    }
    asm volatile("s_waitcnt lgkmcnt(0)" ::: "memory");
    __builtin_amdgcn_sched_barrier(0);
  }

  for (int U = 0; U < NT; ++U) {
    const char* Bc = (const char*)L + 16384 + (U & 1) * 32768;
    const char* An = (const char*)L + (((U + 1) & 1) ? 32768 : 0);
    const char* Bn = (const char*)L + 16384 + (((U + 1) & 1) ? 32768 : 0);
    const bool pf = (U + 1 < NT);

    // phase 1: MFMA a*b0 || read b1 || stage A(U+2)
    STA_(U + 2);
    __builtin_amdgcn_s_setprio(1);
#pragma unroll
    for (int mt = 0; mt < 2; ++mt)
#pragma unroll
      for (int nt = 0; nt < 2; ++nt)
#pragma unroll
        for (int kt = 0; kt < 2; ++kt)
          acc[mt][nt] = __builtin_amdgcn_mfma_f32_16x16x32_bf16(a[mt][kt], b0[nt][kt], acc[mt][nt], 0, 0, 0);
#pragma unroll
    for (int nt = 0; nt < 2; ++nt) {
      b1[nt][0] = *(const bf16x8*)(Bc + laneB + X0 + 4096 + nt * 2048);
      b1[nt][1] = *(const bf16x8*)(Bc + laneB + X1 + 4096 + nt * 2048);
    }
#pragma unroll
    for (int mt = 2; mt < 4; ++mt)
#pragma unroll
      for (int nt = 0; nt < 2; ++nt)
#pragma unroll
        for (int kt = 0; kt < 2; ++kt)
          acc[mt][nt] = __builtin_amdgcn_mfma_f32_16x16x32_bf16(a[mt][kt], b0[nt][kt], acc[mt][nt], 0, 0, 0);
    __builtin_amdgcn_s_setprio(0);
    asm volatile("s_waitcnt lgkmcnt(0)" ::: "memory");
    if (U + 2 < NT) asm volatile("s_waitcnt vmcnt(4)" ::: "memory");
    else            asm volatile("s_waitcnt vmcnt(0)" ::: "memory");
    BARRIER();
    __builtin_amdgcn_sched_barrier(0);

    // phase 2: MFMA a*b1 || read next a,b0 || stage B(U+2)
    STB_(U + 2);
    __builtin_amdgcn_s_setprio(1);
#pragma unroll
    for (int mt = 0; mt < 2; ++mt)
#pragma unroll
      for (int nt = 0; nt < 2; ++nt)
#pragma unroll
        for (int kt = 0; kt < 2; ++kt)
          acc[mt][2 + nt] = __builtin_amdgcn_mfma_f32_16x16x32_bf16(a[mt][kt], b1[nt][kt], acc[mt][2 + nt], 0, 0, 0);
    if (pf) {
#pragma unroll
      for (int mt = 0; mt < 2; ++mt) {
        a[mt][0] = *(const bf16x8*)(An + laneA + X0 + mt * 2048);
        a[mt][1] = *(const bf16x8*)(An + laneA + X1 + mt * 2048);
      }
#pragma unroll
      for (int nt = 0; nt < 2; ++nt) {
        b0[nt][0] = *(const bf16x8*)(Bn + laneB + X0 + nt * 2048);
        b0[nt][1] = *(const bf16x8*)(Bn + laneB + X1 + nt * 2048);
      }
    }
#pragma unroll
    for (int mt = 2; mt < 4; ++mt)
#pragma unroll
      for (int nt = 0; nt < 2; ++nt)
#pragma unroll
        for (int kt = 0; kt < 2; ++kt)
          acc[mt][2 + nt] = __builtin_amdgcn_mfma_f32_16x16x32_bf16(a[mt][kt], b1[nt][kt], acc[mt][2 + nt], 0, 0, 0);
    if (pf) {
#pragma unroll
      for (int mt = 2; mt < 4; ++mt) {
        a[mt][0] = *(const bf16x8*)(An + laneA + X0 + mt * 2048);
        a[mt][1] = *(const bf16x8*)(An + laneA + X1 + mt * 2048);
      }
    }
    __builtin_amdgcn_s_setprio(0);
    asm volatile("s_waitcnt lgkmcnt(0)" ::: "memory");
    BARRIER();
    __builtin_amdgcn_sched_barrier(0);
  }
#undef STA_
#undef STB_
}

// ---------- fused QKV GEMM on the pipelined 128x128 core (R14 proven) ----------
// grid: (24 = which*8 + n-tile, 128 M-tiles). x fastest -> the 24 blocks sharing
// one A M-panel are co-resident (A read ~once; W panels stay L2-hot).
__global__ __launch_bounds__(256, 2)
void gemm_qkv_kernel(const unsigned short* __restrict__ xb,
                     const unsigned short* __restrict__ wqT, const unsigned short* __restrict__ wkT,
                     const unsigned short* __restrict__ wvT,
                     const float* __restrict__ bq, const float* __restrict__ bk,
                     const float* __restrict__ bv,
                     unsigned short* __restrict__ qb, unsigned short* __restrict__ kb,
                     unsigned short* __restrict__ vb) {
  __shared__ short L[32768];   // 64KB double-buffered
  const int which = blockIdx.x >> 3;
  const int ncol0 = (blockIdx.x & 7) * 128;
  const unsigned short* Bt = (which == 0) ? wqT : (which == 1) ? wkT : wvT;
  const float* bias = (which == 0) ? bq : (which == 1) ? bk : bv;
  unsigned short* outp = (which == 0) ? qb : (which == 1) ? kb : vb;
  const int m0 = blockIdx.y * 128;
  int tid = threadIdx.x, lane = tid & 63, wid = tid >> 6;
  int wm = (wid >> 1) * 64, wn = (wid & 1) * 64;

  f32x4 acc[4][4];
#pragma unroll
  for (int i = 0; i < 4; ++i)
#pragma unroll
    for (int j = 0; j < 4; ++j)
#pragma unroll
      for (int r = 0; r < 4; ++r) acc[i][j][r] = 0.f;

  gemm_core_pipe(xb + (size_t)m0 * E_, E_,
                 Bt + (size_t)ncol0 * E_, E_, E_ / 64,
                 L, lane, wid, acc);

  if (which == 2) {
    // transposed write: vT[d = gcol][m = grow..grow+3], 8B packed
#pragma unroll
    for (int nt = 0; nt < 4; ++nt) {
      int gcol = ncol0 + wn + nt * 16 + (lane & 15);
      float bb = bias[gcol];
#pragma unroll
      for (int mt = 0; mt < 4; ++mt) {
        int grow = m0 + wm + mt * 16 + (lane >> 4) * 4;
        ushort4 o;
        o.x = f2bf(acc[mt][nt][0] + bb);
        o.y = f2bf(acc[mt][nt][1] + bb);
        o.z = f2bf(acc[mt][nt][2] + bb);
        o.w = f2bf(acc[mt][nt][3] + bb);
        *(ushort4*)(outp + (size_t)gcol * M_ + grow) = o;
      }
    }
  } else {
#pragma unroll
    for (int nt = 0; nt < 4; ++nt) {
      int gcol = ncol0 + wn + nt * 16 + (lane & 15);
      float bb = bias[gcol];
#pragma unroll
      for (int mt = 0; mt < 4; ++mt) {
        int grow = m0 + wm + mt * 16 + (lane >> 4) * 4;
#pragma unroll
        for (int r = 0; r < 4; ++r)
          outp[(size_t)(grow + r) * H_ + gcol] = f2bf(acc[mt][nt][r] + bb);
      }
    }
  }
}

// ---------- S = (Q K^T) * scale, causal lower-tri 128x128 tiles, bf16 out ----------
// 1024 blocks (exactly 2 dispatch waves @2/CU); blocks 0..63 do a second tile
// (ids 1024..1087 = the mb=15 stragglers), started first for overlap.
__global__ __launch_bounds__(256, 2)
void sgemm_kernel(const unsigned short* __restrict__ qb, const unsigned short* __restrict__ kb,
                  unsigned short* __restrict__ S) {
  __shared__ short L[32768];   // 64KB double-buffered
  int tid = threadIdx.x, lane = tid & 63, wid = tid >> 6;
  int wm = (wid >> 1) * 64, wn = (wid & 1) * 64;
  const int npass = (blockIdx.x < 64) ? 2 : 1;

  for (int pass = 0; pass < npass; ++pass) {
    int id = blockIdx.x + pass * 1024;
    int b = id & 7, t = id >> 3;            // batch-fastest: same batch -> same XCD
    int mb = 0;
    while ((mb + 1) * (mb + 2) / 2 <= t) ++mb;
    int nb = t - mb * (mb + 1) / 2;         // nb <= mb (lower triangle)
    const size_t bT = (size_t)b * T_;

    f32x4 acc[4][4];
#pragma unroll
    for (int i = 0; i < 4; ++i)
#pragma unroll
      for (int j = 0; j < 4; ++j)
#pragma unroll
        for (int r = 0; r < 4; ++r) acc[i][j][r] = 0.f;

    gemm_core_pipe(qb + (bT + mb * 128) * (size_t)H_, H_,
                   kb + (bT + nb * 128) * (size_t)H_, H_, H_ / 64,
                   L, lane, wid, acc);

#pragma unroll
    for (int nt = 0; nt < 4; ++nt) {
      int gcol = nb * 128 + wn + nt * 16 + (lane & 15);
#pragma unroll
      for (int mt = 0; mt < 4; ++mt) {
        int grow = mb * 128 + wm + mt * 16 + (lane >> 4) * 4;
#pragma unroll
        for (int r = 0; r < 4; ++r)
          S[(bT + grow + r) * (size_t)T_ + gcol] = f2bf(acc[mt][nt][r] * 0.03125f);
      }
    }
    if (pass + 1 < npass) { BARRIER(); }   // LDS reuse between passes (reads already drained)
  }
}

// ---------- in-place causal row softmax: only needed 512-col blocks ----------
__global__ __launch_bounds__(256)
void smax_kernel(unsigned short* __restrict__ S) {
  int id = blockIdx.x;
  int b = id & 7, rb = id >> 3;                 // rb 0..511
  int w = threadIdx.x >> 6, lane = threadIdx.x & 63;
  int row = (511 - rb) * 4 + w;                 // biggest rows dispatched first
  unsigned short* rp = S + ((size_t)b * T_ + row) * T_;
  const int nj = (row >> 9) + 1;                // 1..4 column blocks needed

  bf16x8 d0, d1, d2, d3;
  d0 = *(const bf16x8*)(rp + lane * 8);
  if (nj > 1) d1 = *(const bf16x8*)(rp + 512 + lane * 8);
  if (nj > 2) d2 = *(const bf16x8*)(rp + 1024 + lane * 8);
  if (nj > 3) d3 = *(const bf16x8*)(rp + 1536 + lane * 8);

  float v0[8], v1[8], v2[8], v3[8];
  float mx = -1e30f;
#define PROC(VV, DD, BASE) do { \
    _Pragma("unroll") \
    for (int e = 0; e < 8; ++e) { \
      int col = (BASE) + lane * 8 + e; \
      float f = bf2f((unsigned short)DD[e]); \
      f = (col <= row) ? f : -1e30f; \
      VV[e] = f; mx = fmaxf(mx, f); \
    } } while (0)
  PROC(v0, d0, 0);
  if (nj > 1) PROC(v1, d1, 512);
  if (nj > 2) PROC(v2, d2, 1024);
  if (nj > 3) PROC(v3, d3, 1536);
#undef PROC
#pragma unroll
  for (int msk = 1; msk <= 32; msk <<= 1) mx = fmaxf(mx, __shfl_xor(mx, msk));

  float s = 0.f;
#define EXPS(VV) do { \
    _Pragma("unroll") \
    for (int e = 0; e < 8; ++e) { VV[e] = __expf(VV[e] - mx); s += VV[e]; } } while (0)
  EXPS(v0);
  if (nj > 1) EXPS(v1);
  if (nj > 2) EXPS(v2);
  if (nj > 3) EXPS(v3);
#undef EXPS
#pragma unroll
  for (int msk = 1; msk <= 32; msk <<= 1) s += __shfl_xor(s, msk);
  float inv = 1.0f / s;

#define WRB(VV, BASE) do { \
    bf16x8 o; \
    _Pragma("unroll") \
    for (int e = 0; e < 8; ++e) o[e] = (short)f2bf(VV[e] * inv); \
    *(bf16x8*)(rp + (BASE) + lane * 8) = o; } while (0)
  WRB(v0, 0);
  if (nj > 1) WRB(v1, 512);
  if (nj > 2) WRB(v2, 1024);
  if (nj > 3) WRB(v3, 1536);
#undef WRB
}

// ---------- O = P V, causal (K-range = (mb+1)*128), fp32 out ----------
__global__ __launch_bounds__(256, 2)
void pv_kernel(const unsigned short* __restrict__ P, const unsigned short* __restrict__ vT,
               float* __restrict__ out) {
  __shared__ short L[32768];   // 64KB double-buffered
  int id = blockIdx.x;
  int b = id & 7, u = id >> 3;
  int mb = 15 - (u >> 3);                  // biggest K-range first (load balance)
  int nb = u & 7;                          // d-block 0..7
  const size_t bT = (size_t)b * T_;
  int tid = threadIdx.x, lane = tid & 63, wid = tid >> 6;
  int wm = (wid >> 1) * 64, wn = (wid & 1) * 64;

  f32x4 acc[4][4];
#pragma unroll
  for (int i = 0; i < 4; ++i)
#pragma unroll
    for (int j = 0; j < 4; ++j)
#pragma unroll
      for (int r = 0; r < 4; ++r) acc[i][j][r] = 0.f;

  gemm_core_pipe(P + (bT + mb * 128) * (size_t)T_, T_,
                 vT + (size_t)(nb * 128) * M_ + bT, M_,
                 (mb + 1) * 2, L, lane, wid, acc);

#pragma unroll
  for (int nt = 0; nt < 4; ++nt) {
    int gcol = nb * 128 + wn + nt * 16 + (lane & 15);
#pragma unroll
    for (int mt = 0; mt < 4; ++mt) {
      int grow = mb * 128 + wm + mt * 16 + (lane >> 4) * 4;
#pragma unroll
      for (int r = 0; r < 4; ++r)
        out[(bT + grow + r) * (size_t)H_ + gcol] = acc[mt][nt][r];
    }
  }
}

extern "C" void kernel_launch(void* const* d_in, const int* in_sizes, int n_in,
                              void* d_out, int out_size, void* d_ws, size_t ws_size,
                              hipStream_t stream) {
  const float* x  = (const float*)d_in[0];
  const float* Wq = (const float*)d_in[1];
  const float* bq = (const float*)d_in[2];
  const float* Wk = (const float*)d_in[3];
  const float* bk = (const float*)d_in[4];
  const float* Wv = (const float*)d_in[5];
  const float* bv = (const float*)d_in[6];
  float* out = (float*)d_out;

  unsigned short* ws = (unsigned short*)d_ws;
  unsigned short* xb  = ws;                              // M x E bf16      (32MB)
  unsigned short* wqT = xb  + (size_t)M_ * E_;           // H x E bf16
  unsigned short* wkT = wqT + (size_t)E_ * H_;
  unsigned short* wvT = wkT + (size_t)E_ * H_;
  unsigned short* qb  = wvT + (size_t)E_ * H_;           // M x H bf16      (32MB)
  unsigned short* kbp = qb  + (size_t)M_ * H_;           // M x H bf16
  unsigned short* vTp = kbp + (size_t)M_ * H_;           // H x M bf16 (V transposed)
  unsigned short* Sp  = vTp + (size_t)M_ * H_;           // B x T x T bf16  (67MB) S, then P in-place

  conv_x_kernel<<<(M_ * E_ / 8 + 255) / 256, 256, 0, stream>>>(x, xb, M_ * E_ / 8);
  conv_wT_kernel<<<dim3(32, 32, 3), 256, 0, stream>>>(Wq, Wk, Wv, wqT, wkT, wvT);
  gemm_qkv_kernel<<<dim3(24, 128), 256, 0, stream>>>(xb, wqT, wkT, wvT, bq, bk, bv, qb, kbp, vTp);
  sgemm_kernel<<<dim3(1024), 256, 0, stream>>>(qb, kbp, Sp);
  smax_kernel<<<dim3(512 * 8), 256, 0, stream>>>(Sp);
  pv_kernel<<<dim3(128 * 8), 256, 0, stream>>>(Sp, vTp, out);
}